// Round 5
// baseline (502.436 us; speedup 1.0000x reference)
//
#include <hip/hip_runtime.h>
#include <math.h>

#define N_TOK 2000
#define NH 8
#define HD 32
#define SCALE 25.0f
#define SIM_TH 0.75f
#define EPSF 1e-8f
#define NSLOT 4   // ceil(2000/512)
#define NTAIL 464 // valid lanes in slot 3: 2000 - 3*512
#define SPAD 2048 // padded score-plane stride

typedef _Float16 half2_t __attribute__((ext_vector_type(2)));

__device__ __forceinline__ unsigned rflu(unsigned u) {
  return (unsigned)__builtin_amdgcn_readfirstlane((int)u);
}
__device__ __forceinline__ half2_t u2h(unsigned u) {
  return __builtin_bit_cast(half2_t, u);
}
__device__ __forceinline__ unsigned h2u(half2_t h) {
  return __builtin_bit_cast(unsigned, h);
}

// f32 += f16x2 . f16x2 (v_dot2_f32_f16; products exact, fp32 accumulate)
__device__ __forceinline__ float fdot2f(unsigned a, unsigned b, float c) {
#if __has_builtin(__builtin_amdgcn_fdot2)
  return __builtin_amdgcn_fdot2(u2h(a), u2h(b), c, false);
#else
  const half2_t ha = u2h(a), hb = u2h(b);
  return c + (float)ha.x * (float)hb.x + (float)ha.y * (float)hb.y;
#endif
}

// packed block reductions over 512 threads (8 waves); red must hold 8*NV
template <int NV>
__device__ __forceinline__ void block_sumN(float* v, float* red) {
#pragma unroll
  for (int off = 32; off > 0; off >>= 1) {
#pragma unroll
    for (int q = 0; q < NV; q++) v[q] += __shfl_xor(v[q], off, 64);
  }
  __syncthreads();
  const int wid = threadIdx.x >> 6;
  if ((threadIdx.x & 63) == 0) {
#pragma unroll
    for (int q = 0; q < NV; q++) red[wid * NV + q] = v[q];
  }
  __syncthreads();
#pragma unroll
  for (int q = 0; q < NV; q++) {
    float s = 0.f;
#pragma unroll
    for (int w = 0; w < 8; w++) s += red[w * NV + q];
    v[q] = s;
  }
}
template <int NV>
__device__ __forceinline__ void block_maxN(float* v, float* red) {
#pragma unroll
  for (int off = 32; off > 0; off >>= 1) {
#pragma unroll
    for (int q = 0; q < NV; q++) v[q] = fmaxf(v[q], __shfl_xor(v[q], off, 64));
  }
  __syncthreads();
  const int wid = threadIdx.x >> 6;
  if ((threadIdx.x & 63) == 0) {
#pragma unroll
    for (int q = 0; q < NV; q++) red[wid * NV + q] = v[q];
  }
  __syncthreads();
#pragma unroll
  for (int q = 0; q < NV; q++) {
    float s = -1e30f;
#pragma unroll
    for (int w = 0; w < 8; w++) s = fmaxf(s, red[w * NV + q]);
    v[q] = s;
  }
}

// load 4 query rows' packed-f16 data. qp0/qp1 -> SGPR (rflu); qp2/qp3 stay
// in VGPR on purpose: SGPR file can't hold 64 uniform words; at 2 waves/SIMD
// (single 512-thread block resident) the VGPR budget is 256 -> free.
#define LOAD_Q4(BUF)                                                      \
  {                                                                       \
    const uint4* __restrict__ qb =                                        \
        (const uint4*)(BUF) + (size_t)h * 4 * N_TOK;                      \
    _Pragma("unroll") for (int gg = 0; gg < 4; gg++) {                    \
      const uint4 a0 = qb[gg * N_TOK + i0];                               \
      const uint4 a1 = qb[gg * N_TOK + i1];                               \
      const uint4 a2 = qb[gg * N_TOK + i2];                               \
      const uint4 a3 = qb[gg * N_TOK + i3];                               \
      qp0[4 * gg + 0] = rflu(a0.x); qp0[4 * gg + 1] = rflu(a0.y);         \
      qp0[4 * gg + 2] = rflu(a0.z); qp0[4 * gg + 3] = rflu(a0.w);         \
      qp1[4 * gg + 0] = rflu(a1.x); qp1[4 * gg + 1] = rflu(a1.y);         \
      qp1[4 * gg + 2] = rflu(a1.z); qp1[4 * gg + 3] = rflu(a1.w);         \
      qp2[4 * gg + 0] = a2.x; qp2[4 * gg + 1] = a2.y;                     \
      qp2[4 * gg + 2] = a2.z; qp2[4 * gg + 3] = a2.w;                     \
      qp3[4 * gg + 0] = a3.x; qp3[4 * gg + 1] = a3.y;                     \
      qp3[4 * gg + 2] = a3.z; qp3[4 * gg + 3] = a3.w;                     \
    }                                                                     \
  }

#define DOT4(KW, QP, D)                                                   \
  D = fdot2f((KW).x, QP[4 * g_ + 0], D);                                  \
  D = fdot2f((KW).y, QP[4 * g_ + 1], D);                                  \
  D = fdot2f((KW).z, QP[4 * g_ + 2], D);                                  \
  D = fdot2f((KW).w, QP[4 * g_ + 3], D);

// ---------------------------------------------------------------------------
// Kernel 0: pack W fp32 [256][768] into f16 pair-quads Wq[k/8][768].
// grid = (96, 2), block = 256
// ---------------------------------------------------------------------------
__global__ __launch_bounds__(256) void wpack_kernel(
    const float* __restrict__ W_cls, const float* __restrict__ W_reg,
    unsigned* __restrict__ Wp_cls, unsigned* __restrict__ Wp_reg) {
  const int idx = blockIdx.x * 256 + threadIdx.x;
  const int kq = idx / 768, c = idx % 768;
  const float* __restrict__ W = blockIdx.y ? W_reg : W_cls;
  uint4* __restrict__ Wq = (uint4*)(blockIdx.y ? Wp_reg : Wp_cls);
  uint4 o;
  o.x = h2u((half2_t){(_Float16)W[(8 * kq + 0) * 768 + c],
                      (_Float16)W[(8 * kq + 1) * 768 + c]});
  o.y = h2u((half2_t){(_Float16)W[(8 * kq + 2) * 768 + c],
                      (_Float16)W[(8 * kq + 3) * 768 + c]});
  o.z = h2u((half2_t){(_Float16)W[(8 * kq + 4) * 768 + c],
                      (_Float16)W[(8 * kq + 5) * 768 + c]});
  o.w = h2u((half2_t){(_Float16)W[(8 * kq + 6) * 768 + c],
                      (_Float16)W[(8 * kq + 7) * 768 + c]});
  Wq[idx] = o;
}

// ---------------------------------------------------------------------------
// Kernel 1: QKV projection via f16 W + fdot2, 4 rows/block (measured best).
// grid = (500, 2), block = 256
// ---------------------------------------------------------------------------
__global__ __launch_bounds__(256) void qkv_norm_kernel(
    const float* __restrict__ x_cls, const float* __restrict__ x_reg,
    const unsigned* __restrict__ Wp_cls, const unsigned* __restrict__ Wp_reg,
    _Float16* __restrict__ qc_h, _Float16* __restrict__ qr_h,
    _Float16* __restrict__ kc_h, _Float16* __restrict__ kr_h,
    _Float16* __restrict__ vn_h, float* __restrict__ v_rm,
    _Float16* __restrict__ v_h) {
  __shared__ unsigned xs_p[4][128];
  __shared__ float res[4][768];
  __shared__ float inv_norm[96];

  const int n0 = blockIdx.x * 4;
  const int which = blockIdx.y;
  const int tid = threadIdx.x;
  const float* __restrict__ x = which ? x_reg : x_cls;
  const uint4* __restrict__ Wq = (const uint4*)(which ? Wp_reg : Wp_cls);

  if (tid < 128) {
#pragma unroll
    for (int r = 0; r < 4; r++) {
      const float2 xv = ((const float2*)x)[(size_t)(n0 + r) * 128 + tid];
      xs_p[r][tid] = h2u((half2_t){(_Float16)xv.x, (_Float16)xv.y});
    }
  }
  __syncthreads();

  float acc[4][3];
#pragma unroll
  for (int r = 0; r < 4; r++) acc[r][0] = acc[r][1] = acc[r][2] = 0.f;

#pragma unroll 2
  for (int kq = 0; kq < 32; kq++) {
    const uint4 w0 = Wq[kq * 768 + tid];
    const uint4 w1 = Wq[kq * 768 + tid + 256];
    const uint4 w2 = Wq[kq * 768 + tid + 512];
#pragma unroll
    for (int r = 0; r < 4; r++) {
      const uint4 xp = *(const uint4*)&xs_p[r][kq * 4];
      acc[r][0] = fdot2f(w0.x, xp.x, acc[r][0]);
      acc[r][0] = fdot2f(w0.y, xp.y, acc[r][0]);
      acc[r][0] = fdot2f(w0.z, xp.z, acc[r][0]);
      acc[r][0] = fdot2f(w0.w, xp.w, acc[r][0]);
      acc[r][1] = fdot2f(w1.x, xp.x, acc[r][1]);
      acc[r][1] = fdot2f(w1.y, xp.y, acc[r][1]);
      acc[r][1] = fdot2f(w1.z, xp.z, acc[r][1]);
      acc[r][1] = fdot2f(w1.w, xp.w, acc[r][1]);
      acc[r][2] = fdot2f(w2.x, xp.x, acc[r][2]);
      acc[r][2] = fdot2f(w2.y, xp.y, acc[r][2]);
      acc[r][2] = fdot2f(w2.z, xp.z, acc[r][2]);
      acc[r][2] = fdot2f(w2.w, xp.w, acc[r][2]);
    }
  }
#pragma unroll
  for (int r = 0; r < 4; r++) {
    res[r][tid] = acc[r][0];
    res[r][tid + 256] = acc[r][1];
    res[r][tid + 512] = acc[r][2];
  }
  __syncthreads();

  if (tid < 96) {
    const int r = tid / 24, grp = tid % 24;
    float ss = 0.f;
#pragma unroll
    for (int d = 0; d < HD; d++) {
      const float v = res[r][grp * 32 + d];
      ss += v * v;
    }
    inv_norm[tid] = 1.0f / (sqrtf(ss) + EPSF);
  }
  __syncthreads();

#pragma unroll
  for (int j = 0; j < 3; j++) {
    const int c = tid + j * 256;
    const int qkv = c >> 8, grp = c >> 5;
    const int h = grp & 7, d = c & 31;
    const int gg = d >> 3, dd = d & 7;
#pragma unroll
    for (int r = 0; r < 4; r++) {
      const int n = n0 + r;
      const float val = res[r][c];
      const float nval = val * inv_norm[r * 24 + grp];
      const size_t fi = ((size_t)(h * 4 + gg) * N_TOK + n) * 8 + dd;
      if (qkv == 0) {
        (which ? qr_h : qc_h)[fi] = (_Float16)nval;
      } else if (qkv == 1) {
        (which ? kr_h : kc_h)[fi] = (_Float16)nval;
      } else if (which == 0) {
        v_rm[(h * N_TOK + n) * HD + d] = val;
        vn_h[fi] = (_Float16)nval;
        v_h[((size_t)h * N_TOK + n) * HD + d] = (_Float16)val;
      }
    }
  }
}

// ---------------------------------------------------------------------------
// Kernel 2 (r25 -> r26): byte-identical body; ONLY change is
// __launch_bounds__(512, 1). Post-mortem r24/r25: both (512,2) and (512)
// produced VGPR_Count = exactly 128 with ~2.2 KB/thread scratch spills
// (WRITE_SIZE 586 MB). Mechanism: at 512t the backend's occupancy heuristic
// targets 2 workgroups/CU = 4 waves/SIMD -> VGPR cap 512/4 = 128. The hard
// architectural cap for a 512t block is 2 waves/SIMD -> 256 VGPRs; we need
// ~170-210. (512,1) relaxes the heuristic to 1 workgroup/CU under either
// documented semantics of the 2nd arg (1 block/CU -> 8 waves/CU -> 256 cap;
// or 1 wave/EU -> cap 512, clamped to 256 by flat-wg-size). Keeps 500
// blocks x 8 waves = 4000 waves (r21's count) with TQ=4's 2.0 GB L2 stream.
// grid = 500, block = 512
// ---------------------------------------------------------------------------
__global__ __launch_bounds__(512, 1) void attn26_kernel(
    const _Float16* __restrict__ qc_h, const _Float16* __restrict__ qr_h,
    const _Float16* __restrict__ kc_h, const _Float16* __restrict__ kr_h,
    const _Float16* __restrict__ vn_h, const float* __restrict__ v_rm,
    const _Float16* __restrict__ v_h,
    float* __restrict__ out_x, float* __restrict__ out_sim) {
  __shared__ float s_attn[4][SPAD];  // 32 KB f32; tails stay 0 for PV
  __shared__ float s_union[16896];   // 67.6 KB: er f16 [4][SPAD] / part
  __shared__ float red[512];         // 2 KB: stage-2 + block reductions

  _Float16* __restrict__ er_h = (_Float16*)s_union;  // plane r at r*SPAD
  float* __restrict__ part = s_union;  // 512 units x 33 floats ([e][r] x8 +1)

  const int tid = threadIdx.x;
  const int i0 = blockIdx.x * 4;
  const int i1 = i0 + 1, i2 = i0 + 2, i3 = i0 + 3;
  const int bs0 = (i0 / 10) * 10, bs1 = (i1 / 10) * 10;
  const int bs2 = (i2 / 10) * 10, bs3 = (i3 / 10) * 10;

  float sim[4][NSLOT], raw[4][NSLOT];
#pragma unroll
  for (int r = 0; r < 4; r++) {
#pragma unroll
    for (int t = 0; t < NSLOT; t++) { sim[r][t] = 0.f; raw[r][t] = 0.f; }
  }
  if (tid < SPAD - N_TOK) {
#pragma unroll
    for (int r = 0; r < 4; r++) s_attn[r][N_TOK + tid] = 0.f;
  }
  __syncthreads();

  unsigned qp0[16], qp1[16], qp2[16], qp3[16];

  // 3-stage pipelined sweep over 4 slots of 512: loads for t+2 in flight.
  auto sweep = [&](const uint4* __restrict__ kt4, auto&& emit) {
    uint4 ka[4], kb[4];
#pragma unroll
    for (int g_ = 0; g_ < 4; g_++) ka[g_] = kt4[g_ * N_TOK + tid];  // t=0
    {
      const int m1 = tid + 512;  // t=1 always valid (t=1 < 3)
#pragma unroll
      for (int g_ = 0; g_ < 4; g_++) kb[g_] = kt4[g_ * N_TOK + m1];
    }
#pragma unroll
    for (int t = 0; t < NSLOT; t++) {
      uint4 kc_[4];
      if (t < NSLOT - 2) {  // prefetch t+2
        const int m2 = tid + 512 * (t + 2);
        const bool v2 = (t + 2 < 3) || (tid < NTAIL);
        const int mc2 = v2 ? m2 : (N_TOK - 1);
#pragma unroll
        for (int g_ = 0; g_ < 4; g_++) kc_[g_] = kt4[g_ * N_TOK + mc2];
      }
      float d0 = 0.f, d1 = 0.f, d2 = 0.f, d3 = 0.f;
#pragma unroll
      for (int g_ = 0; g_ < 4; g_++) {
        DOT4(ka[g_], qp0, d0);
        DOT4(ka[g_], qp1, d1);
        DOT4(ka[g_], qp2, d2);
        DOT4(ka[g_], qp3, d3);
      }
      emit(t, d0, d1, d2, d3);
#pragma unroll
      for (int g_ = 0; g_ < 4; g_++) {
        ka[g_] = kb[g_];
        kb[g_] = kc_[g_];
      }
    }
  };

  for (int hh = 0; hh < NH; hh++) {
    const int h = (blockIdx.x + hh) & 7;  // XCD-local head schedule

    float sums[8];  // cls x4, reg x4
#pragma unroll
    for (int q = 0; q < 8; q++) sums[q] = 0.f;

    // ===== phase C: cls scores -> e = exp(s-25) -> s_attn (unnormalized) ===
    LOAD_Q4(qc_h);
    sweep((const uint4*)kc_h + (size_t)h * 4 * N_TOK,
          [&](int t, float d0, float d1, float d2, float d3) {
            const int m = tid + 512 * t;
            const bool valid = (t < 3) || (tid < NTAIL);
            const float e0 = valid ? __expf(d0 * SCALE - SCALE) : 0.f;
            const float e1 = valid ? __expf(d1 * SCALE - SCALE) : 0.f;
            const float e2 = valid ? __expf(d2 * SCALE - SCALE) : 0.f;
            const float e3 = valid ? __expf(d3 * SCALE - SCALE) : 0.f;
            sums[0] += e0; sums[1] += e1; sums[2] += e2; sums[3] += e3;
            if (valid) {
              s_attn[0][m] = e0;
              s_attn[1][m] = e1;
              s_attn[2][m] = e2;
              s_attn[3][m] = e3;
            }
          });

    // ===== phase R: reg scores -> er (f16) — NO reduction between phases ===
    LOAD_Q4(qr_h);
    sweep((const uint4*)kr_h + (size_t)h * 4 * N_TOK,
          [&](int t, float d0, float d1, float d2, float d3) {
            const int m = tid + 512 * t;
            const bool valid = (t < 3) || (tid < NTAIL);
            const float e0 = valid ? __expf(d0 * SCALE - SCALE) : 0.f;
            const float e1 = valid ? __expf(d1 * SCALE - SCALE) : 0.f;
            const float e2 = valid ? __expf(d2 * SCALE - SCALE) : 0.f;
            const float e3 = valid ? __expf(d3 * SCALE - SCALE) : 0.f;
            sums[4] += e0; sums[5] += e1; sums[6] += e2; sums[7] += e3;
            if (valid) {
              er_h[m] = (_Float16)e0;
              er_h[SPAD + m] = (_Float16)e1;
              er_h[2 * SPAD + m] = (_Float16)e2;
              er_h[3 * SPAD + m] = (_Float16)e3;
            }
          });

    // ===== ONE packed reduction for all 8 softmax sums =====
    block_sumN<8>(sums, red);
    const float nc0 = 0.5f / sums[0], nc1 = 0.5f / sums[1];
    const float nc2 = 0.5f / sums[2], nc3 = 0.5f / sums[3];
    const float nr0 = 0.5f / sums[4], nr1 = 0.5f / sums[5];
    const float nr2 = 0.5f / sums[6], nr3 = 0.5f / sums[7];

    // ===== combine, mask (per-row decade), sim += =====
#pragma unroll
    for (int t = 0; t < NSLOT; t++) {
      const int m = tid + 512 * t;
      if ((t < 3) || (tid < NTAIL)) {
        float a0 = s_attn[0][m] * nc0 + (float)er_h[m] * nr0;
        float a1 = s_attn[1][m] * nc1 + (float)er_h[SPAD + m] * nr1;
        float a2 = s_attn[2][m] * nc2 + (float)er_h[2 * SPAD + m] * nr2;
        float a3 = s_attn[3][m] * nc3 + (float)er_h[3 * SPAD + m] * nr3;
        if (m >= bs0 && m < bs0 + 9 && m != i0) a0 = 0.f;
        if (m >= bs1 && m < bs1 + 9 && m != i1) a1 = 0.f;
        if (m >= bs2 && m < bs2 + 9 && m != i2) a2 = 0.f;
        if (m >= bs3 && m < bs3 + 9 && m != i3) a3 = 0.f;
        s_attn[0][m] = a0;
        s_attn[1][m] = a1;
        s_attn[2][m] = a2;
        s_attn[3][m] = a3;
        sim[0][t] += a0;
        sim[1][t] += a1;
        sim[2][t] += a2;
        sim[3][t] += a3;
      }
    }

    // ===== phase V: vn cosine -> raw += =====
    LOAD_Q4(vn_h);
    sweep((const uint4*)vn_h + (size_t)h * 4 * N_TOK,
          [&](int t, float d0, float d1, float d2, float d3) {
            const bool valid = (t < 3) || (tid < NTAIL);
            if (valid) {
              raw[0][t] += d0;
              raw[1][t] += d1;
              raw[2][t] += d2;
              raw[3][t] += d3;
            }
          });
    __syncthreads();  // combine writes visible; er reads done -> part free

    // ===== attn @ V : f16 V row-major, one uint4 = 8 d per load =====
    {
      const int g2 = tid & 3;      // d-group of 8
      const int slice = tid >> 2;  // 128 slices x 16 m
      const int m0 = slice * 16;
      float acc[4][8];
#pragma unroll
      for (int r = 0; r < 4; r++)
#pragma unroll
        for (int e = 0; e < 8; e++) acc[r][e] = 0.f;
      const _Float16* __restrict__ vb =
          v_h + (size_t)h * N_TOK * HD + g2 * 8;
#pragma unroll
      for (int jj = 0; jj < 4; jj++) {
        const int m = m0 + 4 * ((jj + slice) & 3);  // rotated: <=2-way LDS
        const float4 av0 = *(const float4*)&s_attn[0][m];
        const float4 av1 = *(const float4*)&s_attn[1][m];
        const float4 av2 = *(const float4*)&s_attn[2][m];
        const float4 av3 = *(const float4*)&s_attn[3][m];
        // m can reach 2047; av=0 there. v_h overrun (<=1.5k elems) lands in
        // the adjacent f16 plane (finite values; contribution x0 = 0).
        uint4 vv[4];
#pragma unroll
        for (int mm = 0; mm < 4; mm++) {
          vv[mm] = *(const uint4*)(vb + (size_t)(m + mm) * HD);
        }
#pragma unroll
        for (int mm = 0; mm < 4; mm++) {
          const float a0 = ((const float*)&av0)[mm];
          const float a1 = ((const float*)&av1)[mm];
          const float a2 = ((const float*)&av2)[mm];
          const float a3 = ((const float*)&av3)[mm];
          const unsigned* vp = (const unsigned*)&vv[mm];
#pragma unroll
          for (int e = 0; e < 4; e++) {
            const half2_t hv = u2h(vp[e]);
            const float vx = (float)hv.x, vy = (float)hv.y;
            acc[0][2 * e] += a0 * vx;
            acc[0][2 * e + 1] += a0 * vy;
            acc[1][2 * e] += a1 * vx;
            acc[1][2 * e + 1] += a1 * vy;
            acc[2][2 * e] += a2 * vx;
            acc[2][2 * e + 1] += a2 * vy;
            acc[3][2 * e] += a3 * vx;
            acc[3][2 * e + 1] += a3 * vy;
          }
        }
      }
      // part unit = 33 floats: [e][r] layout -> stage-1 reads are float4
      // over rows; unit index == tid.
      float* pu = part + (size_t)tid * 33;
#pragma unroll
      for (int e = 0; e < 8; e++) {
        const float4 f4 = {acc[0][e], acc[1][e], acc[2][e], acc[3][e]};
        *(float4*)&pu[e * 4] = f4;
      }
    }
    __syncthreads();  // part written

    // ===== stage 1: 256 threads, 16 slices each; (g+4e+4j) covers all banks
    if (tid < 256) {
      const int d = tid & 31, c = tid >> 5;  // c in [0,8)
      const int g = d >> 3, e = d & 7;
      float s0 = 0.f, s1 = 0.f, s2 = 0.f, s3 = 0.f;
#pragma unroll 4
      for (int j = 0; j < 16; j++) {
        const float4 pv =
            *(const float4*)&part[(size_t)((c * 16 + j) * 4 + g) * 33 + e * 4];
        s0 += pv.x; s1 += pv.y; s2 += pv.z; s3 += pv.w;
      }
      // lanes l and l^32 hold c-pair for same d -> combine within wave
      s0 += __shfl_xor(s0, 32, 64);
      s1 += __shfl_xor(s1, 32, 64);
      s2 += __shfl_xor(s2, 32, 64);
      s3 += __shfl_xor(s3, 32, 64);
      if ((tid & 63) < 32) {
        const int w = tid >> 6;  // 0..3
        const float4 f4 = {s0, s1, s2, s3};
        *(float4*)&red[(size_t)(w * 32 + d) * 4] = f4;
      }
    }
    __syncthreads();  // red written

    // ===== stage 2: final 4-way sum + out_x; v_rm copy in parallel =====
    if (tid < 128) {
      const int q = tid >> 5, d = tid & 31;
      const float s = red[(0 * 32 + d) * 4 + q] + red[(1 * 32 + d) * 4 + q] +
                      red[(2 * 32 + d) * 4 + q] + red[(3 * 32 + d) * 4 + q];
      out_x[(size_t)(i0 + q) * 512 + h * 32 + d] = s;
    } else if (tid < 256) {
      const int q = (tid - 128) >> 5, d = (tid - 128) & 31;
      out_x[(size_t)(i0 + q) * 512 + 256 + h * 32 + d] =
          v_rm[((size_t)h * N_TOK + (i0 + q)) * HD + d];
    }
    __syncthreads();  // part/red reads done -> er/s_attn reuse next head
  }

  // ===== sim_round2 epilogue, from registers, 4 rows packed =====
  float lm[4];
#pragma unroll
  for (int r = 0; r < 4; r++) {
    lm[r] = -1e30f;
#pragma unroll
    for (int t = 0; t < NSLOT; t++) {
      if ((t < 3) || (tid < NTAIL)) lm[r] = fmaxf(lm[r], sim[r][t] * 0.125f);
    }
  }
  block_maxN<4>(lm, red);

  float ls[4];
#pragma unroll
  for (int r = 0; r < 4; r++) {
    ls[r] = 0.f;
#pragma unroll
    for (int t = 0; t < NSLOT; t++) {
      const bool valid = (t < 3) || (tid < NTAIL);
      const float e = valid ? __expf(sim[r][t] * 0.125f - lm[r]) : 0.f;
      sim[r][t] = e;
      ls[r] += e;
    }
  }
  block_sumN<4>(ls, red);

  float lms[4];
#pragma unroll
  for (int r = 0; r < 4; r++) {
    const float invS = 1.0f / ls[r];
    lms[r] = 0.f;
#pragma unroll
    for (int t = 0; t < NSLOT; t++) {
      const bool valid = (t < 3) || (tid < NTAIL);
      const float p = sim[r][t] * invS;
      const float mp = (valid && (raw[r][t] * 0.125f > SIM_TH)) ? p : 0.f;
      sim[r][t] = mp;
      lms[r] += mp;
    }
  }
  block_sumN<4>(lms, red);

#pragma unroll
  for (int r = 0; r < 4; r++) {
    const float invMS = 1.0f / (lms[r] + EPSF);
    const int irow = i0 + r;
#pragma unroll
    for (int t = 0; t < NSLOT; t++) {
      const int m = tid + 512 * t;
      if ((t < 3) || (tid < NTAIL)) {
        out_sim[(size_t)irow * N_TOK + m] = sim[r][t] * invMS;
      }
    }
  }
}

// ---------------------------------------------------------------------------
extern "C" void kernel_launch(void* const* d_in, const int* in_sizes, int n_in,
                              void* d_out, int out_size, void* d_ws,
                              size_t ws_size, hipStream_t stream) {
  const float* x_cls = (const float*)d_in[0];
  const float* x_reg = (const float*)d_in[1];
  const float* W_cls = (const float*)d_in[2];
  const float* W_reg = (const float*)d_in[3];

  // ws layout: v_rm fp32, v_h f16 (NOT last: PV overrun must hit finite f16
  // data), then the score planes, then packed W.
  const size_t seg = (size_t)NH * N_TOK * HD;  // 512000 elements
  float* v_rm = (float*)d_ws;
  _Float16* v_h = (_Float16*)(v_rm + seg);
  _Float16* qc_h = v_h + seg;
  _Float16* qr_h = qc_h + seg;
  _Float16* kc_h = qr_h + seg;
  _Float16* kr_h = kc_h + seg;
  _Float16* vn_h = kr_h + seg;
  unsigned* Wp_cls = (unsigned*)(vn_h + seg);  // 98304 uints each
  unsigned* Wp_reg = Wp_cls + 98304;

  dim3 g0(96, 2);
  wpack_kernel<<<g0, 256, 0, stream>>>(W_cls, W_reg, Wp_cls, Wp_reg);

  dim3 g1(500, 2);
  qkv_norm_kernel<<<g1, 256, 0, stream>>>(x_cls, x_reg, Wp_cls, Wp_reg, qc_h,
                                          qr_h, kc_h, kr_h, vn_h, v_rm, v_h);

  float* out_x = (float*)d_out;                  // [2000, 512]
  float* out_sim = out_x + (size_t)N_TOK * 512;  // [2000, 2000]
  attn26_kernel<<<500, 512, 0, stream>>>(qc_h, qr_h, kc_h, kr_h, vn_h, v_rm,
                                         v_h, out_x, out_sim);
}

// Round 6
// 327.085 us; speedup vs baseline: 1.5361x; 1.5361x over previous
//
#include <hip/hip_runtime.h>
#include <math.h>

#define N_TOK 2000
#define NH 8
#define HD 32
#define SCALE 25.0f
#define SIM_TH 0.75f
#define EPSF 1e-8f
#define NSLOT 4   // ceil(2000/512)
#define NTAIL 464 // valid lanes in slot 3: 2000 - 3*512
#define SPAD 2048 // padded score-plane stride

typedef _Float16 half2_t __attribute__((ext_vector_type(2)));

__device__ __forceinline__ unsigned rflu(unsigned u) {
  return (unsigned)__builtin_amdgcn_readfirstlane((int)u);
}
__device__ __forceinline__ half2_t u2h(unsigned u) {
  return __builtin_bit_cast(half2_t, u);
}
__device__ __forceinline__ unsigned h2u(half2_t h) {
  return __builtin_bit_cast(unsigned, h);
}

// f32 += f16x2 . f16x2 (v_dot2_f32_f16; products exact, fp32 accumulate)
__device__ __forceinline__ float fdot2f(unsigned a, unsigned b, float c) {
#if __has_builtin(__builtin_amdgcn_fdot2)
  return __builtin_amdgcn_fdot2(u2h(a), u2h(b), c, false);
#else
  const half2_t ha = u2h(a), hb = u2h(b);
  return c + (float)ha.x * (float)hb.x + (float)ha.y * (float)hb.y;
#endif
}

// packed block reductions over 512 threads (8 waves); red must hold 8*NV
template <int NV>
__device__ __forceinline__ void block_sumN(float* v, float* red) {
#pragma unroll
  for (int off = 32; off > 0; off >>= 1) {
#pragma unroll
    for (int q = 0; q < NV; q++) v[q] += __shfl_xor(v[q], off, 64);
  }
  __syncthreads();
  const int wid = threadIdx.x >> 6;
  if ((threadIdx.x & 63) == 0) {
#pragma unroll
    for (int q = 0; q < NV; q++) red[wid * NV + q] = v[q];
  }
  __syncthreads();
#pragma unroll
  for (int q = 0; q < NV; q++) {
    float s = 0.f;
#pragma unroll
    for (int w = 0; w < 8; w++) s += red[w * NV + q];
    v[q] = s;
  }
}
template <int NV>
__device__ __forceinline__ void block_maxN(float* v, float* red) {
#pragma unroll
  for (int off = 32; off > 0; off >>= 1) {
#pragma unroll
    for (int q = 0; q < NV; q++) v[q] = fmaxf(v[q], __shfl_xor(v[q], off, 64));
  }
  __syncthreads();
  const int wid = threadIdx.x >> 6;
  if ((threadIdx.x & 63) == 0) {
#pragma unroll
    for (int q = 0; q < NV; q++) red[wid * NV + q] = v[q];
  }
  __syncthreads();
#pragma unroll
  for (int q = 0; q < NV; q++) {
    float s = -1e30f;
#pragma unroll
    for (int w = 0; w < 8; w++) s = fmaxf(s, red[w * NV + q]);
    v[q] = s;
  }
}

// load 4 query rows' packed-f16 data. qp0/qp1 -> SGPR (rflu); qp2/qp3 in
// VGPR (SGPR file can't hold 64 uniform words).
#define LOAD_Q4(BUF)                                                      \
  {                                                                       \
    const uint4* __restrict__ qb =                                        \
        (const uint4*)(BUF) + (size_t)h * 4 * N_TOK;                      \
    _Pragma("unroll") for (int gg = 0; gg < 4; gg++) {                    \
      const uint4 a0 = qb[gg * N_TOK + i0];                               \
      const uint4 a1 = qb[gg * N_TOK + i1];                               \
      const uint4 a2 = qb[gg * N_TOK + i2];                               \
      const uint4 a3 = qb[gg * N_TOK + i3];                               \
      qp0[4 * gg + 0] = rflu(a0.x); qp0[4 * gg + 1] = rflu(a0.y);         \
      qp0[4 * gg + 2] = rflu(a0.z); qp0[4 * gg + 3] = rflu(a0.w);         \
      qp1[4 * gg + 0] = rflu(a1.x); qp1[4 * gg + 1] = rflu(a1.y);         \
      qp1[4 * gg + 2] = rflu(a1.z); qp1[4 * gg + 3] = rflu(a1.w);         \
      qp2[4 * gg + 0] = a2.x; qp2[4 * gg + 1] = a2.y;                     \
      qp2[4 * gg + 2] = a2.z; qp2[4 * gg + 3] = a2.w;                     \
      qp3[4 * gg + 0] = a3.x; qp3[4 * gg + 1] = a3.y;                     \
      qp3[4 * gg + 2] = a3.z; qp3[4 * gg + 3] = a3.w;                     \
    }                                                                     \
  }

#define DOT4(KW, QP, D)                                                   \
  D = fdot2f((KW).x, QP[4 * g_ + 0], D);                                  \
  D = fdot2f((KW).y, QP[4 * g_ + 1], D);                                  \
  D = fdot2f((KW).z, QP[4 * g_ + 2], D);                                  \
  D = fdot2f((KW).w, QP[4 * g_ + 3], D);

// ---------------------------------------------------------------------------
// Kernel 0: pack W fp32 [256][768] into f16 pair-quads Wq[k/8][768].
// grid = (96, 2), block = 256
// ---------------------------------------------------------------------------
__global__ __launch_bounds__(256) void wpack_kernel(
    const float* __restrict__ W_cls, const float* __restrict__ W_reg,
    unsigned* __restrict__ Wp_cls, unsigned* __restrict__ Wp_reg) {
  const int idx = blockIdx.x * 256 + threadIdx.x;
  const int kq = idx / 768, c = idx % 768;
  const float* __restrict__ W = blockIdx.y ? W_reg : W_cls;
  uint4* __restrict__ Wq = (uint4*)(blockIdx.y ? Wp_reg : Wp_cls);
  uint4 o;
  o.x = h2u((half2_t){(_Float16)W[(8 * kq + 0) * 768 + c],
                      (_Float16)W[(8 * kq + 1) * 768 + c]});
  o.y = h2u((half2_t){(_Float16)W[(8 * kq + 2) * 768 + c],
                      (_Float16)W[(8 * kq + 3) * 768 + c]});
  o.z = h2u((half2_t){(_Float16)W[(8 * kq + 4) * 768 + c],
                      (_Float16)W[(8 * kq + 5) * 768 + c]});
  o.w = h2u((half2_t){(_Float16)W[(8 * kq + 6) * 768 + c],
                      (_Float16)W[(8 * kq + 7) * 768 + c]});
  Wq[idx] = o;
}

// ---------------------------------------------------------------------------
// Kernel 1: QKV projection via f16 W + fdot2, 4 rows/block (measured best).
// grid = (500, 2), block = 256
// ---------------------------------------------------------------------------
__global__ __launch_bounds__(256) void qkv_norm_kernel(
    const float* __restrict__ x_cls, const float* __restrict__ x_reg,
    const unsigned* __restrict__ Wp_cls, const unsigned* __restrict__ Wp_reg,
    _Float16* __restrict__ qc_h, _Float16* __restrict__ qr_h,
    _Float16* __restrict__ kc_h, _Float16* __restrict__ kr_h,
    _Float16* __restrict__ vn_h, float* __restrict__ v_rm,
    _Float16* __restrict__ v_h) {
  __shared__ unsigned xs_p[4][128];
  __shared__ float res[4][768];
  __shared__ float inv_norm[96];

  const int n0 = blockIdx.x * 4;
  const int which = blockIdx.y;
  const int tid = threadIdx.x;
  const float* __restrict__ x = which ? x_reg : x_cls;
  const uint4* __restrict__ Wq = (const uint4*)(which ? Wp_reg : Wp_cls);

  if (tid < 128) {
#pragma unroll
    for (int r = 0; r < 4; r++) {
      const float2 xv = ((const float2*)x)[(size_t)(n0 + r) * 128 + tid];
      xs_p[r][tid] = h2u((half2_t){(_Float16)xv.x, (_Float16)xv.y});
    }
  }
  __syncthreads();

  float acc[4][3];
#pragma unroll
  for (int r = 0; r < 4; r++) acc[r][0] = acc[r][1] = acc[r][2] = 0.f;

#pragma unroll 2
  for (int kq = 0; kq < 32; kq++) {
    const uint4 w0 = Wq[kq * 768 + tid];
    const uint4 w1 = Wq[kq * 768 + tid + 256];
    const uint4 w2 = Wq[kq * 768 + tid + 512];
#pragma unroll
    for (int r = 0; r < 4; r++) {
      const uint4 xp = *(const uint4*)&xs_p[r][kq * 4];
      acc[r][0] = fdot2f(w0.x, xp.x, acc[r][0]);
      acc[r][0] = fdot2f(w0.y, xp.y, acc[r][0]);
      acc[r][0] = fdot2f(w0.z, xp.z, acc[r][0]);
      acc[r][0] = fdot2f(w0.w, xp.w, acc[r][0]);
      acc[r][1] = fdot2f(w1.x, xp.x, acc[r][1]);
      acc[r][1] = fdot2f(w1.y, xp.y, acc[r][1]);
      acc[r][1] = fdot2f(w1.z, xp.z, acc[r][1]);
      acc[r][1] = fdot2f(w1.w, xp.w, acc[r][1]);
      acc[r][2] = fdot2f(w2.x, xp.x, acc[r][2]);
      acc[r][2] = fdot2f(w2.y, xp.y, acc[r][2]);
      acc[r][2] = fdot2f(w2.z, xp.z, acc[r][2]);
      acc[r][2] = fdot2f(w2.w, xp.w, acc[r][2]);
    }
  }
#pragma unroll
  for (int r = 0; r < 4; r++) {
    res[r][tid] = acc[r][0];
    res[r][tid + 256] = acc[r][1];
    res[r][tid + 512] = acc[r][2];
  }
  __syncthreads();

  if (tid < 96) {
    const int r = tid / 24, grp = tid % 24;
    float ss = 0.f;
#pragma unroll
    for (int d = 0; d < HD; d++) {
      const float v = res[r][grp * 32 + d];
      ss += v * v;
    }
    inv_norm[tid] = 1.0f / (sqrtf(ss) + EPSF);
  }
  __syncthreads();

#pragma unroll
  for (int j = 0; j < 3; j++) {
    const int c = tid + j * 256;
    const int qkv = c >> 8, grp = c >> 5;
    const int h = grp & 7, d = c & 31;
    const int gg = d >> 3, dd = d & 7;
#pragma unroll
    for (int r = 0; r < 4; r++) {
      const int n = n0 + r;
      const float val = res[r][c];
      const float nval = val * inv_norm[r * 24 + grp];
      const size_t fi = ((size_t)(h * 4 + gg) * N_TOK + n) * 8 + dd;
      if (qkv == 0) {
        (which ? qr_h : qc_h)[fi] = (_Float16)nval;
      } else if (qkv == 1) {
        (which ? kr_h : kc_h)[fi] = (_Float16)nval;
      } else if (which == 0) {
        v_rm[(h * N_TOK + n) * HD + d] = val;
        vn_h[fi] = (_Float16)nval;
        v_h[((size_t)h * N_TOK + n) * HD + d] = (_Float16)val;
      }
    }
  }
}

// ---------------------------------------------------------------------------
// Kernel 2 (r26 -> r27): design INTO the 128-VGPR cap. r24/r25/r26 proved:
// (a) 512t blocks get exactly 128 VGPRs regardless of __launch_bounds__
// variant (the hint can't raise the backend's 4-wave/SIMD allocation
// target); (b) the 8-wave block DOES deliver ~7.3 resident waves/CU (22.9%
// occupancy, r24). Old body needed ~160 VGPRs -> 2.2 KB/thread spills ->
// 586 MB scratch writes. Diet to fit 128: (1) 3-stage -> 2-stage sweep
// (drop kc_, -16 VGPR): at ~7 waves/CU the shared memory pipe is
// oversubscribed (demand ~7x20 B/cy vs ~30 B/cy/CU supply) so one-ahead
// prefetch suffices; (2) raw accumulator -> LDS f32 plane raw_lds[4][2048]
// (-16 VGPR, +32 KB LDS -> 132 KB total, fine at the 1-block/CU design
// point). Estimated peak ~115 VGPR. Keeps 500 blocks x 8 waves = 4000
// waves (r21's count) with TQ=4's halved 2.0 GB L2 stream.
// grid = 500, block = 512
// ---------------------------------------------------------------------------
__global__ __launch_bounds__(512) void attn27_kernel(
    const _Float16* __restrict__ qc_h, const _Float16* __restrict__ qr_h,
    const _Float16* __restrict__ kc_h, const _Float16* __restrict__ kr_h,
    const _Float16* __restrict__ vn_h, const float* __restrict__ v_rm,
    const _Float16* __restrict__ v_h,
    float* __restrict__ out_x, float* __restrict__ out_sim) {
  __shared__ float s_attn[4][SPAD];   // 32 KB f32; tails stay 0 for PV
  __shared__ float s_union[16896];    // 67.6 KB: er f16 [4][SPAD] / part
  __shared__ float raw_lds[4 * SPAD]; // 32 KB: vn-cosine row sums (8 heads)
  __shared__ float red[512];          // 2 KB: stage-2 + block reductions

  _Float16* __restrict__ er_h = (_Float16*)s_union;  // plane r at r*SPAD
  float* __restrict__ part = s_union;  // 512 units x 33 floats ([e][r] x8 +1)

  const int tid = threadIdx.x;
  const int i0 = blockIdx.x * 4;
  const int i1 = i0 + 1, i2 = i0 + 2, i3 = i0 + 3;
  const int bs0 = (i0 / 10) * 10, bs1 = (i1 / 10) * 10;
  const int bs2 = (i2 / 10) * 10, bs3 = (i3 / 10) * 10;

  float sim[4][NSLOT];
#pragma unroll
  for (int r = 0; r < 4; r++) {
#pragma unroll
    for (int t = 0; t < NSLOT; t++) sim[r][t] = 0.f;
  }
  if (tid < SPAD - N_TOK) {
#pragma unroll
    for (int r = 0; r < 4; r++) s_attn[r][N_TOK + tid] = 0.f;
  }
#pragma unroll
  for (int k = 0; k < 16; k++) raw_lds[k * 512 + tid] = 0.f;
  __syncthreads();

  unsigned qp0[16], qp1[16], qp2[16], qp3[16];

  // 2-stage pipelined sweep over 4 slots of 512: load t+1 during t compute.
  auto sweep = [&](const uint4* __restrict__ kt4, auto&& emit) {
    uint4 ka[4], kb[4];
#pragma unroll
    for (int g_ = 0; g_ < 4; g_++) ka[g_] = kt4[g_ * N_TOK + tid];  // t=0
#pragma unroll
    for (int t = 0; t < NSLOT; t++) {
      if (t < NSLOT - 1) {  // prefetch t+1 (clamp tail lanes)
        const int m1 = tid + 512 * (t + 1);
        const bool v1 = (t + 1 < 3) || (tid < NTAIL);
        const int mc1 = v1 ? m1 : (N_TOK - 1);
#pragma unroll
        for (int g_ = 0; g_ < 4; g_++) kb[g_] = kt4[g_ * N_TOK + mc1];
      }
      float d0 = 0.f, d1 = 0.f, d2 = 0.f, d3 = 0.f;
#pragma unroll
      for (int g_ = 0; g_ < 4; g_++) {
        DOT4(ka[g_], qp0, d0);
        DOT4(ka[g_], qp1, d1);
        DOT4(ka[g_], qp2, d2);
        DOT4(ka[g_], qp3, d3);
      }
      emit(t, d0, d1, d2, d3);
#pragma unroll
      for (int g_ = 0; g_ < 4; g_++) ka[g_] = kb[g_];
    }
  };

  for (int hh = 0; hh < NH; hh++) {
    const int h = (blockIdx.x + hh) & 7;  // XCD-local head schedule

    float sums[8];  // cls x4, reg x4
#pragma unroll
    for (int q = 0; q < 8; q++) sums[q] = 0.f;

    // ===== phase C: cls scores -> e = exp(s-25) -> s_attn (unnormalized) ===
    LOAD_Q4(qc_h);
    sweep((const uint4*)kc_h + (size_t)h * 4 * N_TOK,
          [&](int t, float d0, float d1, float d2, float d3) {
            const int m = tid + 512 * t;
            const bool valid = (t < 3) || (tid < NTAIL);
            const float e0 = valid ? __expf(d0 * SCALE - SCALE) : 0.f;
            const float e1 = valid ? __expf(d1 * SCALE - SCALE) : 0.f;
            const float e2 = valid ? __expf(d2 * SCALE - SCALE) : 0.f;
            const float e3 = valid ? __expf(d3 * SCALE - SCALE) : 0.f;
            sums[0] += e0; sums[1] += e1; sums[2] += e2; sums[3] += e3;
            if (valid) {
              s_attn[0][m] = e0;
              s_attn[1][m] = e1;
              s_attn[2][m] = e2;
              s_attn[3][m] = e3;
            }
          });

    // ===== phase R: reg scores -> er (f16) — NO reduction between phases ===
    LOAD_Q4(qr_h);
    sweep((const uint4*)kr_h + (size_t)h * 4 * N_TOK,
          [&](int t, float d0, float d1, float d2, float d3) {
            const int m = tid + 512 * t;
            const bool valid = (t < 3) || (tid < NTAIL);
            const float e0 = valid ? __expf(d0 * SCALE - SCALE) : 0.f;
            const float e1 = valid ? __expf(d1 * SCALE - SCALE) : 0.f;
            const float e2 = valid ? __expf(d2 * SCALE - SCALE) : 0.f;
            const float e3 = valid ? __expf(d3 * SCALE - SCALE) : 0.f;
            sums[4] += e0; sums[5] += e1; sums[6] += e2; sums[7] += e3;
            if (valid) {
              er_h[m] = (_Float16)e0;
              er_h[SPAD + m] = (_Float16)e1;
              er_h[2 * SPAD + m] = (_Float16)e2;
              er_h[3 * SPAD + m] = (_Float16)e3;
            }
          });

    // ===== ONE packed reduction for all 8 softmax sums =====
    block_sumN<8>(sums, red);
    const float nc0 = 0.5f / sums[0], nc1 = 0.5f / sums[1];
    const float nc2 = 0.5f / sums[2], nc3 = 0.5f / sums[3];
    const float nr0 = 0.5f / sums[4], nr1 = 0.5f / sums[5];
    const float nr2 = 0.5f / sums[6], nr3 = 0.5f / sums[7];

    // ===== combine, mask (per-row decade), sim += =====
#pragma unroll
    for (int t = 0; t < NSLOT; t++) {
      const int m = tid + 512 * t;
      if ((t < 3) || (tid < NTAIL)) {
        float a0 = s_attn[0][m] * nc0 + (float)er_h[m] * nr0;
        float a1 = s_attn[1][m] * nc1 + (float)er_h[SPAD + m] * nr1;
        float a2 = s_attn[2][m] * nc2 + (float)er_h[2 * SPAD + m] * nr2;
        float a3 = s_attn[3][m] * nc3 + (float)er_h[3 * SPAD + m] * nr3;
        if (m >= bs0 && m < bs0 + 9 && m != i0) a0 = 0.f;
        if (m >= bs1 && m < bs1 + 9 && m != i1) a1 = 0.f;
        if (m >= bs2 && m < bs2 + 9 && m != i2) a2 = 0.f;
        if (m >= bs3 && m < bs3 + 9 && m != i3) a3 = 0.f;
        s_attn[0][m] = a0;
        s_attn[1][m] = a1;
        s_attn[2][m] = a2;
        s_attn[3][m] = a3;
        sim[0][t] += a0;
        sim[1][t] += a1;
        sim[2][t] += a2;
        sim[3][t] += a3;
      }
    }

    // ===== phase V: vn cosine -> raw_lds += (per-thread-unique m, no race) =
    LOAD_Q4(vn_h);
    sweep((const uint4*)vn_h + (size_t)h * 4 * N_TOK,
          [&](int t, float d0, float d1, float d2, float d3) {
            const int m = tid + 512 * t;
            const bool valid = (t < 3) || (tid < NTAIL);
            if (valid) {
              raw_lds[m] += d0;
              raw_lds[SPAD + m] += d1;
              raw_lds[2 * SPAD + m] += d2;
              raw_lds[3 * SPAD + m] += d3;
            }
          });
    __syncthreads();  // combine writes visible; er reads done -> part free

    // ===== attn @ V : f16 V row-major, one uint4 = 8 d per load =====
    {
      const int g2 = tid & 3;      // d-group of 8
      const int slice = tid >> 2;  // 128 slices x 16 m
      const int m0 = slice * 16;
      float acc[4][8];
#pragma unroll
      for (int r = 0; r < 4; r++)
#pragma unroll
        for (int e = 0; e < 8; e++) acc[r][e] = 0.f;
      const _Float16* __restrict__ vb =
          v_h + (size_t)h * N_TOK * HD + g2 * 8;
#pragma unroll
      for (int jj = 0; jj < 4; jj++) {
        const int m = m0 + 4 * ((jj + slice) & 3);  // rotated: <=2-way LDS
        const float4 av0 = *(const float4*)&s_attn[0][m];
        const float4 av1 = *(const float4*)&s_attn[1][m];
        const float4 av2 = *(const float4*)&s_attn[2][m];
        const float4 av3 = *(const float4*)&s_attn[3][m];
        // m can reach 2047; av=0 there. v_h overrun (<=1.5k elems) lands in
        // the adjacent f16 plane (finite values; contribution x0 = 0).
        uint4 vv[4];
#pragma unroll
        for (int mm = 0; mm < 4; mm++) {
          vv[mm] = *(const uint4*)(vb + (size_t)(m + mm) * HD);
        }
#pragma unroll
        for (int mm = 0; mm < 4; mm++) {
          const float a0 = ((const float*)&av0)[mm];
          const float a1 = ((const float*)&av1)[mm];
          const float a2 = ((const float*)&av2)[mm];
          const float a3 = ((const float*)&av3)[mm];
          const unsigned* vp = (const unsigned*)&vv[mm];
#pragma unroll
          for (int e = 0; e < 4; e++) {
            const half2_t hv = u2h(vp[e]);
            const float vx = (float)hv.x, vy = (float)hv.y;
            acc[0][2 * e] += a0 * vx;
            acc[0][2 * e + 1] += a0 * vy;
            acc[1][2 * e] += a1 * vx;
            acc[1][2 * e + 1] += a1 * vy;
            acc[2][2 * e] += a2 * vx;
            acc[2][2 * e + 1] += a2 * vy;
            acc[3][2 * e] += a3 * vx;
            acc[3][2 * e + 1] += a3 * vy;
          }
        }
      }
      // part unit = 33 floats: [e][r] layout -> stage-1 reads are float4
      // over rows; unit index == tid.
      float* pu = part + (size_t)tid * 33;
#pragma unroll
      for (int e = 0; e < 8; e++) {
        const float4 f4 = {acc[0][e], acc[1][e], acc[2][e], acc[3][e]};
        *(float4*)&pu[e * 4] = f4;
      }
    }
    __syncthreads();  // part written

    // ===== stage 1: 256 threads, 16 slices each; (g+4e+4j) covers all banks
    if (tid < 256) {
      const int d = tid & 31, c = tid >> 5;  // c in [0,8)
      const int g = d >> 3, e = d & 7;
      float s0 = 0.f, s1 = 0.f, s2 = 0.f, s3 = 0.f;
#pragma unroll 4
      for (int j = 0; j < 16; j++) {
        const float4 pv =
            *(const float4*)&part[(size_t)((c * 16 + j) * 4 + g) * 33 + e * 4];
        s0 += pv.x; s1 += pv.y; s2 += pv.z; s3 += pv.w;
      }
      // lanes l and l^32 hold c-pair for same d -> combine within wave
      s0 += __shfl_xor(s0, 32, 64);
      s1 += __shfl_xor(s1, 32, 64);
      s2 += __shfl_xor(s2, 32, 64);
      s3 += __shfl_xor(s3, 32, 64);
      if ((tid & 63) < 32) {
        const int w = tid >> 6;  // 0..3
        const float4 f4 = {s0, s1, s2, s3};
        *(float4*)&red[(size_t)(w * 32 + d) * 4] = f4;
      }
    }
    __syncthreads();  // red written

    // ===== stage 2: final 4-way sum + out_x; v_rm copy in parallel =====
    if (tid < 128) {
      const int q = tid >> 5, d = tid & 31;
      const float s = red[(0 * 32 + d) * 4 + q] + red[(1 * 32 + d) * 4 + q] +
                      red[(2 * 32 + d) * 4 + q] + red[(3 * 32 + d) * 4 + q];
      out_x[(size_t)(i0 + q) * 512 + h * 32 + d] = s;
    } else if (tid < 256) {
      const int q = (tid - 128) >> 5, d = (tid - 128) & 31;
      out_x[(size_t)(i0 + q) * 512 + 256 + h * 32 + d] =
          v_rm[((size_t)h * N_TOK + (i0 + q)) * HD + d];
    }
    __syncthreads();  // part/red reads done -> er/s_attn reuse next head
  }

  // ===== sim_round2 epilogue: sim from registers, raw from LDS =====
  float lm[4];
#pragma unroll
  for (int r = 0; r < 4; r++) {
    lm[r] = -1e30f;
#pragma unroll
    for (int t = 0; t < NSLOT; t++) {
      if ((t < 3) || (tid < NTAIL)) lm[r] = fmaxf(lm[r], sim[r][t] * 0.125f);
    }
  }
  block_maxN<4>(lm, red);

  float ls[4];
#pragma unroll
  for (int r = 0; r < 4; r++) {
    ls[r] = 0.f;
#pragma unroll
    for (int t = 0; t < NSLOT; t++) {
      const bool valid = (t < 3) || (tid < NTAIL);
      const float e = valid ? __expf(sim[r][t] * 0.125f - lm[r]) : 0.f;
      sim[r][t] = e;
      ls[r] += e;
    }
  }
  block_sumN<4>(ls, red);

  float lms[4];
#pragma unroll
  for (int r = 0; r < 4; r++) {
    const float invS = 1.0f / ls[r];
    lms[r] = 0.f;
#pragma unroll
    for (int t = 0; t < NSLOT; t++) {
      const int m = tid + 512 * t;
      const bool valid = (t < 3) || (tid < NTAIL);
      const float p = sim[r][t] * invS;
      const float rw = valid ? raw_lds[r * SPAD + m] : 0.f;
      const float mp = (valid && (rw * 0.125f > SIM_TH)) ? p : 0.f;
      sim[r][t] = mp;
      lms[r] += mp;
    }
  }
  block_sumN<4>(lms, red);

#pragma unroll
  for (int r = 0; r < 4; r++) {
    const float invMS = 1.0f / (lms[r] + EPSF);
    const int irow = i0 + r;
#pragma unroll
    for (int t = 0; t < NSLOT; t++) {
      const int m = tid + 512 * t;
      if ((t < 3) || (tid < NTAIL)) {
        out_sim[(size_t)irow * N_TOK + m] = sim[r][t] * invMS;
      }
    }
  }
}

// ---------------------------------------------------------------------------
extern "C" void kernel_launch(void* const* d_in, const int* in_sizes, int n_in,
                              void* d_out, int out_size, void* d_ws,
                              size_t ws_size, hipStream_t stream) {
  const float* x_cls = (const float*)d_in[0];
  const float* x_reg = (const float*)d_in[1];
  const float* W_cls = (const float*)d_in[2];
  const float* W_reg = (const float*)d_in[3];

  // ws layout: v_rm fp32, v_h f16 (NOT last: PV overrun must hit finite f16
  // data), then the score planes, then packed W.
  const size_t seg = (size_t)NH * N_TOK * HD;  // 512000 elements
  float* v_rm = (float*)d_ws;
  _Float16* v_h = (_Float16*)(v_rm + seg);
  _Float16* qc_h = v_h + seg;
  _Float16* qr_h = qc_h + seg;
  _Float16* kc_h = qr_h + seg;
  _Float16* kr_h = kc_h + seg;
  _Float16* vn_h = kr_h + seg;
  unsigned* Wp_cls = (unsigned*)(vn_h + seg);  // 98304 uints each
  unsigned* Wp_reg = Wp_cls + 98304;

  dim3 g0(96, 2);
  wpack_kernel<<<g0, 256, 0, stream>>>(W_cls, W_reg, Wp_cls, Wp_reg);

  dim3 g1(500, 2);
  qkv_norm_kernel<<<g1, 256, 0, stream>>>(x_cls, x_reg, Wp_cls, Wp_reg, qc_h,
                                          qr_h, kc_h, kr_h, vn_h, v_rm, v_h);

  float* out_x = (float*)d_out;                  // [2000, 512]
  float* out_sim = out_x + (size_t)N_TOK * 512;  // [2000, 2000]
  attn27_kernel<<<500, 512, 0, stream>>>(qc_h, qr_h, kc_h, kr_h, vn_h, v_rm,
                                         v_h, out_x, out_sim);
}

// Round 7
// 294.129 us; speedup vs baseline: 1.7082x; 1.1120x over previous
//
#include <hip/hip_runtime.h>
#include <math.h>

#define N_TOK 2000
#define NH 8
#define HD 32
#define SCALE 25.0f
#define SIM_TH 0.75f
#define EPSF 1e-8f
#define NSLOT 8   // ceil(2000/256)
#define NTAIL 208 // valid lanes in slot 7: 2000 - 7*256
#define SPAD 2048 // padded s_attn stride

typedef _Float16 half2_t __attribute__((ext_vector_type(2)));

__device__ __forceinline__ unsigned rflu(unsigned u) {
  return (unsigned)__builtin_amdgcn_readfirstlane((int)u);
}
__device__ __forceinline__ half2_t u2h(unsigned u) {
  return __builtin_bit_cast(half2_t, u);
}
__device__ __forceinline__ unsigned h2u(half2_t h) {
  return __builtin_bit_cast(unsigned, h);
}

// f32 += f16x2 . f16x2 (v_dot2_f32_f16; products exact, fp32 accumulate)
__device__ __forceinline__ float fdot2f(unsigned a, unsigned b, float c) {
#if __has_builtin(__builtin_amdgcn_fdot2)
  return __builtin_amdgcn_fdot2(u2h(a), u2h(b), c, false);
#else
  const half2_t ha = u2h(a), hb = u2h(b);
  return c + (float)ha.x * (float)hb.x + (float)ha.y * (float)hb.y;
#endif
}

__device__ __forceinline__ float block_max256(float v, float* red) {
#pragma unroll
  for (int off = 32; off > 0; off >>= 1) v = fmaxf(v, __shfl_xor(v, off, 64));
  __syncthreads();
  if ((threadIdx.x & 63) == 0) red[threadIdx.x >> 6] = v;
  __syncthreads();
  return fmaxf(fmaxf(red[0], red[1]), fmaxf(red[2], red[3]));
}
__device__ __forceinline__ float block_sum256(float v, float* red) {
#pragma unroll
  for (int off = 32; off > 0; off >>= 1) v += __shfl_xor(v, off, 64);
  __syncthreads();
  if ((threadIdx.x & 63) == 0) red[threadIdx.x >> 6] = v;
  __syncthreads();
  return (red[0] + red[1]) + (red[2] + red[3]);
}
// one packed block reduction for 4 sums (2 syncs total instead of 8)
__device__ __forceinline__ void block_sum4(float* v, float* red16) {
#pragma unroll
  for (int off = 32; off > 0; off >>= 1) {
#pragma unroll
    for (int q = 0; q < 4; q++) v[q] += __shfl_xor(v[q], off, 64);
  }
  __syncthreads();
  const int wid = threadIdx.x >> 6;
  if ((threadIdx.x & 63) == 0) {
#pragma unroll
    for (int q = 0; q < 4; q++) red16[wid * 4 + q] = v[q];
  }
  __syncthreads();
#pragma unroll
  for (int q = 0; q < 4; q++) {
    v[q] = (red16[q] + red16[4 + q]) + (red16[8 + q] + red16[12 + q]);
  }
}

// load a query pair's packed-f16 row into uniform uints (SGPRs)
#define LOAD_QPAIR(BUF)                                                   \
  {                                                                       \
    const uint4* __restrict__ qb = (const uint4*)(BUF) + (size_t)h * 4 * N_TOK; \
    _Pragma("unroll") for (int gg = 0; gg < 4; gg++) {                    \
      const uint4 a0 = qb[gg * N_TOK + i0];                               \
      const uint4 a1 = qb[gg * N_TOK + i1];                               \
      qp0[4 * gg + 0] = rflu(a0.x); qp0[4 * gg + 1] = rflu(a0.y);         \
      qp0[4 * gg + 2] = rflu(a0.z); qp0[4 * gg + 3] = rflu(a0.w);         \
      qp1[4 * gg + 0] = rflu(a1.x); qp1[4 * gg + 1] = rflu(a1.y);         \
      qp1[4 * gg + 2] = rflu(a1.z); qp1[4 * gg + 3] = rflu(a1.w);         \
    }                                                                     \
  }

// ---------------------------------------------------------------------------
// Kernel 0: pack W fp32 [256][768] into f16 pair-quads Wq[k/8][768].
// grid = (96, 2), block = 256
// ---------------------------------------------------------------------------
__global__ __launch_bounds__(256) void wpack_kernel(
    const float* __restrict__ W_cls, const float* __restrict__ W_reg,
    unsigned* __restrict__ Wp_cls, unsigned* __restrict__ Wp_reg) {
  const int idx = blockIdx.x * 256 + threadIdx.x;
  const int kq = idx / 768, c = idx % 768;
  const float* __restrict__ W = blockIdx.y ? W_reg : W_cls;
  uint4* __restrict__ Wq = (uint4*)(blockIdx.y ? Wp_reg : Wp_cls);
  uint4 o;
  o.x = h2u((half2_t){(_Float16)W[(8 * kq + 0) * 768 + c],
                      (_Float16)W[(8 * kq + 1) * 768 + c]});
  o.y = h2u((half2_t){(_Float16)W[(8 * kq + 2) * 768 + c],
                      (_Float16)W[(8 * kq + 3) * 768 + c]});
  o.z = h2u((half2_t){(_Float16)W[(8 * kq + 4) * 768 + c],
                      (_Float16)W[(8 * kq + 5) * 768 + c]});
  o.w = h2u((half2_t){(_Float16)W[(8 * kq + 6) * 768 + c],
                      (_Float16)W[(8 * kq + 7) * 768 + c]});
  Wq[idx] = o;
}

// ---------------------------------------------------------------------------
// Kernel 1 (r27 -> r28): QKV projection, 4 -> 8 rows/block. Theory: at 4
// rows each block re-reads the full W panel (393 KB L2) -> 393 MB total W
// traffic for a 786 KB matrix, 12 W-loads per 48 fdot2. 8 rows halves W
// traffic (~197 MB) and doubles arithmetic intensity per W fetch. Regs:
// acc[8][3]=24 + 12 W uint4 ~= 90 peak, fits the 128 cap at 256t. LDS 29 KB.
// grid = (250, 2), block = 256
// ---------------------------------------------------------------------------
__global__ __launch_bounds__(256) void qkv_norm_kernel(
    const float* __restrict__ x_cls, const float* __restrict__ x_reg,
    const unsigned* __restrict__ Wp_cls, const unsigned* __restrict__ Wp_reg,
    _Float16* __restrict__ qc_h, _Float16* __restrict__ qr_h,
    _Float16* __restrict__ kc_h, _Float16* __restrict__ kr_h,
    _Float16* __restrict__ vn_h, float* __restrict__ v_rm,
    _Float16* __restrict__ v_h) {
  __shared__ unsigned xs_p[8][128];
  __shared__ float res[8][768];
  __shared__ float inv_norm[192];

  const int n0 = blockIdx.x * 8;
  const int which = blockIdx.y;
  const int tid = threadIdx.x;
  const float* __restrict__ x = which ? x_reg : x_cls;
  const uint4* __restrict__ Wq = (const uint4*)(which ? Wp_reg : Wp_cls);

  if (tid < 128) {
#pragma unroll
    for (int r = 0; r < 8; r++) {
      const float2 xv = ((const float2*)x)[(size_t)(n0 + r) * 128 + tid];
      xs_p[r][tid] = h2u((half2_t){(_Float16)xv.x, (_Float16)xv.y});
    }
  }
  __syncthreads();

  float acc[8][3];
#pragma unroll
  for (int r = 0; r < 8; r++) acc[r][0] = acc[r][1] = acc[r][2] = 0.f;

  for (int kq = 0; kq < 32; kq++) {
    const uint4 w0 = Wq[kq * 768 + tid];
    const uint4 w1 = Wq[kq * 768 + tid + 256];
    const uint4 w2 = Wq[kq * 768 + tid + 512];
#pragma unroll
    for (int r = 0; r < 8; r++) {
      const uint4 xp = *(const uint4*)&xs_p[r][kq * 4];
      acc[r][0] = fdot2f(w0.x, xp.x, acc[r][0]);
      acc[r][0] = fdot2f(w0.y, xp.y, acc[r][0]);
      acc[r][0] = fdot2f(w0.z, xp.z, acc[r][0]);
      acc[r][0] = fdot2f(w0.w, xp.w, acc[r][0]);
      acc[r][1] = fdot2f(w1.x, xp.x, acc[r][1]);
      acc[r][1] = fdot2f(w1.y, xp.y, acc[r][1]);
      acc[r][1] = fdot2f(w1.z, xp.z, acc[r][1]);
      acc[r][1] = fdot2f(w1.w, xp.w, acc[r][1]);
      acc[r][2] = fdot2f(w2.x, xp.x, acc[r][2]);
      acc[r][2] = fdot2f(w2.y, xp.y, acc[r][2]);
      acc[r][2] = fdot2f(w2.z, xp.z, acc[r][2]);
      acc[r][2] = fdot2f(w2.w, xp.w, acc[r][2]);
    }
  }
#pragma unroll
  for (int r = 0; r < 8; r++) {
    res[r][tid] = acc[r][0];
    res[r][tid + 256] = acc[r][1];
    res[r][tid + 512] = acc[r][2];
  }
  __syncthreads();

  if (tid < 192) {
    const int r = tid / 24, grp = tid % 24;
    float ss = 0.f;
#pragma unroll
    for (int d = 0; d < HD; d++) {
      const float v = res[r][grp * 32 + d];
      ss += v * v;
    }
    inv_norm[tid] = 1.0f / (sqrtf(ss) + EPSF);
  }
  __syncthreads();

#pragma unroll
  for (int j = 0; j < 3; j++) {
    const int c = tid + j * 256;
    const int qkv = c >> 8, grp = c >> 5;
    const int h = grp & 7, d = c & 31;
    const int gg = d >> 3, dd = d & 7;
#pragma unroll
    for (int r = 0; r < 8; r++) {
      const int n = n0 + r;
      const float val = res[r][c];
      const float nval = val * inv_norm[r * 24 + grp];
      const size_t fi = ((size_t)(h * 4 + gg) * N_TOK + n) * 8 + dd;
      if (qkv == 0) {
        (which ? qr_h : qc_h)[fi] = (_Float16)nval;
      } else if (qkv == 1) {
        (which ? kr_h : kc_h)[fi] = (_Float16)nval;
      } else if (which == 0) {
        v_rm[(h * N_TOK + n) * HD + d] = val;
        vn_h[fi] = (_Float16)nval;
        v_h[((size_t)h * N_TOK + n) * HD + d] = (_Float16)val;
      }
    }
  }
}

// ---------------------------------------------------------------------------
// Kernel 2 (r28): EXACT revert to the session-best r21 structure (measured
// 234-236 us, 5 dispatches). The TQ=4 arc (r22-r27) is abandoned: per-wave
// stream rate is set by the serial per-wave compute/latency chain (TQ=4
// doubles VALU per byte -> halves load issue rate), occupancy is pinned at
// ~7 waves/CU across all configs, and deeper prefetch was already neutral
// (prior session r19). TQ=2, f16 score streams, 3-stage pipelined sweeps,
// deferred normalization (one packed block_sum4 per head), f16 row-major V
// PV with rotated conflict-free LDS reads, fp32 er, register sim/raw slots,
// XCD head rotation. grid = 1000, block = 256
// ---------------------------------------------------------------------------
__global__ __launch_bounds__(256) void attn28_kernel(
    const _Float16* __restrict__ qc_h, const _Float16* __restrict__ qr_h,
    const _Float16* __restrict__ kc_h, const _Float16* __restrict__ kr_h,
    const _Float16* __restrict__ vn_h, const float* __restrict__ v_rm,
    const _Float16* __restrict__ v_h,
    float* __restrict__ out_x, float* __restrict__ out_sim) {
  __shared__ float s_attn[2][SPAD];  // 16 KB; tails stay 0 for PV
  __shared__ float s_union[4608];    // 18.4 KB: er[2][2000] / part (str 17)
  __shared__ float red[16];

  float* __restrict__ s_er = s_union;
  float* __restrict__ part = s_union;  // [64 slices][4 g2] units of 17 floats

  const int tid = threadIdx.x;
  const int i0 = blockIdx.x * 2;
  const int i1 = i0 + 1;
  const int bs = (i0 / 10) * 10;  // i0 even -> i0,i1 share the same decade

  float sim0[NSLOT], sim1[NSLOT], raw0[NSLOT], raw1[NSLOT];
#pragma unroll
  for (int t = 0; t < NSLOT; t++) {
    sim0[t] = 0.f; sim1[t] = 0.f; raw0[t] = 0.f; raw1[t] = 0.f;
  }
  if (tid < SPAD - N_TOK) {
    s_attn[0][N_TOK + tid] = 0.f;
    s_attn[1][N_TOK + tid] = 0.f;
  }
  __syncthreads();

  unsigned qp0[16], qp1[16];  // packed f16 query pairs, wave-uniform -> SGPR

  // 3-stage pipelined sweep: loads for t+2 in flight during t's compute.
  auto sweep = [&](const uint4* __restrict__ kt4, auto&& emit) {
    uint4 ka[4], kb[4];
#pragma unroll
    for (int g_ = 0; g_ < 4; g_++) ka[g_] = kt4[g_ * N_TOK + tid];  // t=0
    {
      const int m1 = tid + 256;  // t=1 always valid (t=1 < 7)
#pragma unroll
      for (int g_ = 0; g_ < 4; g_++) kb[g_] = kt4[g_ * N_TOK + m1];
    }
#pragma unroll
    for (int t = 0; t < NSLOT; t++) {
      uint4 kc_[4];
      if (t < NSLOT - 2) {  // prefetch t+2
        const int m2 = tid + 256 * (t + 2);
        const bool v2 = (t + 2 < 7) || (tid < NTAIL);
        const int mc2 = v2 ? m2 : (N_TOK - 1);
#pragma unroll
        for (int g_ = 0; g_ < 4; g_++) kc_[g_] = kt4[g_ * N_TOK + mc2];
      }
      float d0 = 0.f, d1 = 0.f;
#pragma unroll
      for (int g_ = 0; g_ < 4; g_++) {
        d0 = fdot2f(ka[g_].x, qp0[4 * g_ + 0], d0);
        d0 = fdot2f(ka[g_].y, qp0[4 * g_ + 1], d0);
        d0 = fdot2f(ka[g_].z, qp0[4 * g_ + 2], d0);
        d0 = fdot2f(ka[g_].w, qp0[4 * g_ + 3], d0);
        d1 = fdot2f(ka[g_].x, qp1[4 * g_ + 0], d1);
        d1 = fdot2f(ka[g_].y, qp1[4 * g_ + 1], d1);
        d1 = fdot2f(ka[g_].z, qp1[4 * g_ + 2], d1);
        d1 = fdot2f(ka[g_].w, qp1[4 * g_ + 3], d1);
      }
      emit(t, d0, d1);
#pragma unroll
      for (int g_ = 0; g_ < 4; g_++) {
        ka[g_] = kb[g_];
        kb[g_] = kc_[g_];
      }
    }
  };

  for (int hh = 0; hh < NH; hh++) {
    const int h = (blockIdx.x + hh) & 7;  // XCD-local head schedule

    float sums[4] = {0.f, 0.f, 0.f, 0.f};  // ls0, ls1, lr0, lr1

    // ===== phase C: cls scores -> e = exp(s-25) -> s_attn (unnormalized) ===
    LOAD_QPAIR(qc_h);
    sweep((const uint4*)kc_h + (size_t)h * 4 * N_TOK,
          [&](int t, float d0, float d1) {
            const int m = tid + 256 * t;
            const bool valid = (t < 7) || (tid < NTAIL);
            const float e0 = valid ? __expf(d0 * SCALE - SCALE) : 0.f;
            const float e1 = valid ? __expf(d1 * SCALE - SCALE) : 0.f;
            sums[0] += e0; sums[1] += e1;
            if (valid) {
              s_attn[0][m] = e0;
              s_attn[1][m] = e1;
            }
          });

    // ===== phase R: reg scores -> s_er — NO reduction between phases =====
    LOAD_QPAIR(qr_h);
    sweep((const uint4*)kr_h + (size_t)h * 4 * N_TOK,
          [&](int t, float d0, float d1) {
            const int m = tid + 256 * t;
            const bool valid = (t < 7) || (tid < NTAIL);
            const float e0 = valid ? __expf(d0 * SCALE - SCALE) : 0.f;
            const float e1 = valid ? __expf(d1 * SCALE - SCALE) : 0.f;
            sums[2] += e0; sums[3] += e1;
            if (valid) {
              s_er[m] = e0;
              s_er[N_TOK + m] = e1;
            }
          });

    // ===== ONE packed reduction for all 4 softmax sums =====
    block_sum4(sums, red);
    const float n0c = 0.5f / sums[0], n1c = 0.5f / sums[1];
    const float n0r = 0.5f / sums[2], n1r = 0.5f / sums[3];

    // ===== combine, mask, sim += =====
#pragma unroll
    for (int t = 0; t < NSLOT; t++) {
      const int m = tid + 256 * t;
      if ((t < 7) || (tid < NTAIL)) {
        float a0 = s_attn[0][m] * n0c + s_er[m] * n0r;
        float a1 = s_attn[1][m] * n1c + s_er[N_TOK + m] * n1r;
        if (m >= bs && m < bs + 9) {
          if (m != i0) a0 = 0.f;
          if (m != i1) a1 = 0.f;
        }
        s_attn[0][m] = a0;
        s_attn[1][m] = a1;
        sim0[t] += a0;
        sim1[t] += a1;
      }
    }

    // ===== phase V: vn cosine -> raw += =====
    LOAD_QPAIR(vn_h);
    sweep((const uint4*)vn_h + (size_t)h * 4 * N_TOK,
          [&](int t, float d0, float d1) {
            const bool valid = (t < 7) || (tid < NTAIL);
            if (valid) { raw0[t] += d0; raw1[t] += d1; }
          });
    __syncthreads();  // s_attn final; s_er reads done -> part may reuse

    // ===== attn @ V : f16 V row-major, one uint4 = 8 d per load =====
    {
      const int g2 = tid & 3;        // d-group of 8
      const int slice = tid >> 2;    // 64 slices x 32 m
      const int m0 = slice * 32;
      float acc0[8], acc1[8];
#pragma unroll
      for (int e = 0; e < 8; e++) { acc0[e] = 0.f; acc1[e] = 0.f; }
      const _Float16* __restrict__ vb =
          v_h + (size_t)h * N_TOK * HD + g2 * 8;
#pragma unroll 2
      for (int jj = 0; jj < 8; jj++) {
        const int m = m0 + 4 * ((jj + slice) & 7);  // rotated: <=2-way LDS
        const float4 av0 = *(const float4*)&s_attn[0][m];
        const float4 av1 = *(const float4*)&s_attn[1][m];
        // m can reach 2047; av=0 there. v_h overrun (<=1.5k elems) lands in
        // the adjacent f16 plane (finite values; x0 = 0).
        uint4 vv[4];
#pragma unroll
        for (int mm = 0; mm < 4; mm++) {
          vv[mm] = *(const uint4*)(vb + (size_t)(m + mm) * HD);
        }
#pragma unroll
        for (int mm = 0; mm < 4; mm++) {
          const float a0 = ((const float*)&av0)[mm];
          const float a1 = ((const float*)&av1)[mm];
          const unsigned* vp = (const unsigned*)&vv[mm];
#pragma unroll
          for (int e = 0; e < 4; e++) {
            const half2_t hv = u2h(vp[e]);
            const float vx = (float)hv.x, vy = (float)hv.y;
            acc0[2 * e] += a0 * vx;
            acc0[2 * e + 1] += a0 * vy;
            acc1[2 * e] += a1 * vx;
            acc1[2 * e + 1] += a1 * vy;
          }
        }
      }
      __syncthreads();  // er reads in combine long done; part write safe
      float* pu = part + (size_t)(slice * 4 + g2) * 17;  // stride 17
#pragma unroll
      for (int e = 0; e < 8; e++) {
        pu[e] = acc0[e];
        pu[8 + e] = acc1[e];
      }
    }
    __syncthreads();
    if (tid < 64) {
      const int q = tid >> 5, d = tid & 31;
      const int g = d >> 3, e = d & 7;
      float s = 0.f;
#pragma unroll 8
      for (int sl = 0; sl < 64; sl++) {
        s += part[(size_t)(sl * 4 + g) * 17 + q * 8 + e];
      }
      const int irow = q ? i1 : i0;
      out_x[(size_t)irow * 512 + h * 32 + d] = s;
    } else if (tid >= 64 && tid < 128) {
      const int q = (tid - 64) >> 5, d = (tid - 64) & 31;
      const int irow = q ? i1 : i0;
      out_x[(size_t)irow * 512 + 256 + h * 32 + d] =
          v_rm[((size_t)h * N_TOK + irow) * HD + d];
    }
    __syncthreads();  // part reads done -> s_er reuse next head
  }

  // ===== sim_round2 epilogue, from registers =====
#pragma unroll
  for (int q = 0; q < 2; q++) {
    const int irow = q ? i1 : i0;
    float* __restrict__ sim = q ? sim1 : sim0;
    float* __restrict__ raw = q ? raw1 : raw0;

    float lm = -1e30f;
#pragma unroll
    for (int t = 0; t < NSLOT; t++) {
      if ((t < 7) || (tid < NTAIL)) lm = fmaxf(lm, sim[t] * 0.125f);
    }
    const float M = block_max256(lm, red);

    float ls = 0.f;
#pragma unroll
    for (int t = 0; t < NSLOT; t++) {
      const bool valid = (t < 7) || (tid < NTAIL);
      const float e = valid ? __expf(sim[t] * 0.125f - M) : 0.f;
      sim[t] = e;
      ls += e;
    }
    const float S = block_sum256(ls, red);
    const float invS = 1.0f / S;

    float lms = 0.f;
#pragma unroll
    for (int t = 0; t < NSLOT; t++) {
      const bool valid = (t < 7) || (tid < NTAIL);
      const float p = sim[t] * invS;
      const float mp = (valid && (raw[t] * 0.125f > SIM_TH)) ? p : 0.f;
      sim[t] = mp;
      lms += mp;
    }
    const float MS = block_sum256(lms, red);
    const float invMS = 1.0f / (MS + EPSF);

#pragma unroll
    for (int t = 0; t < NSLOT; t++) {
      const int m = tid + 256 * t;
      if ((t < 7) || (tid < NTAIL)) {
        out_sim[(size_t)irow * N_TOK + m] = sim[t] * invMS;
      }
    }
  }
}

// ---------------------------------------------------------------------------
extern "C" void kernel_launch(void* const* d_in, const int* in_sizes, int n_in,
                              void* d_out, int out_size, void* d_ws,
                              size_t ws_size, hipStream_t stream) {
  const float* x_cls = (const float*)d_in[0];
  const float* x_reg = (const float*)d_in[1];
  const float* W_cls = (const float*)d_in[2];
  const float* W_reg = (const float*)d_in[3];

  // ws layout: v_rm fp32, v_h f16 (NOT last: PV overrun must hit finite f16
  // data), then the score planes, then packed W.
  const size_t seg = (size_t)NH * N_TOK * HD;  // 512000 elements
  float* v_rm = (float*)d_ws;
  _Float16* v_h = (_Float16*)(v_rm + seg);
  _Float16* qc_h = v_h + seg;
  _Float16* qr_h = qc_h + seg;
  _Float16* kc_h = qr_h + seg;
  _Float16* kr_h = kc_h + seg;
  _Float16* vn_h = kr_h + seg;
  unsigned* Wp_cls = (unsigned*)(vn_h + seg);  // 98304 uints each
  unsigned* Wp_reg = Wp_cls + 98304;

  dim3 g0(96, 2);
  wpack_kernel<<<g0, 256, 0, stream>>>(W_cls, W_reg, Wp_cls, Wp_reg);

  dim3 g1(250, 2);
  qkv_norm_kernel<<<g1, 256, 0, stream>>>(x_cls, x_reg, Wp_cls, Wp_reg, qc_h,
                                          qr_h, kc_h, kr_h, vn_h, v_rm, v_h);

  float* out_x = (float*)d_out;                  // [2000, 512]
  float* out_sim = out_x + (size_t)N_TOK * 512;  // [2000, 2000]
  attn28_kernel<<<1000, 256, 0, stream>>>(qc_h, qr_h, kc_h, kr_h, vn_h, v_rm,
                                          v_h, out_x, out_sim);
}

// Round 9
// 273.917 us; speedup vs baseline: 1.8343x; 1.0738x over previous
//
#include <hip/hip_runtime.h>
#include <math.h>

#define N_TOK 2000
#define NH 8
#define HD 32
#define SCALE 25.0f
#define SIM_TH 0.75f
#define EPSF 1e-8f
#define NT 125  // key tiles of 16 (125*16 = 2000 exact)
#define QT 8    // real query rows per attn block

typedef _Float16 half2_t __attribute__((ext_vector_type(2)));
typedef _Float16 f16x4 __attribute__((ext_vector_type(4)));
typedef _Float16 f16x8 __attribute__((ext_vector_type(8)));
typedef float f32x4 __attribute__((ext_vector_type(4)));

__device__ __forceinline__ half2_t u2h(unsigned u) {
  return __builtin_bit_cast(half2_t, u);
}
__device__ __forceinline__ unsigned h2u(half2_t h) {
  return __builtin_bit_cast(unsigned, h);
}

// f32 += f16x2 . f16x2 (v_dot2_f32_f16; products exact, fp32 accumulate)
__device__ __forceinline__ float fdot2f(unsigned a, unsigned b, float c) {
#if __has_builtin(__builtin_amdgcn_fdot2)
  return __builtin_amdgcn_fdot2(u2h(a), u2h(b), c, false);
#else
  const half2_t ha = u2h(a), hb = u2h(b);
  return c + (float)ha.x * (float)hb.x + (float)ha.y * (float)hb.y;
#endif
}

__device__ __forceinline__ float block_max256(float v, float* red) {
#pragma unroll
  for (int off = 32; off > 0; off >>= 1) v = fmaxf(v, __shfl_xor(v, off, 64));
  __syncthreads();
  if ((threadIdx.x & 63) == 0) red[threadIdx.x >> 6] = v;
  __syncthreads();
  return fmaxf(fmaxf(red[0], red[1]), fmaxf(red[2], red[3]));
}
__device__ __forceinline__ float block_sum256(float v, float* red) {
#pragma unroll
  for (int off = 32; off > 0; off >>= 1) v += __shfl_xor(v, off, 64);
  __syncthreads();
  if ((threadIdx.x & 63) == 0) red[threadIdx.x >> 6] = v;
  __syncthreads();
  return (red[0] + red[1]) + (red[2] + red[3]);
}

// ---------------------------------------------------------------------------
// Kernel 0: pack W fp32 [256][768] into f16 pair-quads Wq[k/8][768].
// grid = (96, 2), block = 256
// ---------------------------------------------------------------------------
__global__ __launch_bounds__(256) void wpack_kernel(
    const float* __restrict__ W_cls, const float* __restrict__ W_reg,
    unsigned* __restrict__ Wp_cls, unsigned* __restrict__ Wp_reg) {
  const int idx = blockIdx.x * 256 + threadIdx.x;
  const int kq = idx / 768, c = idx % 768;
  const float* __restrict__ W = blockIdx.y ? W_reg : W_cls;
  uint4* __restrict__ Wq = (uint4*)(blockIdx.y ? Wp_reg : Wp_cls);
  uint4 o;
  o.x = h2u((half2_t){(_Float16)W[(8 * kq + 0) * 768 + c],
                      (_Float16)W[(8 * kq + 1) * 768 + c]});
  o.y = h2u((half2_t){(_Float16)W[(8 * kq + 2) * 768 + c],
                      (_Float16)W[(8 * kq + 3) * 768 + c]});
  o.z = h2u((half2_t){(_Float16)W[(8 * kq + 4) * 768 + c],
                      (_Float16)W[(8 * kq + 5) * 768 + c]});
  o.w = h2u((half2_t){(_Float16)W[(8 * kq + 6) * 768 + c],
                      (_Float16)W[(8 * kq + 7) * 768 + c]});
  Wq[idx] = o;
}

// ---------------------------------------------------------------------------
// Kernel 1: QKV projection, 8 rows/block (r28). Writes ROW-MAJOR f16 planes
// [h][n][32] for qc/qr/kc/kr/vn (MFMA fragment loads are one 16B read from
// these), transposed v_t[h][d][n] (PV B-operand: 4 contiguous m per lane),
// and v_rm f32 (exact out_x copy half).
// grid = (250, 2), block = 256
// ---------------------------------------------------------------------------
__global__ __launch_bounds__(256) void qkv_norm_kernel(
    const float* __restrict__ x_cls, const float* __restrict__ x_reg,
    const unsigned* __restrict__ Wp_cls, const unsigned* __restrict__ Wp_reg,
    _Float16* __restrict__ qc2, _Float16* __restrict__ qr2,
    _Float16* __restrict__ kc2, _Float16* __restrict__ kr2,
    _Float16* __restrict__ vn2, float* __restrict__ v_rm,
    _Float16* __restrict__ v_t) {
  __shared__ unsigned xs_p[8][128];
  __shared__ float res[8][768];
  __shared__ float inv_norm[192];

  const int n0 = blockIdx.x * 8;
  const int which = blockIdx.y;
  const int tid = threadIdx.x;
  const float* __restrict__ x = which ? x_reg : x_cls;
  const uint4* __restrict__ Wq = (const uint4*)(which ? Wp_reg : Wp_cls);

  if (tid < 128) {
#pragma unroll
    for (int r = 0; r < 8; r++) {
      const float2 xv = ((const float2*)x)[(size_t)(n0 + r) * 128 + tid];
      xs_p[r][tid] = h2u((half2_t){(_Float16)xv.x, (_Float16)xv.y});
    }
  }
  __syncthreads();

  float acc[8][3];
#pragma unroll
  for (int r = 0; r < 8; r++) acc[r][0] = acc[r][1] = acc[r][2] = 0.f;

  for (int kq = 0; kq < 32; kq++) {
    const uint4 w0 = Wq[kq * 768 + tid];
    const uint4 w1 = Wq[kq * 768 + tid + 256];
    const uint4 w2 = Wq[kq * 768 + tid + 512];
#pragma unroll
    for (int r = 0; r < 8; r++) {
      const uint4 xp = *(const uint4*)&xs_p[r][kq * 4];
      acc[r][0] = fdot2f(w0.x, xp.x, acc[r][0]);
      acc[r][0] = fdot2f(w0.y, xp.y, acc[r][0]);
      acc[r][0] = fdot2f(w0.z, xp.z, acc[r][0]);
      acc[r][0] = fdot2f(w0.w, xp.w, acc[r][0]);
      acc[r][1] = fdot2f(w1.x, xp.x, acc[r][1]);
      acc[r][1] = fdot2f(w1.y, xp.y, acc[r][1]);
      acc[r][1] = fdot2f(w1.z, xp.z, acc[r][1]);
      acc[r][1] = fdot2f(w1.w, xp.w, acc[r][1]);
      acc[r][2] = fdot2f(w2.x, xp.x, acc[r][2]);
      acc[r][2] = fdot2f(w2.y, xp.y, acc[r][2]);
      acc[r][2] = fdot2f(w2.z, xp.z, acc[r][2]);
      acc[r][2] = fdot2f(w2.w, xp.w, acc[r][2]);
    }
  }
#pragma unroll
  for (int r = 0; r < 8; r++) {
    res[r][tid] = acc[r][0];
    res[r][tid + 256] = acc[r][1];
    res[r][tid + 512] = acc[r][2];
  }
  __syncthreads();

  if (tid < 192) {
    const int r = tid / 24, grp = tid % 24;
    float ss = 0.f;
#pragma unroll
    for (int d = 0; d < HD; d++) {
      const float v = res[r][grp * 32 + d];
      ss += v * v;
    }
    inv_norm[tid] = 1.0f / (sqrtf(ss) + EPSF);
  }
  __syncthreads();

#pragma unroll
  for (int j = 0; j < 3; j++) {
    const int c = tid + j * 256;
    const int qkv = c >> 8, grp = c >> 5;
    const int h = grp & 7, d = c & 31;
#pragma unroll
    for (int r = 0; r < 8; r++) {
      const int n = n0 + r;
      const float val = res[r][c];
      const float nval = val * inv_norm[r * 24 + grp];
      const size_t fi = ((size_t)(h * N_TOK) + n) * HD + d;
      if (qkv == 0) {
        (which ? qr2 : qc2)[fi] = (_Float16)nval;
      } else if (qkv == 1) {
        (which ? kr2 : kc2)[fi] = (_Float16)nval;
      } else if (which == 0) {
        v_rm[fi] = val;
        vn2[fi] = (_Float16)nval;
        v_t[((size_t)(h * HD) + d) * N_TOK + n] = (_Float16)val;
      }
    }
  }
}

// ---------------------------------------------------------------------------
// Kernel 2 (r29 -> r30): MFMA rewrite, builtin name fixed (the legacy K=16
// f16 mfma is spelled ...16x16x16f16, no underscore). Rationale: MfmaUtil
// was 0.0 across all prior rounds while the problem is 3e12 MACs of matmul;
// the fdot2 structure is latency-co-limited (VALU 49%, L2-stream 50%) and
// immune to further knobs. Query-tiling (QT=8/block, 250 blocks) cuts L2
// bytes 4 GB -> ~1.6 GB and MFMA moves the MACs off the VALU. Swapped
// operands: mfma(K, Q) gives D^T with query=lane&15, key=(lane>>4)*4+reg ==
// the A-fragment layout of the K=16 PV mfma, so P feeds PV with just an
// f32->f16 convert. Pass 1: softmax sums (fixed exp(25s-25), no max).
// Pass 2: recompute scores, combine nc/nr, decade-mask, sim/raw per-tile in
// f32 registers (h-loop innermost), PV in per-head mfma accumulators; sim
// (f32) and raw (f16) stream to ws planes; epilogue kernel does sim_round2.
// 16-row MFMA tiles carry duplicated rows 8-15 (finite, discarded on write).
// grid = 250, block = 256 (4 waves; wave w owns key tiles w, w+4, ...)
// ---------------------------------------------------------------------------
__global__ __launch_bounds__(256) void attn30_kernel(
    const _Float16* __restrict__ qc2, const _Float16* __restrict__ qr2,
    const _Float16* __restrict__ kc2, const _Float16* __restrict__ kr2,
    const _Float16* __restrict__ vn2, const _Float16* __restrict__ v_t,
    const float* __restrict__ v_rm, float* __restrict__ out_x,
    float* __restrict__ sim_ws, _Float16* __restrict__ raw_ws) {
  __shared__ _Float16 qst[3][NH][QT][40];  // staged Q planes, +8 pad (15.4KB)
  __shared__ float sums_l[4][2][NH][16];   // per-wave sum partials (4 KB)
  __shared__ float nrm[2][NH][16];         // nc, nr (1 KB)
  __shared__ float st[4][QT][20];          // per-wave tile bounce (2.5 KB)
  __shared__ float pvr[4][NH][16][32];     // PV cross-wave reduce (64 KB)

  const int tid = threadIdx.x;
  const int w = tid >> 6;
  const int l = tid & 63;
  const int i0 = blockIdx.x * QT;

  // ---- stage Q: 3 planes x 8 heads x 8 rows x 32 d ----
  {
    const int h = tid >> 5, row = (tid >> 2) & 7, dg = tid & 3;
    const size_t src = ((size_t)(h * N_TOK) + (i0 + row)) * HD + dg * 8;
    *(uint4*)&qst[0][h][row][dg * 8] = *(const uint4*)(qc2 + src);
    *(uint4*)&qst[1][h][row][dg * 8] = *(const uint4*)(qr2 + src);
    *(uint4*)&qst[2][h][row][dg * 8] = *(const uint4*)(vn2 + src);
  }
  __syncthreads();

  // per-lane constants. q = lane&15 is the MFMA row/col index: for A-frags
  // it is the key row within the tile; for B-frags the query column.
  const int q = l & 15;
  const int kg = l >> 4;  // 0..3
  const int i_glob = i0 + q;           // only meaningful for q < 8
  const int bs = (i_glob / 10) * 10;   // decade start for the mask

  const f32x4 zero4 = {0.f, 0.f, 0.f, 0.f};

  // ======== pass 1: softmax denominators ========
  float sc[NH], sr[NH];
#pragma unroll
  for (int h = 0; h < NH; h++) { sc[h] = 0.f; sr[h] = 0.f; }

  for (int t = w; t < NT; t += 4) {
    const int mb = t * 16;
#pragma unroll
    for (int h = 0; h < NH; h++) {
      const size_t koff = ((size_t)(h * N_TOK) + mb + q) * HD + kg * 8;
      const f16x8 akc = *(const f16x8*)(kc2 + koff);
      const f16x8 akr = *(const f16x8*)(kr2 + koff);
      const f16x8 bqc = *(const f16x8*)&qst[0][h][q & 7][kg * 8];
      const f16x8 bqr = *(const f16x8*)&qst[1][h][q & 7][kg * 8];
      const f32x4 dc =
          __builtin_amdgcn_mfma_f32_16x16x32_f16(akc, bqc, zero4, 0, 0, 0);
      const f32x4 dr =
          __builtin_amdgcn_mfma_f32_16x16x32_f16(akr, bqr, zero4, 0, 0, 0);
#pragma unroll
      for (int i = 0; i < 4; i++) {
        sc[h] += __expf(dc[i] * SCALE - SCALE);
        sr[h] += __expf(dr[i] * SCALE - SCALE);
      }
    }
  }
  // lanes {l, l^16, l^32, l^48} share the same query column
#pragma unroll
  for (int h = 0; h < NH; h++) {
    sc[h] += __shfl_xor(sc[h], 16, 64);
    sc[h] += __shfl_xor(sc[h], 32, 64);
    sr[h] += __shfl_xor(sr[h], 16, 64);
    sr[h] += __shfl_xor(sr[h], 32, 64);
  }
  if (l < 16) {
#pragma unroll
    for (int h = 0; h < NH; h++) {
      sums_l[w][0][h][l] = sc[h];
      sums_l[w][1][h][l] = sr[h];
    }
  }
  __syncthreads();
  {
    const int pl = tid >> 7, h = (tid >> 4) & 7, qq = tid & 15;
    const float s = sums_l[0][pl][h][qq] + sums_l[1][pl][h][qq] +
                    sums_l[2][pl][h][qq] + sums_l[3][pl][h][qq];
    nrm[pl][h][qq] = 0.5f / s;
  }
  __syncthreads();
  float ncr[NH], nrr[NH];
#pragma unroll
  for (int h = 0; h < NH; h++) {
    ncr[h] = nrm[0][h][q];
    nrr[h] = nrm[1][h][q];
  }

  // ======== pass 2: combine + mask + sim/raw + PV ========
  f32x4 pv[NH][2];
#pragma unroll
  for (int h = 0; h < NH; h++) { pv[h][0] = zero4; pv[h][1] = zero4; }

  for (int t = w; t < NT; t += 4) {
    const int mb = t * 16;
    f32x4 simt = zero4;
    f32x4 rawt = zero4;
#pragma unroll
    for (int h = 0; h < NH; h++) {
      const size_t koff = ((size_t)(h * N_TOK) + mb + q) * HD + kg * 8;
      const f16x8 akc = *(const f16x8*)(kc2 + koff);
      const f16x8 akr = *(const f16x8*)(kr2 + koff);
      const f16x8 avn = *(const f16x8*)(vn2 + koff);
      const f16x8 bqc = *(const f16x8*)&qst[0][h][q & 7][kg * 8];
      const f16x8 bqr = *(const f16x8*)&qst[1][h][q & 7][kg * 8];
      const f16x8 bqv = *(const f16x8*)&qst[2][h][q & 7][kg * 8];
      const f32x4 dc =
          __builtin_amdgcn_mfma_f32_16x16x32_f16(akc, bqc, zero4, 0, 0, 0);
      const f32x4 dr =
          __builtin_amdgcn_mfma_f32_16x16x32_f16(akr, bqr, zero4, 0, 0, 0);
      // raw accumulates over heads via the C operand
      rawt = __builtin_amdgcn_mfma_f32_16x16x32_f16(avn, bqv, rawt, 0, 0, 0);

      f16x4 pa;
#pragma unroll
      for (int i = 0; i < 4; i++) {
        const float ec = __expf(dc[i] * SCALE - SCALE);
        const float er = __expf(dr[i] * SCALE - SCALE);
        float ai = ncr[h] * ec + nrr[h] * er;
        const int m = mb + kg * 4 + i;
        if (m >= bs && m < bs + 9 && m != i_glob) ai = 0.f;
        simt[i] += ai;
        pa[i] = (_Float16)ai;
      }
      // PV: D^T reg order == A-frag (k = 4*kg + i) of the K=16 mfma
      const f16x4 bv0 = *(const f16x4*)(
          v_t + ((size_t)(h * HD) + q) * N_TOK + mb + kg * 4);
      const f16x4 bv1 = *(const f16x4*)(
          v_t + ((size_t)(h * HD) + 16 + q) * N_TOK + mb + kg * 4);
      pv[h][0] =
          __builtin_amdgcn_mfma_f32_16x16x16f16(pa, bv0, pv[h][0], 0, 0, 0);
      pv[h][1] =
          __builtin_amdgcn_mfma_f32_16x16x16f16(pa, bv1, pv[h][1], 0, 0, 0);
    }
    // ---- stream sim tile (f32) via wave-local LDS bounce ----
    if (q < 8) {
#pragma unroll
      for (int i = 0; i < 4; i++) st[w][q][kg * 4 + i] = simt[i];
    }
    if (l < 32) {
      const int qq = l >> 2, mo = (l & 3) * 4;
      const float4 v4 = *(const float4*)&st[w][qq][mo];
      *(float4*)(sim_ws + (size_t)(i0 + qq) * N_TOK + mb + mo) = v4;
    }
    // ---- stream raw tile (f16) ----
    if (q < 8) {
#pragma unroll
      for (int i = 0; i < 4; i++) st[w][q][kg * 4 + i] = rawt[i];
    }
    if (l < 32) {
      const int qq = l >> 2, mo = (l & 3) * 4;
      const float4 v4 = *(const float4*)&st[w][qq][mo];
      uint2 u;
      u.x = h2u((half2_t){(_Float16)v4.x, (_Float16)v4.y});
      u.y = h2u((half2_t){(_Float16)v4.z, (_Float16)v4.w});
      *(uint2*)(raw_ws + (size_t)(i0 + qq) * N_TOK + mb + mo) = u;
    }
  }

  // ======== PV cross-wave reduction + out_x ========
  __syncthreads();
#pragma unroll
  for (int h = 0; h < NH; h++) {
#pragma unroll
    for (int i = 0; i < 4; i++) {
      pvr[w][h][kg * 4 + i][q] = pv[h][0][i];
      pvr[w][h][kg * 4 + i][16 + q] = pv[h][1][i];
    }
  }
  __syncthreads();
  {
    const int h = tid >> 5, d = tid & 31;
#pragma unroll
    for (int qq = 0; qq < QT; qq++) {
      const float s = pvr[0][h][qq][d] + pvr[1][h][qq][d] +
                      pvr[2][h][qq][d] + pvr[3][h][qq][d];
      out_x[(size_t)(i0 + qq) * 512 + tid] = s;
      out_x[(size_t)(i0 + qq) * 512 + 256 + tid] =
          v_rm[((size_t)(h * N_TOK) + i0 + qq) * HD + d];
    }
  }
}

// ---------------------------------------------------------------------------
// Kernel 3: sim_round2 epilogue from ws planes (r21's proven math).
// grid = 250, block = 256; 8 rows per block.
// ---------------------------------------------------------------------------
__global__ __launch_bounds__(256) void sim_round2_kernel(
    const float* __restrict__ sim_ws, const _Float16* __restrict__ raw_ws,
    float* __restrict__ out_sim) {
  __shared__ float red[16];
  const int tid = threadIdx.x;
  const int i0 = blockIdx.x * 8;
  for (int r = 0; r < 8; r++) {
    const int i = i0 + r;
    float s[8], rw[8];
#pragma unroll
    for (int t = 0; t < 8; t++) {
      const int m = tid + 256 * t;
      const bool valid = (t < 7) || (tid < 208);
      s[t] = valid ? sim_ws[(size_t)i * N_TOK + m] * 0.125f : -1e30f;
      rw[t] = valid ? (float)raw_ws[(size_t)i * N_TOK + m] : 0.f;
    }
    float lm = -1e30f;
#pragma unroll
    for (int t = 0; t < 8; t++) lm = fmaxf(lm, s[t]);
    const float M = block_max256(lm, red);
    float ls = 0.f;
#pragma unroll
    for (int t = 0; t < 8; t++) {
      const bool valid = (t < 7) || (tid < 208);
      const float e = valid ? __expf(s[t] - M) : 0.f;
      s[t] = e;
      ls += e;
    }
    const float S = block_sum256(ls, red);
    const float invS = 1.0f / S;
    float lms = 0.f;
#pragma unroll
    for (int t = 0; t < 8; t++) {
      const bool valid = (t < 7) || (tid < 208);
      const float p = s[t] * invS;
      const float mp = (valid && (rw[t] * 0.125f > SIM_TH)) ? p : 0.f;
      s[t] = mp;
      lms += mp;
    }
    const float MS = block_sum256(lms, red);
    const float invMS = 1.0f / (MS + EPSF);
#pragma unroll
    for (int t = 0; t < 8; t++) {
      const int m = tid + 256 * t;
      if ((t < 7) || (tid < 208)) {
        out_sim[(size_t)i * N_TOK + m] = s[t] * invMS;
      }
    }
  }
}

// ---------------------------------------------------------------------------
extern "C" void kernel_launch(void* const* d_in, const int* in_sizes, int n_in,
                              void* d_out, int out_size, void* d_ws,
                              size_t ws_size, hipStream_t stream) {
  const float* x_cls = (const float*)d_in[0];
  const float* x_reg = (const float*)d_in[1];
  const float* W_cls = (const float*)d_in[2];
  const float* W_reg = (const float*)d_in[3];

  // ws layout (~33 MB): v_rm f32, 6 f16 planes, sim f32 plane, raw f16
  // plane, packed W.
  const size_t seg = (size_t)NH * N_TOK * HD;  // 512000 elements
  float* v_rm = (float*)d_ws;
  _Float16* qc2 = (_Float16*)(v_rm + seg);
  _Float16* qr2 = qc2 + seg;
  _Float16* kc2 = qr2 + seg;
  _Float16* kr2 = kc2 + seg;
  _Float16* vn2 = kr2 + seg;
  _Float16* v_t = vn2 + seg;
  float* sim_ws = (float*)(v_t + seg);  // N*N f32
  _Float16* raw_ws = (_Float16*)(sim_ws + (size_t)N_TOK * N_TOK);
  unsigned* Wp_cls = (unsigned*)(raw_ws + (size_t)N_TOK * N_TOK);
  unsigned* Wp_reg = Wp_cls + 98304;

  dim3 g0(96, 2);
  wpack_kernel<<<g0, 256, 0, stream>>>(W_cls, W_reg, Wp_cls, Wp_reg);

  dim3 g1(250, 2);
  qkv_norm_kernel<<<g1, 256, 0, stream>>>(x_cls, x_reg, Wp_cls, Wp_reg, qc2,
                                          qr2, kc2, kr2, vn2, v_rm, v_t);

  float* out_x = (float*)d_out;                  // [2000, 512]
  float* out_sim = out_x + (size_t)N_TOK * 512;  // [2000, 2000]
  attn30_kernel<<<250, 256, 0, stream>>>(qc2, qr2, kc2, kr2, vn2, v_t, v_rm,
                                         out_x, sim_ws, raw_ws);
  sim_round2_kernel<<<250, 256, 0, stream>>>(sim_ws, raw_ws, out_sim);
}

// Round 10
// 273.833 us; speedup vs baseline: 1.8348x; 1.0003x over previous
//
#include <hip/hip_runtime.h>
#include <math.h>

#define N_TOK 2000
#define NH 8
#define HD 32
#define SCALE 25.0f
#define SIM_TH 0.75f
#define EPSF 1e-8f
#define NT 125  // key tiles of 16 (125*16 = 2000 exact)
#define QT 8    // real query rows per attn block

typedef _Float16 half2_t __attribute__((ext_vector_type(2)));
typedef _Float16 f16x4 __attribute__((ext_vector_type(4)));
typedef _Float16 f16x8 __attribute__((ext_vector_type(8)));
typedef float f32x4 __attribute__((ext_vector_type(4)));

__device__ __forceinline__ half2_t u2h(unsigned u) {
  return __builtin_bit_cast(half2_t, u);
}
__device__ __forceinline__ unsigned h2u(half2_t h) {
  return __builtin_bit_cast(unsigned, h);
}

// f32 += f16x2 . f16x2 (v_dot2_f32_f16; products exact, fp32 accumulate)
__device__ __forceinline__ float fdot2f(unsigned a, unsigned b, float c) {
#if __has_builtin(__builtin_amdgcn_fdot2)
  return __builtin_amdgcn_fdot2(u2h(a), u2h(b), c, false);
#else
  const half2_t ha = u2h(a), hb = u2h(b);
  return c + (float)ha.x * (float)hb.x + (float)ha.y * (float)hb.y;
#endif
}

__device__ __forceinline__ float block_max256(float v, float* red) {
#pragma unroll
  for (int off = 32; off > 0; off >>= 1) v = fmaxf(v, __shfl_xor(v, off, 64));
  __syncthreads();
  if ((threadIdx.x & 63) == 0) red[threadIdx.x >> 6] = v;
  __syncthreads();
  return fmaxf(fmaxf(red[0], red[1]), fmaxf(red[2], red[3]));
}
__device__ __forceinline__ float block_sum256(float v, float* red) {
#pragma unroll
  for (int off = 32; off > 0; off >>= 1) v += __shfl_xor(v, off, 64);
  __syncthreads();
  if ((threadIdx.x & 63) == 0) red[threadIdx.x >> 6] = v;
  __syncthreads();
  return (red[0] + red[1]) + (red[2] + red[3]);
}

// ---------------------------------------------------------------------------
// Kernel 0: pack W fp32 [256][768] into f16 pair-quads Wq[k/8][768].
// grid = (96, 2), block = 256
// ---------------------------------------------------------------------------
__global__ __launch_bounds__(256) void wpack_kernel(
    const float* __restrict__ W_cls, const float* __restrict__ W_reg,
    unsigned* __restrict__ Wp_cls, unsigned* __restrict__ Wp_reg) {
  const int idx = blockIdx.x * 256 + threadIdx.x;
  const int kq = idx / 768, c = idx % 768;
  const float* __restrict__ W = blockIdx.y ? W_reg : W_cls;
  uint4* __restrict__ Wq = (uint4*)(blockIdx.y ? Wp_reg : Wp_cls);
  uint4 o;
  o.x = h2u((half2_t){(_Float16)W[(8 * kq + 0) * 768 + c],
                      (_Float16)W[(8 * kq + 1) * 768 + c]});
  o.y = h2u((half2_t){(_Float16)W[(8 * kq + 2) * 768 + c],
                      (_Float16)W[(8 * kq + 3) * 768 + c]});
  o.z = h2u((half2_t){(_Float16)W[(8 * kq + 4) * 768 + c],
                      (_Float16)W[(8 * kq + 5) * 768 + c]});
  o.w = h2u((half2_t){(_Float16)W[(8 * kq + 6) * 768 + c],
                      (_Float16)W[(8 * kq + 7) * 768 + c]});
  Wq[idx] = o;
}

// ---------------------------------------------------------------------------
// Kernel 1: QKV projection, 8 rows/block (r28). Writes ROW-MAJOR f16 planes
// [h][n][32] for qc/qr/kc/kr/vn (MFMA fragment loads are one 16B read from
// these), transposed v_t[h][d][n] (PV B-operand: 4 contiguous m per lane),
// and v_rm f32 (exact out_x copy half).
// grid = (250, 2), block = 256
// ---------------------------------------------------------------------------
__global__ __launch_bounds__(256) void qkv_norm_kernel(
    const float* __restrict__ x_cls, const float* __restrict__ x_reg,
    const unsigned* __restrict__ Wp_cls, const unsigned* __restrict__ Wp_reg,
    _Float16* __restrict__ qc2, _Float16* __restrict__ qr2,
    _Float16* __restrict__ kc2, _Float16* __restrict__ kr2,
    _Float16* __restrict__ vn2, float* __restrict__ v_rm,
    _Float16* __restrict__ v_t) {
  __shared__ unsigned xs_p[8][128];
  __shared__ float res[8][768];
  __shared__ float inv_norm[192];

  const int n0 = blockIdx.x * 8;
  const int which = blockIdx.y;
  const int tid = threadIdx.x;
  const float* __restrict__ x = which ? x_reg : x_cls;
  const uint4* __restrict__ Wq = (const uint4*)(which ? Wp_reg : Wp_cls);

  if (tid < 128) {
#pragma unroll
    for (int r = 0; r < 8; r++) {
      const float2 xv = ((const float2*)x)[(size_t)(n0 + r) * 128 + tid];
      xs_p[r][tid] = h2u((half2_t){(_Float16)xv.x, (_Float16)xv.y});
    }
  }
  __syncthreads();

  float acc[8][3];
#pragma unroll
  for (int r = 0; r < 8; r++) acc[r][0] = acc[r][1] = acc[r][2] = 0.f;

  for (int kq = 0; kq < 32; kq++) {
    const uint4 w0 = Wq[kq * 768 + tid];
    const uint4 w1 = Wq[kq * 768 + tid + 256];
    const uint4 w2 = Wq[kq * 768 + tid + 512];
#pragma unroll
    for (int r = 0; r < 8; r++) {
      const uint4 xp = *(const uint4*)&xs_p[r][kq * 4];
      acc[r][0] = fdot2f(w0.x, xp.x, acc[r][0]);
      acc[r][0] = fdot2f(w0.y, xp.y, acc[r][0]);
      acc[r][0] = fdot2f(w0.z, xp.z, acc[r][0]);
      acc[r][0] = fdot2f(w0.w, xp.w, acc[r][0]);
      acc[r][1] = fdot2f(w1.x, xp.x, acc[r][1]);
      acc[r][1] = fdot2f(w1.y, xp.y, acc[r][1]);
      acc[r][1] = fdot2f(w1.z, xp.z, acc[r][1]);
      acc[r][1] = fdot2f(w1.w, xp.w, acc[r][1]);
      acc[r][2] = fdot2f(w2.x, xp.x, acc[r][2]);
      acc[r][2] = fdot2f(w2.y, xp.y, acc[r][2]);
      acc[r][2] = fdot2f(w2.z, xp.z, acc[r][2]);
      acc[r][2] = fdot2f(w2.w, xp.w, acc[r][2]);
    }
  }
#pragma unroll
  for (int r = 0; r < 8; r++) {
    res[r][tid] = acc[r][0];
    res[r][tid + 256] = acc[r][1];
    res[r][tid + 512] = acc[r][2];
  }
  __syncthreads();

  if (tid < 192) {
    const int r = tid / 24, grp = tid % 24;
    float ss = 0.f;
#pragma unroll
    for (int d = 0; d < HD; d++) {
      const float v = res[r][grp * 32 + d];
      ss += v * v;
    }
    inv_norm[tid] = 1.0f / (sqrtf(ss) + EPSF);
  }
  __syncthreads();

#pragma unroll
  for (int j = 0; j < 3; j++) {
    const int c = tid + j * 256;
    const int qkv = c >> 8, grp = c >> 5;
    const int h = grp & 7, d = c & 31;
#pragma unroll
    for (int r = 0; r < 8; r++) {
      const int n = n0 + r;
      const float val = res[r][c];
      const float nval = val * inv_norm[r * 24 + grp];
      const size_t fi = ((size_t)(h * N_TOK) + n) * HD + d;
      if (qkv == 0) {
        (which ? qr2 : qc2)[fi] = (_Float16)nval;
      } else if (qkv == 1) {
        (which ? kr2 : kc2)[fi] = (_Float16)nval;
      } else if (which == 0) {
        v_rm[fi] = val;
        vn2[fi] = (_Float16)nval;
        v_t[((size_t)(h * HD) + d) * N_TOK + n] = (_Float16)val;
      }
    }
  }
}

// ---------------------------------------------------------------------------
// Kernel 2 (r30 -> r31): same MFMA structure, LDS 88.5 -> ~31.5 KB to lift
// occupancy. Post-mortem r30: MfmaUtil 6.6 (first nonzero), attn 175 us,
// absmax unchanged -> layouts correct. But occupancy 11% = 1 block/CU = ~0.9
// waves/SIMD (no latency hiding); session threshold for 2-block residency at
// 256t is between 35.3 KB (2 blocks, r21) and 50.7 KB (1 block, r23). The
// 64 KB pvr buffer is the gate. Changes: (1) PV cross-wave reduce split into
// 4 head-groups of 2 (pvr [4][2][16][33] f32 = 16.9 KB, stride-33 rows for
// bank spread; 8 extra syncs/kernel, identical 4-wave sum order); (2) union
// sums_l/nrm (pass-1-only), st (tile-loop-only), pvr (post-loop) in one
// buffer; one added sync after the ncr/nrr register loads separates the
// lifetimes. Total LDS = 15360 (qst) + 16896 (union) = 32256 B.
// grid = 250, block = 256 (4 waves; wave w owns key tiles w, w+4, ...)
// ---------------------------------------------------------------------------
__global__ __launch_bounds__(256) void attn31_kernel(
    const _Float16* __restrict__ qc2, const _Float16* __restrict__ qr2,
    const _Float16* __restrict__ kc2, const _Float16* __restrict__ kr2,
    const _Float16* __restrict__ vn2, const _Float16* __restrict__ v_t,
    const float* __restrict__ v_rm, float* __restrict__ out_x,
    float* __restrict__ sim_ws, _Float16* __restrict__ raw_ws) {
  __shared__ _Float16 qst[3][NH][QT][40];  // staged Q planes, pad 40 (15.4KB)
  __shared__ float smem_u[4224];           // 16.9 KB union (see header)

  float* __restrict__ sums_l = smem_u;          // [4][2][8][16] = 1024 f
  float* __restrict__ nrm = smem_u + 1024;      // [2][8][16] = 256 f
  float* __restrict__ st = smem_u;              // [4][8][20] = 640 f
  float* __restrict__ pvr = smem_u;             // [4][2][16][33] = 4224 f

  const int tid = threadIdx.x;
  const int w = tid >> 6;
  const int l = tid & 63;
  const int i0 = blockIdx.x * QT;

  // ---- stage Q: 3 planes x 8 heads x 8 rows x 32 d ----
  {
    const int h = tid >> 5, row = (tid >> 2) & 7, dg = tid & 3;
    const size_t src = ((size_t)(h * N_TOK) + (i0 + row)) * HD + dg * 8;
    *(uint4*)&qst[0][h][row][dg * 8] = *(const uint4*)(qc2 + src);
    *(uint4*)&qst[1][h][row][dg * 8] = *(const uint4*)(qr2 + src);
    *(uint4*)&qst[2][h][row][dg * 8] = *(const uint4*)(vn2 + src);
  }
  __syncthreads();

  // per-lane constants. q = lane&15 is the MFMA row/col index: for A-frags
  // it is the key row within the tile; for B-frags the query column.
  const int q = l & 15;
  const int kg = l >> 4;  // 0..3
  const int i_glob = i0 + q;           // only meaningful for q < 8
  const int bs = (i_glob / 10) * 10;   // decade start for the mask

  const f32x4 zero4 = {0.f, 0.f, 0.f, 0.f};

  // ======== pass 1: softmax denominators ========
  float sc[NH], sr[NH];
#pragma unroll
  for (int h = 0; h < NH; h++) { sc[h] = 0.f; sr[h] = 0.f; }

  for (int t = w; t < NT; t += 4) {
    const int mb = t * 16;
#pragma unroll
    for (int h = 0; h < NH; h++) {
      const size_t koff = ((size_t)(h * N_TOK) + mb + q) * HD + kg * 8;
      const f16x8 akc = *(const f16x8*)(kc2 + koff);
      const f16x8 akr = *(const f16x8*)(kr2 + koff);
      const f16x8 bqc = *(const f16x8*)&qst[0][h][q & 7][kg * 8];
      const f16x8 bqr = *(const f16x8*)&qst[1][h][q & 7][kg * 8];
      const f32x4 dc =
          __builtin_amdgcn_mfma_f32_16x16x32_f16(akc, bqc, zero4, 0, 0, 0);
      const f32x4 dr =
          __builtin_amdgcn_mfma_f32_16x16x32_f16(akr, bqr, zero4, 0, 0, 0);
#pragma unroll
      for (int i = 0; i < 4; i++) {
        sc[h] += __expf(dc[i] * SCALE - SCALE);
        sr[h] += __expf(dr[i] * SCALE - SCALE);
      }
    }
  }
  // lanes {l, l^16, l^32, l^48} share the same query column
#pragma unroll
  for (int h = 0; h < NH; h++) {
    sc[h] += __shfl_xor(sc[h], 16, 64);
    sc[h] += __shfl_xor(sc[h], 32, 64);
    sr[h] += __shfl_xor(sr[h], 16, 64);
    sr[h] += __shfl_xor(sr[h], 32, 64);
  }
  if (l < 16) {
#pragma unroll
    for (int h = 0; h < NH; h++) {
      sums_l[((w * 2 + 0) * 8 + h) * 16 + l] = sc[h];
      sums_l[((w * 2 + 1) * 8 + h) * 16 + l] = sr[h];
    }
  }
  __syncthreads();
  {
    const int pl = tid >> 7, h = (tid >> 4) & 7, qq = tid & 15;
    const float s = sums_l[((0 * 2 + pl) * 8 + h) * 16 + qq] +
                    sums_l[((1 * 2 + pl) * 8 + h) * 16 + qq] +
                    sums_l[((2 * 2 + pl) * 8 + h) * 16 + qq] +
                    sums_l[((3 * 2 + pl) * 8 + h) * 16 + qq];
    nrm[(pl * 8 + h) * 16 + qq] = 0.5f / s;
  }
  __syncthreads();
  float ncr[NH], nrr[NH];
#pragma unroll
  for (int h = 0; h < NH; h++) {
    ncr[h] = nrm[(0 * 8 + h) * 16 + q];
    nrr[h] = nrm[(1 * 8 + h) * 16 + q];
  }
  __syncthreads();  // nrm reads done -> st (aliased) may be written

  // ======== pass 2: combine + mask + sim/raw + PV ========
  f32x4 pv[NH][2];
#pragma unroll
  for (int h = 0; h < NH; h++) { pv[h][0] = zero4; pv[h][1] = zero4; }

  for (int t = w; t < NT; t += 4) {
    const int mb = t * 16;
    f32x4 simt = zero4;
    f32x4 rawt = zero4;
#pragma unroll
    for (int h = 0; h < NH; h++) {
      const size_t koff = ((size_t)(h * N_TOK) + mb + q) * HD + kg * 8;
      const f16x8 akc = *(const f16x8*)(kc2 + koff);
      const f16x8 akr = *(const f16x8*)(kr2 + koff);
      const f16x8 avn = *(const f16x8*)(vn2 + koff);
      const f16x8 bqc = *(const f16x8*)&qst[0][h][q & 7][kg * 8];
      const f16x8 bqr = *(const f16x8*)&qst[1][h][q & 7][kg * 8];
      const f16x8 bqv = *(const f16x8*)&qst[2][h][q & 7][kg * 8];
      const f32x4 dc =
          __builtin_amdgcn_mfma_f32_16x16x32_f16(akc, bqc, zero4, 0, 0, 0);
      const f32x4 dr =
          __builtin_amdgcn_mfma_f32_16x16x32_f16(akr, bqr, zero4, 0, 0, 0);
      // raw accumulates over heads via the C operand
      rawt = __builtin_amdgcn_mfma_f32_16x16x32_f16(avn, bqv, rawt, 0, 0, 0);

      f16x4 pa;
#pragma unroll
      for (int i = 0; i < 4; i++) {
        const float ec = __expf(dc[i] * SCALE - SCALE);
        const float er = __expf(dr[i] * SCALE - SCALE);
        float ai = ncr[h] * ec + nrr[h] * er;
        const int m = mb + kg * 4 + i;
        if (m >= bs && m < bs + 9 && m != i_glob) ai = 0.f;
        simt[i] += ai;
        pa[i] = (_Float16)ai;
      }
      // PV: D^T reg order == A-frag (k = 4*kg + i) of the K=16 mfma
      const f16x4 bv0 = *(const f16x4*)(
          v_t + ((size_t)(h * HD) + q) * N_TOK + mb + kg * 4);
      const f16x4 bv1 = *(const f16x4*)(
          v_t + ((size_t)(h * HD) + 16 + q) * N_TOK + mb + kg * 4);
      pv[h][0] =
          __builtin_amdgcn_mfma_f32_16x16x16f16(pa, bv0, pv[h][0], 0, 0, 0);
      pv[h][1] =
          __builtin_amdgcn_mfma_f32_16x16x16f16(pa, bv1, pv[h][1], 0, 0, 0);
    }
    // ---- stream sim tile (f32) via wave-local LDS bounce ----
    if (q < 8) {
#pragma unroll
      for (int i = 0; i < 4; i++) st[(w * 8 + q) * 20 + kg * 4 + i] = simt[i];
    }
    if (l < 32) {
      const int qq = l >> 2, mo = (l & 3) * 4;
      const float4 v4 = *(const float4*)&st[(w * 8 + qq) * 20 + mo];
      *(float4*)(sim_ws + (size_t)(i0 + qq) * N_TOK + mb + mo) = v4;
    }
    // ---- stream raw tile (f16) ----
    if (q < 8) {
#pragma unroll
      for (int i = 0; i < 4; i++) st[(w * 8 + q) * 20 + kg * 4 + i] = rawt[i];
    }
    if (l < 32) {
      const int qq = l >> 2, mo = (l & 3) * 4;
      const float4 v4 = *(const float4*)&st[(w * 8 + qq) * 20 + mo];
      uint2 u;
      u.x = h2u((half2_t){(_Float16)v4.x, (_Float16)v4.y});
      u.y = h2u((half2_t){(_Float16)v4.z, (_Float16)v4.w});
      *(uint2*)(raw_ws + (size_t)(i0 + qq) * N_TOK + mb + mo) = u;
    }
  }

  // ======== PV cross-wave reduction + out_x, 4 head-groups of 2 ========
#pragma unroll
  for (int hg = 0; hg < 4; hg++) {
    __syncthreads();  // st reads / previous group's pvr reads done
#pragma unroll
    for (int hh = 0; hh < 2; hh++) {
      const int h = hg * 2 + hh;
#pragma unroll
      for (int i = 0; i < 4; i++) {
        pvr[((w * 2 + hh) * 16 + kg * 4 + i) * 33 + q] = pv[h][0][i];
        pvr[((w * 2 + hh) * 16 + kg * 4 + i) * 33 + 16 + q] = pv[h][1][i];
      }
    }
    __syncthreads();
    {
      const int hh = tid >> 7, qg = (tid >> 5) & 3, d = tid & 31;
#pragma unroll
      for (int qi = 0; qi < 2; qi++) {
        const int qq = qg * 2 + qi;
        float s = 0.f;
#pragma unroll
        for (int wv = 0; wv < 4; wv++) {
          s += pvr[((wv * 2 + hh) * 16 + qq) * 33 + d];
        }
        out_x[(size_t)(i0 + qq) * 512 + (hg * 2 + hh) * 32 + d] = s;
      }
    }
  }
  // ---- v_rm copy half (global-only, no sync needed) ----
  {
    const int h = tid >> 5, d = tid & 31;
#pragma unroll
    for (int qq = 0; qq < QT; qq++) {
      out_x[(size_t)(i0 + qq) * 512 + 256 + tid] =
          v_rm[((size_t)(h * N_TOK) + i0 + qq) * HD + d];
    }
  }
}

// ---------------------------------------------------------------------------
// Kernel 3: sim_round2 epilogue from ws planes (r21's proven math).
// grid = 250, block = 256; 8 rows per block.
// ---------------------------------------------------------------------------
__global__ __launch_bounds__(256) void sim_round2_kernel(
    const float* __restrict__ sim_ws, const _Float16* __restrict__ raw_ws,
    float* __restrict__ out_sim) {
  __shared__ float red[16];
  const int tid = threadIdx.x;
  const int i0 = blockIdx.x * 8;
  for (int r = 0; r < 8; r++) {
    const int i = i0 + r;
    float s[8], rw[8];
#pragma unroll
    for (int t = 0; t < 8; t++) {
      const int m = tid + 256 * t;
      const bool valid = (t < 7) || (tid < 208);
      s[t] = valid ? sim_ws[(size_t)i * N_TOK + m] * 0.125f : -1e30f;
      rw[t] = valid ? (float)raw_ws[(size_t)i * N_TOK + m] : 0.f;
    }
    float lm = -1e30f;
#pragma unroll
    for (int t = 0; t < 8; t++) lm = fmaxf(lm, s[t]);
    const float M = block_max256(lm, red);
    float ls = 0.f;
#pragma unroll
    for (int t = 0; t < 8; t++) {
      const bool valid = (t < 7) || (tid < 208);
      const float e = valid ? __expf(s[t] - M) : 0.f;
      s[t] = e;
      ls += e;
    }
    const float S = block_sum256(ls, red);
    const float invS = 1.0f / S;
    float lms = 0.f;
#pragma unroll
    for (int t = 0; t < 8; t++) {
      const bool valid = (t < 7) || (tid < 208);
      const float p = s[t] * invS;
      const float mp = (valid && (rw[t] * 0.125f > SIM_TH)) ? p : 0.f;
      s[t] = mp;
      lms += mp;
    }
    const float MS = block_sum256(lms, red);
    const float invMS = 1.0f / (MS + EPSF);
#pragma unroll
    for (int t = 0; t < 8; t++) {
      const int m = tid + 256 * t;
      if ((t < 7) || (tid < 208)) {
        out_sim[(size_t)i * N_TOK + m] = s[t] * invMS;
      }
    }
  }
}

// ---------------------------------------------------------------------------
extern "C" void kernel_launch(void* const* d_in, const int* in_sizes, int n_in,
                              void* d_out, int out_size, void* d_ws,
                              size_t ws_size, hipStream_t stream) {
  const float* x_cls = (const float*)d_in[0];
  const float* x_reg = (const float*)d_in[1];
  const float* W_cls = (const float*)d_in[2];
  const float* W_reg = (const float*)d_in[3];

  // ws layout (~33 MB): v_rm f32, 6 f16 planes, sim f32 plane, raw f16
  // plane, packed W.
  const size_t seg = (size_t)NH * N_TOK * HD;  // 512000 elements
  float* v_rm = (float*)d_ws;
  _Float16* qc2 = (_Float16*)(v_rm + seg);
  _Float16* qr2 = qc2 + seg;
  _Float16* kc2 = qr2 + seg;
  _Float16* kr2 = kc2 + seg;
  _Float16* vn2 = kr2 + seg;
  _Float16* v_t = vn2 + seg;
  float* sim_ws = (float*)(v_t + seg);  // N*N f32
  _Float16* raw_ws = (_Float16*)(sim_ws + (size_t)N_TOK * N_TOK);
  unsigned* Wp_cls = (unsigned*)(raw_ws + (size_t)N_TOK * N_TOK);
  unsigned* Wp_reg = Wp_cls + 98304;

  dim3 g0(96, 2);
  wpack_kernel<<<g0, 256, 0, stream>>>(W_cls, W_reg, Wp_cls, Wp_reg);

  dim3 g1(250, 2);
  qkv_norm_kernel<<<g1, 256, 0, stream>>>(x_cls, x_reg, Wp_cls, Wp_reg, qc2,
                                          qr2, kc2, kr2, vn2, v_rm, v_t);

  float* out_x = (float*)d_out;                  // [2000, 512]
  float* out_sim = out_x + (size_t)N_TOK * 512;  // [2000, 2000]
  attn31_kernel<<<250, 256, 0, stream>>>(qc2, qr2, kc2, kr2, vn2, v_t, v_rm,
                                         out_x, sim_ws, raw_ws);
  sim_round2_kernel<<<250, 256, 0, stream>>>(sim_ws, raw_ws, out_sim);
}

// Round 11
// 220.082 us; speedup vs baseline: 2.2829x; 1.2442x over previous
//
#include <hip/hip_runtime.h>
#include <math.h>

#define N_TOK 2000
#define NH 8
#define NHH 4  // heads per attn block (2-way head split)
#define HD 32
#define SCALE 25.0f
#define SIM_TH 0.75f
#define EPSF 1e-8f
#define NT 125  // key tiles of 16 (125*16 = 2000 exact)
#define QT 8    // query rows per attn block

typedef _Float16 half2_t __attribute__((ext_vector_type(2)));
typedef _Float16 f16x4 __attribute__((ext_vector_type(4)));
typedef _Float16 f16x8 __attribute__((ext_vector_type(8)));
typedef float f32x4 __attribute__((ext_vector_type(4)));

__device__ __forceinline__ half2_t u2h(unsigned u) {
  return __builtin_bit_cast(half2_t, u);
}
__device__ __forceinline__ unsigned h2u(half2_t h) {
  return __builtin_bit_cast(unsigned, h);
}

// f32 += f16x2 . f16x2 (v_dot2_f32_f16; products exact, fp32 accumulate)
__device__ __forceinline__ float fdot2f(unsigned a, unsigned b, float c) {
#if __has_builtin(__builtin_amdgcn_fdot2)
  return __builtin_amdgcn_fdot2(u2h(a), u2h(b), c, false);
#else
  const half2_t ha = u2h(a), hb = u2h(b);
  return c + (float)ha.x * (float)hb.x + (float)ha.y * (float)hb.y;
#endif
}

__device__ __forceinline__ float block_max256(float v, float* red) {
#pragma unroll
  for (int off = 32; off > 0; off >>= 1) v = fmaxf(v, __shfl_xor(v, off, 64));
  __syncthreads();
  if ((threadIdx.x & 63) == 0) red[threadIdx.x >> 6] = v;
  __syncthreads();
  return fmaxf(fmaxf(red[0], red[1]), fmaxf(red[2], red[3]));
}
__device__ __forceinline__ float block_sum256(float v, float* red) {
#pragma unroll
  for (int off = 32; off > 0; off >>= 1) v += __shfl_xor(v, off, 64);
  __syncthreads();
  if ((threadIdx.x & 63) == 0) red[threadIdx.x >> 6] = v;
  __syncthreads();
  return (red[0] + red[1]) + (red[2] + red[3]);
}

// ---------------------------------------------------------------------------
// Kernel 0: pack W fp32 [256][768] into f16 pair-quads Wq[k/8][768].
// grid = (96, 2), block = 256
// ---------------------------------------------------------------------------
__global__ __launch_bounds__(256) void wpack_kernel(
    const float* __restrict__ W_cls, const float* __restrict__ W_reg,
    unsigned* __restrict__ Wp_cls, unsigned* __restrict__ Wp_reg) {
  const int idx = blockIdx.x * 256 + threadIdx.x;
  const int kq = idx / 768, c = idx % 768;
  const float* __restrict__ W = blockIdx.y ? W_reg : W_cls;
  uint4* __restrict__ Wq = (uint4*)(blockIdx.y ? Wp_reg : Wp_cls);
  uint4 o;
  o.x = h2u((half2_t){(_Float16)W[(8 * kq + 0) * 768 + c],
                      (_Float16)W[(8 * kq + 1) * 768 + c]});
  o.y = h2u((half2_t){(_Float16)W[(8 * kq + 2) * 768 + c],
                      (_Float16)W[(8 * kq + 3) * 768 + c]});
  o.z = h2u((half2_t){(_Float16)W[(8 * kq + 4) * 768 + c],
                      (_Float16)W[(8 * kq + 5) * 768 + c]});
  o.w = h2u((half2_t){(_Float16)W[(8 * kq + 6) * 768 + c],
                      (_Float16)W[(8 * kq + 7) * 768 + c]});
  Wq[idx] = o;
}

// ---------------------------------------------------------------------------
// Kernel 1: QKV projection, 8 rows/block (r28). Writes ROW-MAJOR f16 planes
// [h][n][32] for qc/qr/kc/kr/vn (MFMA fragment loads are one 16B read from
// these), transposed v_t[h][d][n] (PV B-operand: 4 contiguous m per lane),
// and v_rm f32 (exact out_x copy half).
// grid = (250, 2), block = 256
// ---------------------------------------------------------------------------
__global__ __launch_bounds__(256) void qkv_norm_kernel(
    const float* __restrict__ x_cls, const float* __restrict__ x_reg,
    const unsigned* __restrict__ Wp_cls, const unsigned* __restrict__ Wp_reg,
    _Float16* __restrict__ qc2, _Float16* __restrict__ qr2,
    _Float16* __restrict__ kc2, _Float16* __restrict__ kr2,
    _Float16* __restrict__ vn2, float* __restrict__ v_rm,
    _Float16* __restrict__ v_t) {
  __shared__ unsigned xs_p[8][128];
  __shared__ float res[8][768];
  __shared__ float inv_norm[192];

  const int n0 = blockIdx.x * 8;
  const int which = blockIdx.y;
  const int tid = threadIdx.x;
  const float* __restrict__ x = which ? x_reg : x_cls;
  const uint4* __restrict__ Wq = (const uint4*)(which ? Wp_reg : Wp_cls);

  if (tid < 128) {
#pragma unroll
    for (int r = 0; r < 8; r++) {
      const float2 xv = ((const float2*)x)[(size_t)(n0 + r) * 128 + tid];
      xs_p[r][tid] = h2u((half2_t){(_Float16)xv.x, (_Float16)xv.y});
    }
  }
  __syncthreads();

  float acc[8][3];
#pragma unroll
  for (int r = 0; r < 8; r++) acc[r][0] = acc[r][1] = acc[r][2] = 0.f;

  for (int kq = 0; kq < 32; kq++) {
    const uint4 w0 = Wq[kq * 768 + tid];
    const uint4 w1 = Wq[kq * 768 + tid + 256];
    const uint4 w2 = Wq[kq * 768 + tid + 512];
#pragma unroll
    for (int r = 0; r < 8; r++) {
      const uint4 xp = *(const uint4*)&xs_p[r][kq * 4];
      acc[r][0] = fdot2f(w0.x, xp.x, acc[r][0]);
      acc[r][0] = fdot2f(w0.y, xp.y, acc[r][0]);
      acc[r][0] = fdot2f(w0.z, xp.z, acc[r][0]);
      acc[r][0] = fdot2f(w0.w, xp.w, acc[r][0]);
      acc[r][1] = fdot2f(w1.x, xp.x, acc[r][1]);
      acc[r][1] = fdot2f(w1.y, xp.y, acc[r][1]);
      acc[r][1] = fdot2f(w1.z, xp.z, acc[r][1]);
      acc[r][1] = fdot2f(w1.w, xp.w, acc[r][1]);
      acc[r][2] = fdot2f(w2.x, xp.x, acc[r][2]);
      acc[r][2] = fdot2f(w2.y, xp.y, acc[r][2]);
      acc[r][2] = fdot2f(w2.z, xp.z, acc[r][2]);
      acc[r][2] = fdot2f(w2.w, xp.w, acc[r][2]);
    }
  }
#pragma unroll
  for (int r = 0; r < 8; r++) {
    res[r][tid] = acc[r][0];
    res[r][tid + 256] = acc[r][1];
    res[r][tid + 512] = acc[r][2];
  }
  __syncthreads();

  if (tid < 192) {
    const int r = tid / 24, grp = tid % 24;
    float ss = 0.f;
#pragma unroll
    for (int d = 0; d < HD; d++) {
      const float v = res[r][grp * 32 + d];
      ss += v * v;
    }
    inv_norm[tid] = 1.0f / (sqrtf(ss) + EPSF);
  }
  __syncthreads();

#pragma unroll
  for (int j = 0; j < 3; j++) {
    const int c = tid + j * 256;
    const int qkv = c >> 8, grp = c >> 5;
    const int h = grp & 7, d = c & 31;
#pragma unroll
    for (int r = 0; r < 8; r++) {
      const int n = n0 + r;
      const float val = res[r][c];
      const float nval = val * inv_norm[r * 24 + grp];
      const size_t fi = ((size_t)(h * N_TOK) + n) * HD + d;
      if (qkv == 0) {
        (which ? qr2 : qc2)[fi] = (_Float16)nval;
      } else if (qkv == 1) {
        (which ? kr2 : kc2)[fi] = (_Float16)nval;
      } else if (which == 0) {
        v_rm[fi] = val;
        vn2[fi] = (_Float16)nval;
        v_t[((size_t)(h * HD) + d) * N_TOK + n] = (_Float16)val;
      }
    }
  }
}

// ---------------------------------------------------------------------------
// Kernel 2 (r31 -> r32): 2-way HEAD SPLIT, grid 250 -> 500. Post-mortem r31:
// LDS dropped to 32 KB but occupancy stayed 11% because GRID = 250 < 256 CUs
// — residency was grid-limited all along, not LDS-limited. Block b handles
// query group b>>1 (QT=8 rows) x heads [(b&1)*4, +4). Per-head softmax and
// per-head out_x columns are block-local; sim/raw (sums over 8 heads) are
// written as PARTIAL planes (sim f32 x2, raw f16 x2) and added in the
// sim_round2 epilogue — race-free, total K/V traffic unchanged (~1.5 GB).
// Per-block state halves: pv 32 regs, qst 7.7 KB, LDS total 24.6 KB ->
// 2 blocks/CU within every cap observed this session.
// grid = 500, block = 256 (4 waves; wave w owns key tiles w, w+4, ...)
// ---------------------------------------------------------------------------
__global__ __launch_bounds__(256) void attn32_kernel(
    const _Float16* __restrict__ qc2, const _Float16* __restrict__ qr2,
    const _Float16* __restrict__ kc2, const _Float16* __restrict__ kr2,
    const _Float16* __restrict__ vn2, const _Float16* __restrict__ v_t,
    const float* __restrict__ v_rm, float* __restrict__ out_x,
    float* __restrict__ sim_ws, _Float16* __restrict__ raw_ws) {
  __shared__ _Float16 qst[3][NHH][QT][40];  // staged Q planes (7.7 KB)
  __shared__ float smem_u[4224];            // 16.9 KB union

  float* __restrict__ sums_l = smem_u;          // [4][2][NHH][16] = 512 f
  float* __restrict__ nrm = smem_u + 512;       // [2][NHH][16] = 128 f
  float* __restrict__ st = smem_u;              // [4][8][20] = 640 f
  float* __restrict__ pvr = smem_u;             // [4][2][16][33] = 4224 f

  const int tid = threadIdx.x;
  const int w = tid >> 6;
  const int l = tid & 63;
  const int qgrp = blockIdx.x >> 1;
  const int hq = (blockIdx.x & 1) * NHH;  // head base for this block
  const int i0 = qgrp * QT;
  float* __restrict__ simp =
      sim_ws + (size_t)(blockIdx.x & 1) * N_TOK * N_TOK;
  _Float16* __restrict__ rawp =
      raw_ws + (size_t)(blockIdx.x & 1) * N_TOK * N_TOK;

  // ---- stage Q: 3 planes x 4 heads x 8 rows x 32 d ----
  if (tid < 128) {
    const int hh = tid >> 5, row = (tid >> 2) & 7, dg = tid & 3;
    const size_t src =
        ((size_t)((hq + hh) * N_TOK) + (i0 + row)) * HD + dg * 8;
    *(uint4*)&qst[0][hh][row][dg * 8] = *(const uint4*)(qc2 + src);
    *(uint4*)&qst[1][hh][row][dg * 8] = *(const uint4*)(qr2 + src);
    *(uint4*)&qst[2][hh][row][dg * 8] = *(const uint4*)(vn2 + src);
  }
  __syncthreads();

  // per-lane constants. q = lane&15 is the MFMA row/col index: for A-frags
  // it is the key row within the tile; for B-frags the query column.
  const int q = l & 15;
  const int kg = l >> 4;  // 0..3
  const int i_glob = i0 + q;           // only meaningful for q < 8
  const int bs = (i_glob / 10) * 10;   // decade start for the mask

  const f32x4 zero4 = {0.f, 0.f, 0.f, 0.f};

  // ======== pass 1: softmax denominators (4 heads) ========
  float sc[NHH], sr[NHH];
#pragma unroll
  for (int hh = 0; hh < NHH; hh++) { sc[hh] = 0.f; sr[hh] = 0.f; }

  for (int t = w; t < NT; t += 4) {
    const int mb = t * 16;
#pragma unroll
    for (int hh = 0; hh < NHH; hh++) {
      const size_t koff =
          ((size_t)((hq + hh) * N_TOK) + mb + q) * HD + kg * 8;
      const f16x8 akc = *(const f16x8*)(kc2 + koff);
      const f16x8 akr = *(const f16x8*)(kr2 + koff);
      const f16x8 bqc = *(const f16x8*)&qst[0][hh][q & 7][kg * 8];
      const f16x8 bqr = *(const f16x8*)&qst[1][hh][q & 7][kg * 8];
      const f32x4 dc =
          __builtin_amdgcn_mfma_f32_16x16x32_f16(akc, bqc, zero4, 0, 0, 0);
      const f32x4 dr =
          __builtin_amdgcn_mfma_f32_16x16x32_f16(akr, bqr, zero4, 0, 0, 0);
#pragma unroll
      for (int i = 0; i < 4; i++) {
        sc[hh] += __expf(dc[i] * SCALE - SCALE);
        sr[hh] += __expf(dr[i] * SCALE - SCALE);
      }
    }
  }
  // lanes {l, l^16, l^32, l^48} share the same query column
#pragma unroll
  for (int hh = 0; hh < NHH; hh++) {
    sc[hh] += __shfl_xor(sc[hh], 16, 64);
    sc[hh] += __shfl_xor(sc[hh], 32, 64);
    sr[hh] += __shfl_xor(sr[hh], 16, 64);
    sr[hh] += __shfl_xor(sr[hh], 32, 64);
  }
  if (l < 16) {
#pragma unroll
    for (int hh = 0; hh < NHH; hh++) {
      sums_l[((w * 2 + 0) * NHH + hh) * 16 + l] = sc[hh];
      sums_l[((w * 2 + 1) * NHH + hh) * 16 + l] = sr[hh];
    }
  }
  __syncthreads();
  if (tid < 128) {
    const int pl = tid >> 6, hh = (tid >> 4) & 3, qq = tid & 15;
    const float s = sums_l[((0 * 2 + pl) * NHH + hh) * 16 + qq] +
                    sums_l[((1 * 2 + pl) * NHH + hh) * 16 + qq] +
                    sums_l[((2 * 2 + pl) * NHH + hh) * 16 + qq] +
                    sums_l[((3 * 2 + pl) * NHH + hh) * 16 + qq];
    nrm[(pl * NHH + hh) * 16 + qq] = 0.5f / s;
  }
  __syncthreads();
  float ncr[NHH], nrr[NHH];
#pragma unroll
  for (int hh = 0; hh < NHH; hh++) {
    ncr[hh] = nrm[(0 * NHH + hh) * 16 + q];
    nrr[hh] = nrm[(1 * NHH + hh) * 16 + q];
  }
  __syncthreads();  // nrm reads done -> st (aliased) may be written

  // ======== pass 2: combine + mask + sim/raw + PV ========
  f32x4 pv[NHH][2];
#pragma unroll
  for (int hh = 0; hh < NHH; hh++) { pv[hh][0] = zero4; pv[hh][1] = zero4; }

  for (int t = w; t < NT; t += 4) {
    const int mb = t * 16;
    f32x4 simt = zero4;
    f32x4 rawt = zero4;
#pragma unroll
    for (int hh = 0; hh < NHH; hh++) {
      const int h = hq + hh;
      const size_t koff = ((size_t)(h * N_TOK) + mb + q) * HD + kg * 8;
      const f16x8 akc = *(const f16x8*)(kc2 + koff);
      const f16x8 akr = *(const f16x8*)(kr2 + koff);
      const f16x8 avn = *(const f16x8*)(vn2 + koff);
      const f16x8 bqc = *(const f16x8*)&qst[0][hh][q & 7][kg * 8];
      const f16x8 bqr = *(const f16x8*)&qst[1][hh][q & 7][kg * 8];
      const f16x8 bqv = *(const f16x8*)&qst[2][hh][q & 7][kg * 8];
      const f32x4 dc =
          __builtin_amdgcn_mfma_f32_16x16x32_f16(akc, bqc, zero4, 0, 0, 0);
      const f32x4 dr =
          __builtin_amdgcn_mfma_f32_16x16x32_f16(akr, bqr, zero4, 0, 0, 0);
      // raw accumulates over this block's heads via the C operand
      rawt = __builtin_amdgcn_mfma_f32_16x16x32_f16(avn, bqv, rawt, 0, 0, 0);

      f16x4 pa;
#pragma unroll
      for (int i = 0; i < 4; i++) {
        const float ec = __expf(dc[i] * SCALE - SCALE);
        const float er = __expf(dr[i] * SCALE - SCALE);
        float ai = ncr[hh] * ec + nrr[hh] * er;
        const int m = mb + kg * 4 + i;
        if (m >= bs && m < bs + 9 && m != i_glob) ai = 0.f;
        simt[i] += ai;
        pa[i] = (_Float16)ai;
      }
      // PV: D^T reg order == A-frag (k = 4*kg + i) of the K=16 mfma
      const f16x4 bv0 = *(const f16x4*)(
          v_t + ((size_t)(h * HD) + q) * N_TOK + mb + kg * 4);
      const f16x4 bv1 = *(const f16x4*)(
          v_t + ((size_t)(h * HD) + 16 + q) * N_TOK + mb + kg * 4);
      pv[hh][0] =
          __builtin_amdgcn_mfma_f32_16x16x16f16(pa, bv0, pv[hh][0], 0, 0, 0);
      pv[hh][1] =
          __builtin_amdgcn_mfma_f32_16x16x16f16(pa, bv1, pv[hh][1], 0, 0, 0);
    }
    // ---- stream partial sim tile (f32) via wave-local LDS bounce ----
    if (q < 8) {
#pragma unroll
      for (int i = 0; i < 4; i++) st[(w * 8 + q) * 20 + kg * 4 + i] = simt[i];
    }
    if (l < 32) {
      const int qq = l >> 2, mo = (l & 3) * 4;
      const float4 v4 = *(const float4*)&st[(w * 8 + qq) * 20 + mo];
      *(float4*)(simp + (size_t)(i0 + qq) * N_TOK + mb + mo) = v4;
    }
    // ---- stream partial raw tile (f16) ----
    if (q < 8) {
#pragma unroll
      for (int i = 0; i < 4; i++) st[(w * 8 + q) * 20 + kg * 4 + i] = rawt[i];
    }
    if (l < 32) {
      const int qq = l >> 2, mo = (l & 3) * 4;
      const float4 v4 = *(const float4*)&st[(w * 8 + qq) * 20 + mo];
      uint2 u;
      u.x = h2u((half2_t){(_Float16)v4.x, (_Float16)v4.y});
      u.y = h2u((half2_t){(_Float16)v4.z, (_Float16)v4.w});
      *(uint2*)(rawp + (size_t)(i0 + qq) * N_TOK + mb + mo) = u;
    }
  }

  // ======== PV cross-wave reduction + out_x, 2 head-groups of 2 ========
#pragma unroll
  for (int hg = 0; hg < 2; hg++) {
    __syncthreads();  // st reads / previous group's pvr reads done
#pragma unroll
    for (int h2 = 0; h2 < 2; h2++) {
      const int hh = hg * 2 + h2;
#pragma unroll
      for (int i = 0; i < 4; i++) {
        pvr[((w * 2 + h2) * 16 + kg * 4 + i) * 33 + q] = pv[hh][0][i];
        pvr[((w * 2 + h2) * 16 + kg * 4 + i) * 33 + 16 + q] = pv[hh][1][i];
      }
    }
    __syncthreads();
    {
      const int h2 = tid >> 7, qg2 = (tid >> 5) & 3, d = tid & 31;
#pragma unroll
      for (int qi = 0; qi < 2; qi++) {
        const int qq = qg2 * 2 + qi;
        float s = 0.f;
#pragma unroll
        for (int wv = 0; wv < 4; wv++) {
          s += pvr[((wv * 2 + h2) * 16 + qq) * 33 + d];
        }
        out_x[(size_t)(i0 + qq) * 512 + (hq + hg * 2 + h2) * 32 + d] = s;
      }
    }
  }
  // ---- v_rm copy half for this block's 4 heads ----
  if (tid < 128) {
    const int hh = tid >> 5, d = tid & 31;
    const int h = hq + hh;
#pragma unroll
    for (int qq = 0; qq < QT; qq++) {
      out_x[(size_t)(i0 + qq) * 512 + 256 + h * 32 + d] =
          v_rm[((size_t)(h * N_TOK) + i0 + qq) * HD + d];
    }
  }
}

// ---------------------------------------------------------------------------
// Kernel 3: sim_round2 epilogue; adds the two head-half partial planes.
// grid = 250, block = 256; 8 rows per block.
// ---------------------------------------------------------------------------
__global__ __launch_bounds__(256) void sim_round2_kernel(
    const float* __restrict__ sim_ws, const _Float16* __restrict__ raw_ws,
    float* __restrict__ out_sim) {
  __shared__ float red[16];
  const int tid = threadIdx.x;
  const int i0 = blockIdx.x * 8;
  const size_t NN = (size_t)N_TOK * N_TOK;
  for (int r = 0; r < 8; r++) {
    const int i = i0 + r;
    float s[8], rw[8];
#pragma unroll
    for (int t = 0; t < 8; t++) {
      const int m = tid + 256 * t;
      const bool valid = (t < 7) || (tid < 208);
      const size_t idx = (size_t)i * N_TOK + m;
      s[t] = valid ? (sim_ws[idx] + sim_ws[NN + idx]) * 0.125f : -1e30f;
      rw[t] = valid ? ((float)raw_ws[idx] + (float)raw_ws[NN + idx]) : 0.f;
    }
    float lm = -1e30f;
#pragma unroll
    for (int t = 0; t < 8; t++) lm = fmaxf(lm, s[t]);
    const float M = block_max256(lm, red);
    float ls = 0.f;
#pragma unroll
    for (int t = 0; t < 8; t++) {
      const bool valid = (t < 7) || (tid < 208);
      const float e = valid ? __expf(s[t] - M) : 0.f;
      s[t] = e;
      ls += e;
    }
    const float S = block_sum256(ls, red);
    const float invS = 1.0f / S;
    float lms = 0.f;
#pragma unroll
    for (int t = 0; t < 8; t++) {
      const bool valid = (t < 7) || (tid < 208);
      const float p = s[t] * invS;
      const float mp = (valid && (rw[t] * 0.125f > SIM_TH)) ? p : 0.f;
      s[t] = mp;
      lms += mp;
    }
    const float MS = block_sum256(lms, red);
    const float invMS = 1.0f / (MS + EPSF);
#pragma unroll
    for (int t = 0; t < 8; t++) {
      const int m = tid + 256 * t;
      if ((t < 7) || (tid < 208)) {
        out_sim[(size_t)i * N_TOK + m] = s[t] * invMS;
      }
    }
  }
}

// ---------------------------------------------------------------------------
extern "C" void kernel_launch(void* const* d_in, const int* in_sizes, int n_in,
                              void* d_out, int out_size, void* d_ws,
                              size_t ws_size, hipStream_t stream) {
  const float* x_cls = (const float*)d_in[0];
  const float* x_reg = (const float*)d_in[1];
  const float* W_cls = (const float*)d_in[2];
  const float* W_reg = (const float*)d_in[3];

  // ws layout (~57 MB): v_rm f32, 6 f16 planes, sim f32 x2 partial planes,
  // raw f16 x2 partial planes, packed W.
  const size_t seg = (size_t)NH * N_TOK * HD;  // 512000 elements
  float* v_rm = (float*)d_ws;
  _Float16* qc2 = (_Float16*)(v_rm + seg);
  _Float16* qr2 = qc2 + seg;
  _Float16* kc2 = qr2 + seg;
  _Float16* kr2 = kc2 + seg;
  _Float16* vn2 = kr2 + seg;
  _Float16* v_t = vn2 + seg;
  float* sim_ws = (float*)(v_t + seg);  // 2 x N*N f32
  _Float16* raw_ws =
      (_Float16*)(sim_ws + 2 * (size_t)N_TOK * N_TOK);  // 2 x N*N f16
  unsigned* Wp_cls = (unsigned*)(raw_ws + 2 * (size_t)N_TOK * N_TOK);
  unsigned* Wp_reg = Wp_cls + 98304;

  dim3 g0(96, 2);
  wpack_kernel<<<g0, 256, 0, stream>>>(W_cls, W_reg, Wp_cls, Wp_reg);

  dim3 g1(250, 2);
  qkv_norm_kernel<<<g1, 256, 0, stream>>>(x_cls, x_reg, Wp_cls, Wp_reg, qc2,
                                          qr2, kc2, kr2, vn2, v_rm, v_t);

  float* out_x = (float*)d_out;                  // [2000, 512]
  float* out_sim = out_x + (size_t)N_TOK * 512;  // [2000, 2000]
  attn32_kernel<<<500, 256, 0, stream>>>(qc2, qr2, kc2, kr2, vn2, v_t, v_rm,
                                         out_x, sim_ws, raw_ws);
  sim_round2_kernel<<<250, 256, 0, stream>>>(sim_ws, raw_ws, out_sim);
}

// Round 12
// 182.990 us; speedup vs baseline: 2.7457x; 1.2027x over previous
//
#include <hip/hip_runtime.h>
#include <math.h>

#define N_TOK 2000
#define NH 8
#define NHH 2   // heads per attn block (4-way head split)
#define HD 32
#define SCALE 25.0f
#define SIM_TH 0.75f
#define EPSF 1e-8f
#define NT 125  // key tiles of 16 (125*16 = 2000 exact)
#define QT 16   // query rows per attn block — ALL 16 MFMA cols real

typedef _Float16 half2_t __attribute__((ext_vector_type(2)));
typedef _Float16 f16x4 __attribute__((ext_vector_type(4)));
typedef _Float16 f16x8 __attribute__((ext_vector_type(8)));
typedef float f32x4 __attribute__((ext_vector_type(4)));

__device__ __forceinline__ half2_t u2h(unsigned u) {
  return __builtin_bit_cast(half2_t, u);
}
__device__ __forceinline__ unsigned h2u(half2_t h) {
  return __builtin_bit_cast(unsigned, h);
}

// f32 += f16x2 . f16x2 (v_dot2_f32_f16; products exact, fp32 accumulate)
__device__ __forceinline__ float fdot2f(unsigned a, unsigned b, float c) {
#if __has_builtin(__builtin_amdgcn_fdot2)
  return __builtin_amdgcn_fdot2(u2h(a), u2h(b), c, false);
#else
  const half2_t ha = u2h(a), hb = u2h(b);
  return c + (float)ha.x * (float)hb.x + (float)ha.y * (float)hb.y;
#endif
}

__device__ __forceinline__ float block_max256(float v, float* red) {
#pragma unroll
  for (int off = 32; off > 0; off >>= 1) v = fmaxf(v, __shfl_xor(v, off, 64));
  __syncthreads();
  if ((threadIdx.x & 63) == 0) red[threadIdx.x >> 6] = v;
  __syncthreads();
  return fmaxf(fmaxf(red[0], red[1]), fmaxf(red[2], red[3]));
}
__device__ __forceinline__ float block_sum256(float v, float* red) {
#pragma unroll
  for (int off = 32; off > 0; off >>= 1) v += __shfl_xor(v, off, 64);
  __syncthreads();
  if ((threadIdx.x & 63) == 0) red[threadIdx.x >> 6] = v;
  __syncthreads();
  return (red[0] + red[1]) + (red[2] + red[3]);
}

// ---------------------------------------------------------------------------
// Kernel 0: pack W fp32 [256][768] into f16 pair-quads Wq[k/8][768].
// grid = (96, 2), block = 256
// ---------------------------------------------------------------------------
__global__ __launch_bounds__(256) void wpack_kernel(
    const float* __restrict__ W_cls, const float* __restrict__ W_reg,
    unsigned* __restrict__ Wp_cls, unsigned* __restrict__ Wp_reg) {
  const int idx = blockIdx.x * 256 + threadIdx.x;
  const int kq = idx / 768, c = idx % 768;
  const float* __restrict__ W = blockIdx.y ? W_reg : W_cls;
  uint4* __restrict__ Wq = (uint4*)(blockIdx.y ? Wp_reg : Wp_cls);
  uint4 o;
  o.x = h2u((half2_t){(_Float16)W[(8 * kq + 0) * 768 + c],
                      (_Float16)W[(8 * kq + 1) * 768 + c]});
  o.y = h2u((half2_t){(_Float16)W[(8 * kq + 2) * 768 + c],
                      (_Float16)W[(8 * kq + 3) * 768 + c]});
  o.z = h2u((half2_t){(_Float16)W[(8 * kq + 4) * 768 + c],
                      (_Float16)W[(8 * kq + 5) * 768 + c]});
  o.w = h2u((half2_t){(_Float16)W[(8 * kq + 6) * 768 + c],
                      (_Float16)W[(8 * kq + 7) * 768 + c]});
  Wq[idx] = o;
}

// ---------------------------------------------------------------------------
// Kernel 1: QKV projection, 8 rows/block (r28). Writes ROW-MAJOR f16 planes
// [h][n][32] for qc/qr/kc/kr/vn, transposed v_t[h][d][n], v_rm f32.
// grid = (250, 2), block = 256
// ---------------------------------------------------------------------------
__global__ __launch_bounds__(256) void qkv_norm_kernel(
    const float* __restrict__ x_cls, const float* __restrict__ x_reg,
    const unsigned* __restrict__ Wp_cls, const unsigned* __restrict__ Wp_reg,
    _Float16* __restrict__ qc2, _Float16* __restrict__ qr2,
    _Float16* __restrict__ kc2, _Float16* __restrict__ kr2,
    _Float16* __restrict__ vn2, float* __restrict__ v_rm,
    _Float16* __restrict__ v_t) {
  __shared__ unsigned xs_p[8][128];
  __shared__ float res[8][768];
  __shared__ float inv_norm[192];

  const int n0 = blockIdx.x * 8;
  const int which = blockIdx.y;
  const int tid = threadIdx.x;
  const float* __restrict__ x = which ? x_reg : x_cls;
  const uint4* __restrict__ Wq = (const uint4*)(which ? Wp_reg : Wp_cls);

  if (tid < 128) {
#pragma unroll
    for (int r = 0; r < 8; r++) {
      const float2 xv = ((const float2*)x)[(size_t)(n0 + r) * 128 + tid];
      xs_p[r][tid] = h2u((half2_t){(_Float16)xv.x, (_Float16)xv.y});
    }
  }
  __syncthreads();

  float acc[8][3];
#pragma unroll
  for (int r = 0; r < 8; r++) acc[r][0] = acc[r][1] = acc[r][2] = 0.f;

  for (int kq = 0; kq < 32; kq++) {
    const uint4 w0 = Wq[kq * 768 + tid];
    const uint4 w1 = Wq[kq * 768 + tid + 256];
    const uint4 w2 = Wq[kq * 768 + tid + 512];
#pragma unroll
    for (int r = 0; r < 8; r++) {
      const uint4 xp = *(const uint4*)&xs_p[r][kq * 4];
      acc[r][0] = fdot2f(w0.x, xp.x, acc[r][0]);
      acc[r][0] = fdot2f(w0.y, xp.y, acc[r][0]);
      acc[r][0] = fdot2f(w0.z, xp.z, acc[r][0]);
      acc[r][0] = fdot2f(w0.w, xp.w, acc[r][0]);
      acc[r][1] = fdot2f(w1.x, xp.x, acc[r][1]);
      acc[r][1] = fdot2f(w1.y, xp.y, acc[r][1]);
      acc[r][1] = fdot2f(w1.z, xp.z, acc[r][1]);
      acc[r][1] = fdot2f(w1.w, xp.w, acc[r][1]);
      acc[r][2] = fdot2f(w2.x, xp.x, acc[r][2]);
      acc[r][2] = fdot2f(w2.y, xp.y, acc[r][2]);
      acc[r][2] = fdot2f(w2.z, xp.z, acc[r][2]);
      acc[r][2] = fdot2f(w2.w, xp.w, acc[r][2]);
    }
  }
#pragma unroll
  for (int r = 0; r < 8; r++) {
    res[r][tid] = acc[r][0];
    res[r][tid + 256] = acc[r][1];
    res[r][tid + 512] = acc[r][2];
  }
  __syncthreads();

  if (tid < 192) {
    const int r = tid / 24, grp = tid % 24;
    float ss = 0.f;
#pragma unroll
    for (int d = 0; d < HD; d++) {
      const float v = res[r][grp * 32 + d];
      ss += v * v;
    }
    inv_norm[tid] = 1.0f / (sqrtf(ss) + EPSF);
  }
  __syncthreads();

#pragma unroll
  for (int j = 0; j < 3; j++) {
    const int c = tid + j * 256;
    const int qkv = c >> 8, grp = c >> 5;
    const int h = grp & 7, d = c & 31;
#pragma unroll
    for (int r = 0; r < 8; r++) {
      const int n = n0 + r;
      const float val = res[r][c];
      const float nval = val * inv_norm[r * 24 + grp];
      const size_t fi = ((size_t)(h * N_TOK) + n) * HD + d;
      if (qkv == 0) {
        (which ? qr2 : qc2)[fi] = (_Float16)nval;
      } else if (qkv == 1) {
        (which ? kr2 : kc2)[fi] = (_Float16)nval;
      } else if (which == 0) {
        v_rm[fi] = val;
        vn2[fi] = (_Float16)nval;
        v_t[((size_t)(h * HD) + d) * N_TOK + n] = (_Float16)val;
      }
    }
  }
}

// ---------------------------------------------------------------------------
// Kernel 2 (r32 -> r33): QT 8->16, NHH 4->2. Post-mortem r32: head split
// worked (occ 20%, attn 122us), but HALF of every QK/VN MFMA tile was
// duplicated query rows (waste). QT=16 makes all 16 MFMA cols real queries;
// NHH=2 keeps grid at 500 (125 qgroups x 4 head-pairs). Per-block MFMA, exp,
// mask VALU, and K-plane traffic all HALVE at constant useful output and
// constant concurrency. sim/raw partials: 4 f16 planes each (head-pairs),
// summed in the epilogue; f16 partial err ~1e-3 << 0.0156 absmax budget.
// grid = 500, block = 256 (4 waves; wave w owns key tiles w, w+4, ...)
// ---------------------------------------------------------------------------
__global__ __launch_bounds__(256) void attn33_kernel(
    const _Float16* __restrict__ qc2, const _Float16* __restrict__ qr2,
    const _Float16* __restrict__ kc2, const _Float16* __restrict__ kr2,
    const _Float16* __restrict__ vn2, const _Float16* __restrict__ v_t,
    const float* __restrict__ v_rm, float* __restrict__ out_x,
    _Float16* __restrict__ sim_ws, _Float16* __restrict__ raw_ws) {
  __shared__ _Float16 qst[3][NHH][QT][40];  // staged Q planes (7.7 KB)
  __shared__ float smem_u[4224];            // 16.9 KB union

  float* __restrict__ sums_l = smem_u;          // [4][2][NHH][16] = 256 f
  float* __restrict__ nrm = smem_u + 256;       // [2][NHH][16] = 64 f
  float* __restrict__ st = smem_u;              // [4][16][20] = 1280 f
  float* __restrict__ pvr = smem_u;             // [4][2][16][33] = 4224 f

  const int tid = threadIdx.x;
  const int w = tid >> 6;
  const int l = tid & 63;
  const int qgrp = blockIdx.x >> 2;
  const int hp = blockIdx.x & 3;   // head pair index
  const int hq = hp * NHH;         // head base for this block
  const int i0 = qgrp * QT;
  _Float16* __restrict__ simp = sim_ws + (size_t)hp * N_TOK * N_TOK;
  _Float16* __restrict__ rawp = raw_ws + (size_t)hp * N_TOK * N_TOK;

  // ---- stage Q: 3 planes x 2 heads x 16 rows x 32 d ----
  if (tid < 128) {
    const int hh = tid >> 6, row = (tid >> 2) & 15, dg = tid & 3;
    const size_t src =
        ((size_t)((hq + hh) * N_TOK) + (i0 + row)) * HD + dg * 8;
    *(uint4*)&qst[0][hh][row][dg * 8] = *(const uint4*)(qc2 + src);
    *(uint4*)&qst[1][hh][row][dg * 8] = *(const uint4*)(qr2 + src);
    *(uint4*)&qst[2][hh][row][dg * 8] = *(const uint4*)(vn2 + src);
  }
  __syncthreads();

  // per-lane constants. q = lane&15: real query column AND (for A-frags)
  // the key row within the tile.
  const int q = l & 15;
  const int kg = l >> 4;  // 0..3
  const int i_glob = i0 + q;           // real query index (all 16 real)
  const int bs = (i_glob / 10) * 10;   // decade start for the mask

  const f32x4 zero4 = {0.f, 0.f, 0.f, 0.f};

  // ======== pass 1: softmax denominators (2 heads) ========
  float sc[NHH], sr[NHH];
#pragma unroll
  for (int hh = 0; hh < NHH; hh++) { sc[hh] = 0.f; sr[hh] = 0.f; }

  for (int t = w; t < NT; t += 4) {
    const int mb = t * 16;
#pragma unroll
    for (int hh = 0; hh < NHH; hh++) {
      const size_t koff =
          ((size_t)((hq + hh) * N_TOK) + mb + q) * HD + kg * 8;
      const f16x8 akc = *(const f16x8*)(kc2 + koff);
      const f16x8 akr = *(const f16x8*)(kr2 + koff);
      const f16x8 bqc = *(const f16x8*)&qst[0][hh][q][kg * 8];
      const f16x8 bqr = *(const f16x8*)&qst[1][hh][q][kg * 8];
      const f32x4 dc =
          __builtin_amdgcn_mfma_f32_16x16x32_f16(akc, bqc, zero4, 0, 0, 0);
      const f32x4 dr =
          __builtin_amdgcn_mfma_f32_16x16x32_f16(akr, bqr, zero4, 0, 0, 0);
#pragma unroll
      for (int i = 0; i < 4; i++) {
        sc[hh] += __expf(dc[i] * SCALE - SCALE);
        sr[hh] += __expf(dr[i] * SCALE - SCALE);
      }
    }
  }
  // lanes {l, l^16, l^32, l^48} share the same query column
#pragma unroll
  for (int hh = 0; hh < NHH; hh++) {
    sc[hh] += __shfl_xor(sc[hh], 16, 64);
    sc[hh] += __shfl_xor(sc[hh], 32, 64);
    sr[hh] += __shfl_xor(sr[hh], 16, 64);
    sr[hh] += __shfl_xor(sr[hh], 32, 64);
  }
  if (l < 16) {
#pragma unroll
    for (int hh = 0; hh < NHH; hh++) {
      sums_l[((w * 2 + 0) * NHH + hh) * 16 + l] = sc[hh];
      sums_l[((w * 2 + 1) * NHH + hh) * 16 + l] = sr[hh];
    }
  }
  __syncthreads();
  if (tid < 64) {
    const int pl = tid >> 5, hh = (tid >> 4) & 1, qq = tid & 15;
    const float s = sums_l[((0 * 2 + pl) * NHH + hh) * 16 + qq] +
                    sums_l[((1 * 2 + pl) * NHH + hh) * 16 + qq] +
                    sums_l[((2 * 2 + pl) * NHH + hh) * 16 + qq] +
                    sums_l[((3 * 2 + pl) * NHH + hh) * 16 + qq];
    nrm[(pl * NHH + hh) * 16 + qq] = 0.5f / s;
  }
  __syncthreads();
  float ncr[NHH], nrr[NHH];
#pragma unroll
  for (int hh = 0; hh < NHH; hh++) {
    ncr[hh] = nrm[(0 * NHH + hh) * 16 + q];
    nrr[hh] = nrm[(1 * NHH + hh) * 16 + q];
  }
  __syncthreads();  // nrm reads done -> st (aliased) may be written

  // ======== pass 2: combine + mask + sim/raw + PV ========
  f32x4 pv[NHH][2];
#pragma unroll
  for (int hh = 0; hh < NHH; hh++) { pv[hh][0] = zero4; pv[hh][1] = zero4; }

  for (int t = w; t < NT; t += 4) {
    const int mb = t * 16;
    f32x4 simt = zero4;
    f32x4 rawt = zero4;
#pragma unroll
    for (int hh = 0; hh < NHH; hh++) {
      const int h = hq + hh;
      const size_t koff = ((size_t)(h * N_TOK) + mb + q) * HD + kg * 8;
      const f16x8 akc = *(const f16x8*)(kc2 + koff);
      const f16x8 akr = *(const f16x8*)(kr2 + koff);
      const f16x8 avn = *(const f16x8*)(vn2 + koff);
      const f16x8 bqc = *(const f16x8*)&qst[0][hh][q][kg * 8];
      const f16x8 bqr = *(const f16x8*)&qst[1][hh][q][kg * 8];
      const f16x8 bqv = *(const f16x8*)&qst[2][hh][q][kg * 8];
      const f32x4 dc =
          __builtin_amdgcn_mfma_f32_16x16x32_f16(akc, bqc, zero4, 0, 0, 0);
      const f32x4 dr =
          __builtin_amdgcn_mfma_f32_16x16x32_f16(akr, bqr, zero4, 0, 0, 0);
      // raw accumulates over this block's heads via the C operand
      rawt = __builtin_amdgcn_mfma_f32_16x16x32_f16(avn, bqv, rawt, 0, 0, 0);

      f16x4 pa;
#pragma unroll
      for (int i = 0; i < 4; i++) {
        const float ec = __expf(dc[i] * SCALE - SCALE);
        const float er = __expf(dr[i] * SCALE - SCALE);
        float ai = ncr[hh] * ec + nrr[hh] * er;
        const int m = mb + kg * 4 + i;
        if (m >= bs && m < bs + 9 && m != i_glob) ai = 0.f;
        simt[i] += ai;
        pa[i] = (_Float16)ai;
      }
      // PV: D^T reg order == A-frag (k = 4*kg + i) of the K=16 mfma
      const f16x4 bv0 = *(const f16x4*)(
          v_t + ((size_t)(h * HD) + q) * N_TOK + mb + kg * 4);
      const f16x4 bv1 = *(const f16x4*)(
          v_t + ((size_t)(h * HD) + 16 + q) * N_TOK + mb + kg * 4);
      pv[hh][0] =
          __builtin_amdgcn_mfma_f32_16x16x16f16(pa, bv0, pv[hh][0], 0, 0, 0);
      pv[hh][1] =
          __builtin_amdgcn_mfma_f32_16x16x16f16(pa, bv1, pv[hh][1], 0, 0, 0);
    }
    // ---- stream partial sim tile (f16): 16 rows x 16 cols per wave ----
    st[(w * 16 + q) * 20 + kg * 4 + 0] = simt[0];
    st[(w * 16 + q) * 20 + kg * 4 + 1] = simt[1];
    st[(w * 16 + q) * 20 + kg * 4 + 2] = simt[2];
    st[(w * 16 + q) * 20 + kg * 4 + 3] = simt[3];
    {
      const int row = l >> 2, mo = (l & 3) * 4;
      const float4 v4 = *(const float4*)&st[(w * 16 + row) * 20 + mo];
      uint2 u;
      u.x = h2u((half2_t){(_Float16)v4.x, (_Float16)v4.y});
      u.y = h2u((half2_t){(_Float16)v4.z, (_Float16)v4.w});
      *(uint2*)(simp + (size_t)(i0 + row) * N_TOK + mb + mo) = u;
    }
    // ---- stream partial raw tile (f16) ----
    st[(w * 16 + q) * 20 + kg * 4 + 0] = rawt[0];
    st[(w * 16 + q) * 20 + kg * 4 + 1] = rawt[1];
    st[(w * 16 + q) * 20 + kg * 4 + 2] = rawt[2];
    st[(w * 16 + q) * 20 + kg * 4 + 3] = rawt[3];
    {
      const int row = l >> 2, mo = (l & 3) * 4;
      const float4 v4 = *(const float4*)&st[(w * 16 + row) * 20 + mo];
      uint2 u;
      u.x = h2u((half2_t){(_Float16)v4.x, (_Float16)v4.y});
      u.y = h2u((half2_t){(_Float16)v4.z, (_Float16)v4.w});
      *(uint2*)(rawp + (size_t)(i0 + row) * N_TOK + mb + mo) = u;
    }
  }

  // ======== PV cross-wave reduction + out_x (2 heads, 16 queries) ========
  __syncthreads();  // st reads done -> pvr (aliased) may be written
#pragma unroll
  for (int hh = 0; hh < NHH; hh++) {
#pragma unroll
    for (int i = 0; i < 4; i++) {
      pvr[((w * 2 + hh) * 16 + kg * 4 + i) * 33 + q] = pv[hh][0][i];
      pvr[((w * 2 + hh) * 16 + kg * 4 + i) * 33 + 16 + q] = pv[hh][1][i];
    }
  }
  __syncthreads();
  {
    const int hh = tid >> 7, qg2 = (tid >> 5) & 3, d = tid & 31;
#pragma unroll
    for (int qi = 0; qi < 4; qi++) {
      const int qq = qg2 * 4 + qi;
      float s = 0.f;
#pragma unroll
      for (int wv = 0; wv < 4; wv++) {
        s += pvr[((wv * 2 + hh) * 16 + qq) * 33 + d];
      }
      out_x[(size_t)(i0 + qq) * 512 + (hq + hh) * 32 + d] = s;
    }
  }
  // ---- v_rm copy half for this block's 2 heads ----
  if (tid < 64) {
    const int hh = tid >> 5, d = tid & 31;
    const int h = hq + hh;
#pragma unroll
    for (int qq = 0; qq < QT; qq++) {
      out_x[(size_t)(i0 + qq) * 512 + 256 + h * 32 + d] =
          v_rm[((size_t)(h * N_TOK) + i0 + qq) * HD + d];
    }
  }
}

// ---------------------------------------------------------------------------
// Kernel 3: sim_round2 epilogue; sums the 4 head-pair partial planes.
// grid = 250, block = 256; 8 rows per block.
// ---------------------------------------------------------------------------
__global__ __launch_bounds__(256) void sim_round2_kernel(
    const _Float16* __restrict__ sim_ws, const _Float16* __restrict__ raw_ws,
    float* __restrict__ out_sim) {
  __shared__ float red[16];
  const int tid = threadIdx.x;
  const int i0 = blockIdx.x * 8;
  const size_t NN = (size_t)N_TOK * N_TOK;
  for (int r = 0; r < 8; r++) {
    const int i = i0 + r;
    float s[8], rw[8];
#pragma unroll
    for (int t = 0; t < 8; t++) {
      const int m = tid + 256 * t;
      const bool valid = (t < 7) || (tid < 208);
      const size_t idx = (size_t)i * N_TOK + m;
      if (valid) {
        s[t] = ((float)sim_ws[idx] + (float)sim_ws[NN + idx] +
                (float)sim_ws[2 * NN + idx] + (float)sim_ws[3 * NN + idx]) *
               0.125f;
        rw[t] = (float)raw_ws[idx] + (float)raw_ws[NN + idx] +
                (float)raw_ws[2 * NN + idx] + (float)raw_ws[3 * NN + idx];
      } else {
        s[t] = -1e30f;
        rw[t] = 0.f;
      }
    }
    float lm = -1e30f;
#pragma unroll
    for (int t = 0; t < 8; t++) lm = fmaxf(lm, s[t]);
    const float M = block_max256(lm, red);
    float ls = 0.f;
#pragma unroll
    for (int t = 0; t < 8; t++) {
      const bool valid = (t < 7) || (tid < 208);
      const float e = valid ? __expf(s[t] - M) : 0.f;
      s[t] = e;
      ls += e;
    }
    const float S = block_sum256(ls, red);
    const float invS = 1.0f / S;
    float lms = 0.f;
#pragma unroll
    for (int t = 0; t < 8; t++) {
      const bool valid = (t < 7) || (tid < 208);
      const float p = s[t] * invS;
      const float mp = (valid && (rw[t] * 0.125f > SIM_TH)) ? p : 0.f;
      s[t] = mp;
      lms += mp;
    }
    const float MS = block_sum256(lms, red);
    const float invMS = 1.0f / (MS + EPSF);
#pragma unroll
    for (int t = 0; t < 8; t++) {
      const int m = tid + 256 * t;
      if ((t < 7) || (tid < 208)) {
        out_sim[(size_t)i * N_TOK + m] = s[t] * invMS;
      }
    }
  }
}

// ---------------------------------------------------------------------------
extern "C" void kernel_launch(void* const* d_in, const int* in_sizes, int n_in,
                              void* d_out, int out_size, void* d_ws,
                              size_t ws_size, hipStream_t stream) {
  const float* x_cls = (const float*)d_in[0];
  const float* x_reg = (const float*)d_in[1];
  const float* W_cls = (const float*)d_in[2];
  const float* W_reg = (const float*)d_in[3];

  // ws layout (~73 MB): v_rm f32, 6 f16 planes, sim f16 x4 partial planes,
  // raw f16 x4 partial planes, packed W.
  const size_t seg = (size_t)NH * N_TOK * HD;  // 512000 elements
  float* v_rm = (float*)d_ws;
  _Float16* qc2 = (_Float16*)(v_rm + seg);
  _Float16* qr2 = qc2 + seg;
  _Float16* kc2 = qr2 + seg;
  _Float16* kr2 = kc2 + seg;
  _Float16* vn2 = kr2 + seg;
  _Float16* v_t = vn2 + seg;
  _Float16* sim_ws = v_t + seg;  // 4 x N*N f16
  _Float16* raw_ws = sim_ws + 4 * (size_t)N_TOK * N_TOK;  // 4 x N*N f16
  unsigned* Wp_cls = (unsigned*)(raw_ws + 4 * (size_t)N_TOK * N_TOK);
  unsigned* Wp_reg = Wp_cls + 98304;

  dim3 g0(96, 2);
  wpack_kernel<<<g0, 256, 0, stream>>>(W_cls, W_reg, Wp_cls, Wp_reg);

  dim3 g1(250, 2);
  qkv_norm_kernel<<<g1, 256, 0, stream>>>(x_cls, x_reg, Wp_cls, Wp_reg, qc2,
                                          qr2, kc2, kr2, vn2, v_rm, v_t);

  float* out_x = (float*)d_out;                  // [2000, 512]
  float* out_sim = out_x + (size_t)N_TOK * 512;  // [2000, 2000]
  attn33_kernel<<<500, 256, 0, stream>>>(qc2, qr2, kc2, kr2, vn2, v_t, v_rm,
                                         out_x, sim_ws, raw_ws);
  sim_round2_kernel<<<250, 256, 0, stream>>>(sim_ws, raw_ws, out_sim);
}

// Round 13
// 177.242 us; speedup vs baseline: 2.8348x; 1.0324x over previous
//
#include <hip/hip_runtime.h>
#include <math.h>

#define N_TOK 2000
#define NH 8
#define NHH 2   // heads per attn block (4-way head split)
#define HD 32
#define SCALE 25.0f
#define SIM_TH 0.75f
#define EPSF 1e-8f
#define NT 125  // key tiles of 16 (125*16 = 2000 exact)
#define QT 16   // query rows per attn block — ALL 16 MFMA cols real

typedef _Float16 half2_t __attribute__((ext_vector_type(2)));
typedef _Float16 f16x4 __attribute__((ext_vector_type(4)));
typedef _Float16 f16x8 __attribute__((ext_vector_type(8)));
typedef float f32x4 __attribute__((ext_vector_type(4)));

__device__ __forceinline__ half2_t u2h(unsigned u) {
  return __builtin_bit_cast(half2_t, u);
}
__device__ __forceinline__ unsigned h2u(half2_t h) {
  return __builtin_bit_cast(unsigned, h);
}

__device__ __forceinline__ float block_max256(float v, float* red) {
#pragma unroll
  for (int off = 32; off > 0; off >>= 1) v = fmaxf(v, __shfl_xor(v, off, 64));
  __syncthreads();
  if ((threadIdx.x & 63) == 0) red[threadIdx.x >> 6] = v;
  __syncthreads();
  return fmaxf(fmaxf(red[0], red[1]), fmaxf(red[2], red[3]));
}
__device__ __forceinline__ float block_sum256(float v, float* red) {
#pragma unroll
  for (int off = 32; off > 0; off >>= 1) v += __shfl_xor(v, off, 64);
  __syncthreads();
  if ((threadIdx.x & 63) == 0) red[threadIdx.x >> 6] = v;
  __syncthreads();
  return (red[0] + red[1]) + (red[2] + red[3]);
}

// ---------------------------------------------------------------------------
// Kernel 0 (r33 -> r34): pack W fp32 [256][768] TRANSPOSED into f16
// Wt[768][256] — MFMA A-operand rows are output cols n, contiguous in k.
// grid = (96, 2), block = 256; thread handles (kc, n): 8 k values, 16B write.
// Reads coalesced (consecutive threads -> consecutive n per j).
// ---------------------------------------------------------------------------
__global__ __launch_bounds__(256) void wpackT_kernel(
    const float* __restrict__ W_cls, const float* __restrict__ W_reg,
    _Float16* __restrict__ Wt_cls, _Float16* __restrict__ Wt_reg) {
  const int idx = blockIdx.x * 256 + threadIdx.x;  // 0..24575
  const int kc = idx / 768;                        // 0..31 (k chunk of 8)
  const int n = idx % 768;
  const float* __restrict__ W = blockIdx.y ? W_reg : W_cls;
  _Float16* __restrict__ Wt = blockIdx.y ? Wt_reg : Wt_cls;
  uint4 o;
  o.x = h2u((half2_t){(_Float16)W[(kc * 8 + 0) * 768 + n],
                      (_Float16)W[(kc * 8 + 1) * 768 + n]});
  o.y = h2u((half2_t){(_Float16)W[(kc * 8 + 2) * 768 + n],
                      (_Float16)W[(kc * 8 + 3) * 768 + n]});
  o.z = h2u((half2_t){(_Float16)W[(kc * 8 + 4) * 768 + n],
                      (_Float16)W[(kc * 8 + 5) * 768 + n]});
  o.w = h2u((half2_t){(_Float16)W[(kc * 8 + 6) * 768 + n],
                      (_Float16)W[(kc * 8 + 7) * 768 + n]});
  *(uint4*)(Wt + (size_t)n * 256 + kc * 8) = o;
}

// ---------------------------------------------------------------------------
// Kernel 1 (r33 -> r34): MFMA QKV projection. Old fdot2 qkv was ~40us for a
// 1.57 TFLOP-equivalent GEMM (VALU-bound + 393 MB L2 W re-stream). Grid
// (125, 5): col-sections of 256 {q-cls, k-cls, v-cls, q-reg, k-reg} — v-reg
// is never computed (reference discards it). Block: stage x[16][256] f32->
// f16 in LDS (+8 pad, <=2-way banks); 4 waves x 4 n-tiles x 8 k-steps of
// mfma(A=Wt rows=n, B=x cols=token) — operand convention proven in attn
// (D: col=lane&15=token, row=(l>>4)*4+i=n). Norm groups of 32 n = 2 tiles;
// shfl_xor(16,32) gives group sum-of-squares. Writes the exact plane
// layouts attn33 consumes. block = 256
// ---------------------------------------------------------------------------
__global__ __launch_bounds__(256) void qkv_mfma_kernel(
    const float* __restrict__ x_cls, const float* __restrict__ x_reg,
    const _Float16* __restrict__ Wt_cls, const _Float16* __restrict__ Wt_reg,
    _Float16* __restrict__ qc2, _Float16* __restrict__ qr2,
    _Float16* __restrict__ kc2, _Float16* __restrict__ kr2,
    _Float16* __restrict__ vn2, float* __restrict__ v_rm,
    _Float16* __restrict__ v_t) {
  __shared__ _Float16 xs[16][264];  // +8 pad: token stride 528B -> <=2-way

  const int tid = threadIdx.x;
  const int c = blockIdx.y;
  const int which = (c >= 3) ? 1 : 0;
  const int sec = which ? (c - 3) : c;  // 0=q, 1=k, 2=v(cls only)
  const int n0 = sec * 256;
  const int i0 = blockIdx.x * 16;
  const float* __restrict__ x = which ? x_reg : x_cls;
  const _Float16* __restrict__ Wt = which ? Wt_reg : Wt_cls;

  // ---- stage x: 16 tokens x 256 k, f32 -> f16 ----
  {
    const int tok = tid >> 4, c4 = tid & 15;
    const float4* __restrict__ xr =
        (const float4*)(x + (size_t)(i0 + tok) * 256);
#pragma unroll
    for (int r = 0; r < 4; r++) {
      const float4 v = xr[c4 + 16 * r];
      *(unsigned*)&xs[tok][(c4 + 16 * r) * 4] =
          h2u((half2_t){(_Float16)v.x, (_Float16)v.y});
      *(unsigned*)&xs[tok][(c4 + 16 * r) * 4 + 2] =
          h2u((half2_t){(_Float16)v.z, (_Float16)v.w});
    }
  }
  __syncthreads();

  const int w = tid >> 6, l = tid & 63;
  const int q = l & 15, kg = l >> 4;
  const f32x4 zero4 = {0.f, 0.f, 0.f, 0.f};
  f32x4 acc[4] = {zero4, zero4, zero4, zero4};
  const int nb = n0 + w * 64;

#pragma unroll
  for (int ks = 0; ks < 8; ks++) {
    const int k0 = ks * 32;
    const f16x8 bx = *(const f16x8*)&xs[q][k0 + kg * 8];
#pragma unroll
    for (int t2 = 0; t2 < 4; t2++) {
      const f16x8 aw = *(const f16x8*)(
          Wt + (size_t)(nb + t2 * 16 + q) * 256 + k0 + kg * 8);
      acc[t2] =
          __builtin_amdgcn_mfma_f32_16x16x32_f16(aw, bx, acc[t2], 0, 0, 0);
    }
  }

  // ---- l2norm sums: group0 = tiles {0,1}, group1 = tiles {2,3} ----
  float ss0 = 0.f, ss1 = 0.f;
#pragma unroll
  for (int i = 0; i < 4; i++) {
    ss0 += acc[0][i] * acc[0][i] + acc[1][i] * acc[1][i];
    ss1 += acc[2][i] * acc[2][i] + acc[3][i] * acc[3][i];
  }
  ss0 += __shfl_xor(ss0, 16, 64);
  ss0 += __shfl_xor(ss0, 32, 64);
  ss1 += __shfl_xor(ss1, 16, 64);
  ss1 += __shfl_xor(ss1, 32, 64);
  const float inv0 = 1.0f / (sqrtf(ss0) + EPSF);
  const float inv1 = 1.0f / (sqrtf(ss1) + EPSF);

  const int tok = i0 + q;
#pragma unroll
  for (int t2 = 0; t2 < 4; t2++) {
    const float inv = (t2 < 2) ? inv0 : inv1;
    const int nrel = w * 64 + t2 * 16 + kg * 4;  // + i
    const int h = nrel >> 5, d0 = nrel & 31;
    uint2 un;
    un.x = h2u((half2_t){(_Float16)(acc[t2][0] * inv),
                         (_Float16)(acc[t2][1] * inv)});
    un.y = h2u((half2_t){(_Float16)(acc[t2][2] * inv),
                         (_Float16)(acc[t2][3] * inv)});
    const size_t off = ((size_t)(h * N_TOK) + tok) * 32 + d0;
    if (sec == 0) {
      *(uint2*)((which ? qr2 : qc2) + off) = un;
    } else if (sec == 1) {
      *(uint2*)((which ? kr2 : kc2) + off) = un;
    } else {
      *(uint2*)(vn2 + off) = un;
      const float4 vr = {acc[t2][0], acc[t2][1], acc[t2][2], acc[t2][3]};
      *(float4*)(v_rm + off) = vr;
#pragma unroll
      for (int i = 0; i < 4; i++) {
        v_t[((size_t)(h * 32) + d0 + i) * N_TOK + tok] = (_Float16)acc[t2][i];
      }
    }
  }
}

// ---------------------------------------------------------------------------
// Kernel 2 (r33, UNCHANGED): QT=16 x NHH=2 MFMA attention.
// grid = 500, block = 256 (4 waves; wave w owns key tiles w, w+4, ...)
// ---------------------------------------------------------------------------
__global__ __launch_bounds__(256) void attn33_kernel(
    const _Float16* __restrict__ qc2, const _Float16* __restrict__ qr2,
    const _Float16* __restrict__ kc2, const _Float16* __restrict__ kr2,
    const _Float16* __restrict__ vn2, const _Float16* __restrict__ v_t,
    const float* __restrict__ v_rm, float* __restrict__ out_x,
    _Float16* __restrict__ sim_ws, _Float16* __restrict__ raw_ws) {
  __shared__ _Float16 qst[3][NHH][QT][40];  // staged Q planes (7.7 KB)
  __shared__ float smem_u[4224];            // 16.9 KB union

  float* __restrict__ sums_l = smem_u;          // [4][2][NHH][16] = 256 f
  float* __restrict__ nrm = smem_u + 256;       // [2][NHH][16] = 64 f
  float* __restrict__ st = smem_u;              // [4][16][20] = 1280 f
  float* __restrict__ pvr = smem_u;             // [4][2][16][33] = 4224 f

  const int tid = threadIdx.x;
  const int w = tid >> 6;
  const int l = tid & 63;
  const int qgrp = blockIdx.x >> 2;
  const int hp = blockIdx.x & 3;   // head pair index
  const int hq = hp * NHH;         // head base for this block
  const int i0 = qgrp * QT;
  _Float16* __restrict__ simp = sim_ws + (size_t)hp * N_TOK * N_TOK;
  _Float16* __restrict__ rawp = raw_ws + (size_t)hp * N_TOK * N_TOK;

  // ---- stage Q: 3 planes x 2 heads x 16 rows x 32 d ----
  if (tid < 128) {
    const int hh = tid >> 6, row = (tid >> 2) & 15, dg = tid & 3;
    const size_t src =
        ((size_t)((hq + hh) * N_TOK) + (i0 + row)) * HD + dg * 8;
    *(uint4*)&qst[0][hh][row][dg * 8] = *(const uint4*)(qc2 + src);
    *(uint4*)&qst[1][hh][row][dg * 8] = *(const uint4*)(qr2 + src);
    *(uint4*)&qst[2][hh][row][dg * 8] = *(const uint4*)(vn2 + src);
  }
  __syncthreads();

  const int q = l & 15;
  const int kg = l >> 4;  // 0..3
  const int i_glob = i0 + q;           // real query index (all 16 real)
  const int bs = (i_glob / 10) * 10;   // decade start for the mask

  const f32x4 zero4 = {0.f, 0.f, 0.f, 0.f};

  // ======== pass 1: softmax denominators (2 heads) ========
  float sc[NHH], sr[NHH];
#pragma unroll
  for (int hh = 0; hh < NHH; hh++) { sc[hh] = 0.f; sr[hh] = 0.f; }

  for (int t = w; t < NT; t += 4) {
    const int mb = t * 16;
#pragma unroll
    for (int hh = 0; hh < NHH; hh++) {
      const size_t koff =
          ((size_t)((hq + hh) * N_TOK) + mb + q) * HD + kg * 8;
      const f16x8 akc = *(const f16x8*)(kc2 + koff);
      const f16x8 akr = *(const f16x8*)(kr2 + koff);
      const f16x8 bqc = *(const f16x8*)&qst[0][hh][q][kg * 8];
      const f16x8 bqr = *(const f16x8*)&qst[1][hh][q][kg * 8];
      const f32x4 dc =
          __builtin_amdgcn_mfma_f32_16x16x32_f16(akc, bqc, zero4, 0, 0, 0);
      const f32x4 dr =
          __builtin_amdgcn_mfma_f32_16x16x32_f16(akr, bqr, zero4, 0, 0, 0);
#pragma unroll
      for (int i = 0; i < 4; i++) {
        sc[hh] += __expf(dc[i] * SCALE - SCALE);
        sr[hh] += __expf(dr[i] * SCALE - SCALE);
      }
    }
  }
#pragma unroll
  for (int hh = 0; hh < NHH; hh++) {
    sc[hh] += __shfl_xor(sc[hh], 16, 64);
    sc[hh] += __shfl_xor(sc[hh], 32, 64);
    sr[hh] += __shfl_xor(sr[hh], 16, 64);
    sr[hh] += __shfl_xor(sr[hh], 32, 64);
  }
  if (l < 16) {
#pragma unroll
    for (int hh = 0; hh < NHH; hh++) {
      sums_l[((w * 2 + 0) * NHH + hh) * 16 + l] = sc[hh];
      sums_l[((w * 2 + 1) * NHH + hh) * 16 + l] = sr[hh];
    }
  }
  __syncthreads();
  if (tid < 64) {
    const int pl = tid >> 5, hh = (tid >> 4) & 1, qq = tid & 15;
    const float s = sums_l[((0 * 2 + pl) * NHH + hh) * 16 + qq] +
                    sums_l[((1 * 2 + pl) * NHH + hh) * 16 + qq] +
                    sums_l[((2 * 2 + pl) * NHH + hh) * 16 + qq] +
                    sums_l[((3 * 2 + pl) * NHH + hh) * 16 + qq];
    nrm[(pl * NHH + hh) * 16 + qq] = 0.5f / s;
  }
  __syncthreads();
  float ncr[NHH], nrr[NHH];
#pragma unroll
  for (int hh = 0; hh < NHH; hh++) {
    ncr[hh] = nrm[(0 * NHH + hh) * 16 + q];
    nrr[hh] = nrm[(1 * NHH + hh) * 16 + q];
  }
  __syncthreads();  // nrm reads done -> st (aliased) may be written

  // ======== pass 2: combine + mask + sim/raw + PV ========
  f32x4 pv[NHH][2];
#pragma unroll
  for (int hh = 0; hh < NHH; hh++) { pv[hh][0] = zero4; pv[hh][1] = zero4; }

  for (int t = w; t < NT; t += 4) {
    const int mb = t * 16;
    f32x4 simt = zero4;
    f32x4 rawt = zero4;
#pragma unroll
    for (int hh = 0; hh < NHH; hh++) {
      const int h = hq + hh;
      const size_t koff = ((size_t)(h * N_TOK) + mb + q) * HD + kg * 8;
      const f16x8 akc = *(const f16x8*)(kc2 + koff);
      const f16x8 akr = *(const f16x8*)(kr2 + koff);
      const f16x8 avn = *(const f16x8*)(vn2 + koff);
      const f16x8 bqc = *(const f16x8*)&qst[0][hh][q][kg * 8];
      const f16x8 bqr = *(const f16x8*)&qst[1][hh][q][kg * 8];
      const f16x8 bqv = *(const f16x8*)&qst[2][hh][q][kg * 8];
      const f32x4 dc =
          __builtin_amdgcn_mfma_f32_16x16x32_f16(akc, bqc, zero4, 0, 0, 0);
      const f32x4 dr =
          __builtin_amdgcn_mfma_f32_16x16x32_f16(akr, bqr, zero4, 0, 0, 0);
      rawt = __builtin_amdgcn_mfma_f32_16x16x32_f16(avn, bqv, rawt, 0, 0, 0);

      f16x4 pa;
#pragma unroll
      for (int i = 0; i < 4; i++) {
        const float ec = __expf(dc[i] * SCALE - SCALE);
        const float er = __expf(dr[i] * SCALE - SCALE);
        float ai = ncr[hh] * ec + nrr[hh] * er;
        const int m = mb + kg * 4 + i;
        if (m >= bs && m < bs + 9 && m != i_glob) ai = 0.f;
        simt[i] += ai;
        pa[i] = (_Float16)ai;
      }
      const f16x4 bv0 = *(const f16x4*)(
          v_t + ((size_t)(h * HD) + q) * N_TOK + mb + kg * 4);
      const f16x4 bv1 = *(const f16x4*)(
          v_t + ((size_t)(h * HD) + 16 + q) * N_TOK + mb + kg * 4);
      pv[hh][0] =
          __builtin_amdgcn_mfma_f32_16x16x16f16(pa, bv0, pv[hh][0], 0, 0, 0);
      pv[hh][1] =
          __builtin_amdgcn_mfma_f32_16x16x16f16(pa, bv1, pv[hh][1], 0, 0, 0);
    }
    // ---- stream partial sim tile (f16): 16 rows x 16 cols per wave ----
    st[(w * 16 + q) * 20 + kg * 4 + 0] = simt[0];
    st[(w * 16 + q) * 20 + kg * 4 + 1] = simt[1];
    st[(w * 16 + q) * 20 + kg * 4 + 2] = simt[2];
    st[(w * 16 + q) * 20 + kg * 4 + 3] = simt[3];
    {
      const int row = l >> 2, mo = (l & 3) * 4;
      const float4 v4 = *(const float4*)&st[(w * 16 + row) * 20 + mo];
      uint2 u;
      u.x = h2u((half2_t){(_Float16)v4.x, (_Float16)v4.y});
      u.y = h2u((half2_t){(_Float16)v4.z, (_Float16)v4.w});
      *(uint2*)(simp + (size_t)(i0 + row) * N_TOK + mb + mo) = u;
    }
    // ---- stream partial raw tile (f16) ----
    st[(w * 16 + q) * 20 + kg * 4 + 0] = rawt[0];
    st[(w * 16 + q) * 20 + kg * 4 + 1] = rawt[1];
    st[(w * 16 + q) * 20 + kg * 4 + 2] = rawt[2];
    st[(w * 16 + q) * 20 + kg * 4 + 3] = rawt[3];
    {
      const int row = l >> 2, mo = (l & 3) * 4;
      const float4 v4 = *(const float4*)&st[(w * 16 + row) * 20 + mo];
      uint2 u;
      u.x = h2u((half2_t){(_Float16)v4.x, (_Float16)v4.y});
      u.y = h2u((half2_t){(_Float16)v4.z, (_Float16)v4.w});
      *(uint2*)(rawp + (size_t)(i0 + row) * N_TOK + mb + mo) = u;
    }
  }

  // ======== PV cross-wave reduction + out_x (2 heads, 16 queries) ========
  __syncthreads();  // st reads done -> pvr (aliased) may be written
#pragma unroll
  for (int hh = 0; hh < NHH; hh++) {
#pragma unroll
    for (int i = 0; i < 4; i++) {
      pvr[((w * 2 + hh) * 16 + kg * 4 + i) * 33 + q] = pv[hh][0][i];
      pvr[((w * 2 + hh) * 16 + kg * 4 + i) * 33 + 16 + q] = pv[hh][1][i];
    }
  }
  __syncthreads();
  {
    const int hh = tid >> 7, qg2 = (tid >> 5) & 3, d = tid & 31;
#pragma unroll
    for (int qi = 0; qi < 4; qi++) {
      const int qq = qg2 * 4 + qi;
      float s = 0.f;
#pragma unroll
      for (int wv = 0; wv < 4; wv++) {
        s += pvr[((wv * 2 + hh) * 16 + qq) * 33 + d];
      }
      out_x[(size_t)(i0 + qq) * 512 + (hq + hh) * 32 + d] = s;
    }
  }
  // ---- v_rm copy half for this block's 2 heads ----
  if (tid < 64) {
    const int hh = tid >> 5, d = tid & 31;
    const int h = hq + hh;
#pragma unroll
    for (int qq = 0; qq < QT; qq++) {
      out_x[(size_t)(i0 + qq) * 512 + 256 + h * 32 + d] =
          v_rm[((size_t)(h * N_TOK) + i0 + qq) * HD + d];
    }
  }
}

// ---------------------------------------------------------------------------
// Kernel 3 (r33, UNCHANGED): sim_round2; sums the 4 head-pair partials.
// grid = 250, block = 256; 8 rows per block.
// ---------------------------------------------------------------------------
__global__ __launch_bounds__(256) void sim_round2_kernel(
    const _Float16* __restrict__ sim_ws, const _Float16* __restrict__ raw_ws,
    float* __restrict__ out_sim) {
  __shared__ float red[16];
  const int tid = threadIdx.x;
  const int i0 = blockIdx.x * 8;
  const size_t NN = (size_t)N_TOK * N_TOK;
  for (int r = 0; r < 8; r++) {
    const int i = i0 + r;
    float s[8], rw[8];
#pragma unroll
    for (int t = 0; t < 8; t++) {
      const int m = tid + 256 * t;
      const bool valid = (t < 7) || (tid < 208);
      const size_t idx = (size_t)i * N_TOK + m;
      if (valid) {
        s[t] = ((float)sim_ws[idx] + (float)sim_ws[NN + idx] +
                (float)sim_ws[2 * NN + idx] + (float)sim_ws[3 * NN + idx]) *
               0.125f;
        rw[t] = (float)raw_ws[idx] + (float)raw_ws[NN + idx] +
                (float)raw_ws[2 * NN + idx] + (float)raw_ws[3 * NN + idx];
      } else {
        s[t] = -1e30f;
        rw[t] = 0.f;
      }
    }
    float lm = -1e30f;
#pragma unroll
    for (int t = 0; t < 8; t++) lm = fmaxf(lm, s[t]);
    const float M = block_max256(lm, red);
    float ls = 0.f;
#pragma unroll
    for (int t = 0; t < 8; t++) {
      const bool valid = (t < 7) || (tid < 208);
      const float e = valid ? __expf(s[t] - M) : 0.f;
      s[t] = e;
      ls += e;
    }
    const float S = block_sum256(ls, red);
    const float invS = 1.0f / S;
    float lms = 0.f;
#pragma unroll
    for (int t = 0; t < 8; t++) {
      const bool valid = (t < 7) || (tid < 208);
      const float p = s[t] * invS;
      const float mp = (valid && (rw[t] * 0.125f > SIM_TH)) ? p : 0.f;
      s[t] = mp;
      lms += mp;
    }
    const float MS = block_sum256(lms, red);
    const float invMS = 1.0f / (MS + EPSF);
#pragma unroll
    for (int t = 0; t < 8; t++) {
      const int m = tid + 256 * t;
      if ((t < 7) || (tid < 208)) {
        out_sim[(size_t)i * N_TOK + m] = s[t] * invMS;
      }
    }
  }
}

// ---------------------------------------------------------------------------
extern "C" void kernel_launch(void* const* d_in, const int* in_sizes, int n_in,
                              void* d_out, int out_size, void* d_ws,
                              size_t ws_size, hipStream_t stream) {
  const float* x_cls = (const float*)d_in[0];
  const float* x_reg = (const float*)d_in[1];
  const float* W_cls = (const float*)d_in[2];
  const float* W_reg = (const float*)d_in[3];

  // ws layout (~73 MB): v_rm f32, 6 f16 planes, sim f16 x4 partial planes,
  // raw f16 x4 partial planes, transposed-packed W f16 x2.
  const size_t seg = (size_t)NH * N_TOK * HD;  // 512000 elements
  float* v_rm = (float*)d_ws;
  _Float16* qc2 = (_Float16*)(v_rm + seg);
  _Float16* qr2 = qc2 + seg;
  _Float16* kc2 = qr2 + seg;
  _Float16* kr2 = kc2 + seg;
  _Float16* vn2 = kr2 + seg;
  _Float16* v_t = vn2 + seg;
  _Float16* sim_ws = v_t + seg;  // 4 x N*N f16
  _Float16* raw_ws = sim_ws + 4 * (size_t)N_TOK * N_TOK;  // 4 x N*N f16
  _Float16* Wt_cls = raw_ws + 4 * (size_t)N_TOK * N_TOK;  // [768][256] f16
  _Float16* Wt_reg = Wt_cls + 768 * 256;

  dim3 g0(96, 2);
  wpackT_kernel<<<g0, 256, 0, stream>>>(W_cls, W_reg, Wt_cls, Wt_reg);

  dim3 g1(125, 5);
  qkv_mfma_kernel<<<g1, 256, 0, stream>>>(x_cls, x_reg, Wt_cls, Wt_reg, qc2,
                                          qr2, kc2, kr2, vn2, v_rm, v_t);

  float* out_x = (float*)d_out;                  // [2000, 512]
  float* out_sim = out_x + (size_t)N_TOK * 512;  // [2000, 2000]
  attn33_kernel<<<500, 256, 0, stream>>>(qc2, qr2, kc2, kr2, vn2, v_t, v_rm,
                                         out_x, sim_ws, raw_ws);
  sim_round2_kernel<<<250, 256, 0, stream>>>(sim_ws, raw_ws, out_sim);
}

// Round 14
// 162.583 us; speedup vs baseline: 3.0903x; 1.0902x over previous
//
#include <hip/hip_runtime.h>
#include <math.h>

#define N_TOK 2000
#define NH 8
#define NHH 2   // heads per attn block (4-way head split)
#define HD 32
#define SCALE 25.0f
#define SIM_TH 0.75f
#define EPSF 1e-8f
#define NT 125  // key tiles of 16 (125*16 = 2000 exact)
#define QT 16   // query rows per attn block — ALL 16 MFMA cols real

typedef _Float16 half2_t __attribute__((ext_vector_type(2)));
typedef _Float16 f16x4 __attribute__((ext_vector_type(4)));
typedef _Float16 f16x8 __attribute__((ext_vector_type(8)));
typedef float f32x4 __attribute__((ext_vector_type(4)));

__device__ __forceinline__ half2_t u2h(unsigned u) {
  return __builtin_bit_cast(half2_t, u);
}
__device__ __forceinline__ unsigned h2u(half2_t h) {
  return __builtin_bit_cast(unsigned, h);
}

__device__ __forceinline__ float block_max256(float v, float* red) {
#pragma unroll
  for (int off = 32; off > 0; off >>= 1) v = fmaxf(v, __shfl_xor(v, off, 64));
  __syncthreads();
  if ((threadIdx.x & 63) == 0) red[threadIdx.x >> 6] = v;
  __syncthreads();
  return fmaxf(fmaxf(red[0], red[1]), fmaxf(red[2], red[3]));
}
__device__ __forceinline__ float block_sum256(float v, float* red) {
#pragma unroll
  for (int off = 32; off > 0; off >>= 1) v += __shfl_xor(v, off, 64);
  __syncthreads();
  if ((threadIdx.x & 63) == 0) red[threadIdx.x >> 6] = v;
  __syncthreads();
  return (red[0] + red[1]) + (red[2] + red[3]);
}

// ---------------------------------------------------------------------------
// Kernel 0 (r34, UNCHANGED): pack W fp32 [256][768] TRANSPOSED into f16
// Wt[768][256]. grid = (96, 2), block = 256.
// ---------------------------------------------------------------------------
__global__ __launch_bounds__(256) void wpackT_kernel(
    const float* __restrict__ W_cls, const float* __restrict__ W_reg,
    _Float16* __restrict__ Wt_cls, _Float16* __restrict__ Wt_reg) {
  const int idx = blockIdx.x * 256 + threadIdx.x;  // 0..24575
  const int kc = idx / 768;                        // 0..31 (k chunk of 8)
  const int n = idx % 768;
  const float* __restrict__ W = blockIdx.y ? W_reg : W_cls;
  _Float16* __restrict__ Wt = blockIdx.y ? Wt_reg : Wt_cls;
  uint4 o;
  o.x = h2u((half2_t){(_Float16)W[(kc * 8 + 0) * 768 + n],
                      (_Float16)W[(kc * 8 + 1) * 768 + n]});
  o.y = h2u((half2_t){(_Float16)W[(kc * 8 + 2) * 768 + n],
                      (_Float16)W[(kc * 8 + 3) * 768 + n]});
  o.z = h2u((half2_t){(_Float16)W[(kc * 8 + 4) * 768 + n],
                      (_Float16)W[(kc * 8 + 5) * 768 + n]});
  o.w = h2u((half2_t){(_Float16)W[(kc * 8 + 6) * 768 + n],
                      (_Float16)W[(kc * 8 + 7) * 768 + n]});
  *(uint4*)(Wt + (size_t)n * 256 + kc * 8) = o;
}

// ---------------------------------------------------------------------------
// Kernel 1 (r34, UNCHANGED): MFMA QKV projection. grid = (125, 5), block 256.
// ---------------------------------------------------------------------------
__global__ __launch_bounds__(256) void qkv_mfma_kernel(
    const float* __restrict__ x_cls, const float* __restrict__ x_reg,
    const _Float16* __restrict__ Wt_cls, const _Float16* __restrict__ Wt_reg,
    _Float16* __restrict__ qc2, _Float16* __restrict__ qr2,
    _Float16* __restrict__ kc2, _Float16* __restrict__ kr2,
    _Float16* __restrict__ vn2, float* __restrict__ v_rm,
    _Float16* __restrict__ v_t) {
  __shared__ _Float16 xs[16][264];  // +8 pad: token stride 528B -> <=2-way

  const int tid = threadIdx.x;
  const int c = blockIdx.y;
  const int which = (c >= 3) ? 1 : 0;
  const int sec = which ? (c - 3) : c;  // 0=q, 1=k, 2=v(cls only)
  const int n0 = sec * 256;
  const int i0 = blockIdx.x * 16;
  const float* __restrict__ x = which ? x_reg : x_cls;
  const _Float16* __restrict__ Wt = which ? Wt_reg : Wt_cls;

  // ---- stage x: 16 tokens x 256 k, f32 -> f16 ----
  {
    const int tok = tid >> 4, c4 = tid & 15;
    const float4* __restrict__ xr =
        (const float4*)(x + (size_t)(i0 + tok) * 256);
#pragma unroll
    for (int r = 0; r < 4; r++) {
      const float4 v = xr[c4 + 16 * r];
      *(unsigned*)&xs[tok][(c4 + 16 * r) * 4] =
          h2u((half2_t){(_Float16)v.x, (_Float16)v.y});
      *(unsigned*)&xs[tok][(c4 + 16 * r) * 4 + 2] =
          h2u((half2_t){(_Float16)v.z, (_Float16)v.w});
    }
  }
  __syncthreads();

  const int w = tid >> 6, l = tid & 63;
  const int q = l & 15, kg = l >> 4;
  const f32x4 zero4 = {0.f, 0.f, 0.f, 0.f};
  f32x4 acc[4] = {zero4, zero4, zero4, zero4};
  const int nb = n0 + w * 64;

#pragma unroll
  for (int ks = 0; ks < 8; ks++) {
    const int k0 = ks * 32;
    const f16x8 bx = *(const f16x8*)&xs[q][k0 + kg * 8];
#pragma unroll
    for (int t2 = 0; t2 < 4; t2++) {
      const f16x8 aw = *(const f16x8*)(
          Wt + (size_t)(nb + t2 * 16 + q) * 256 + k0 + kg * 8);
      acc[t2] =
          __builtin_amdgcn_mfma_f32_16x16x32_f16(aw, bx, acc[t2], 0, 0, 0);
    }
  }

  // ---- l2norm sums: group0 = tiles {0,1}, group1 = tiles {2,3} ----
  float ss0 = 0.f, ss1 = 0.f;
#pragma unroll
  for (int i = 0; i < 4; i++) {
    ss0 += acc[0][i] * acc[0][i] + acc[1][i] * acc[1][i];
    ss1 += acc[2][i] * acc[2][i] + acc[3][i] * acc[3][i];
  }
  ss0 += __shfl_xor(ss0, 16, 64);
  ss0 += __shfl_xor(ss0, 32, 64);
  ss1 += __shfl_xor(ss1, 16, 64);
  ss1 += __shfl_xor(ss1, 32, 64);
  const float inv0 = 1.0f / (sqrtf(ss0) + EPSF);
  const float inv1 = 1.0f / (sqrtf(ss1) + EPSF);

  const int tok = i0 + q;
#pragma unroll
  for (int t2 = 0; t2 < 4; t2++) {
    const float inv = (t2 < 2) ? inv0 : inv1;
    const int nrel = w * 64 + t2 * 16 + kg * 4;  // + i
    const int h = nrel >> 5, d0 = nrel & 31;
    uint2 un;
    un.x = h2u((half2_t){(_Float16)(acc[t2][0] * inv),
                         (_Float16)(acc[t2][1] * inv)});
    un.y = h2u((half2_t){(_Float16)(acc[t2][2] * inv),
                         (_Float16)(acc[t2][3] * inv)});
    const size_t off = ((size_t)(h * N_TOK) + tok) * 32 + d0;
    if (sec == 0) {
      *(uint2*)((which ? qr2 : qc2) + off) = un;
    } else if (sec == 1) {
      *(uint2*)((which ? kr2 : kc2) + off) = un;
    } else {
      *(uint2*)(vn2 + off) = un;
      const float4 vr = {acc[t2][0], acc[t2][1], acc[t2][2], acc[t2][3]};
      *(float4*)(v_rm + off) = vr;
#pragma unroll
      for (int i = 0; i < 4; i++) {
        v_t[((size_t)(h * 32) + d0 + i) * N_TOK + tok] = (_Float16)acc[t2][i];
      }
    }
  }
}

// ---------------------------------------------------------------------------
// Kernel 2 (r33, UNCHANGED): QT=16 x NHH=2 MFMA attention.
// grid = 500, block = 256 (4 waves; wave w owns key tiles w, w+4, ...)
// ---------------------------------------------------------------------------
__global__ __launch_bounds__(256) void attn33_kernel(
    const _Float16* __restrict__ qc2, const _Float16* __restrict__ qr2,
    const _Float16* __restrict__ kc2, const _Float16* __restrict__ kr2,
    const _Float16* __restrict__ vn2, const _Float16* __restrict__ v_t,
    const float* __restrict__ v_rm, float* __restrict__ out_x,
    _Float16* __restrict__ sim_ws, _Float16* __restrict__ raw_ws) {
  __shared__ _Float16 qst[3][NHH][QT][40];  // staged Q planes (7.7 KB)
  __shared__ float smem_u[4224];            // 16.9 KB union

  float* __restrict__ sums_l = smem_u;          // [4][2][NHH][16] = 256 f
  float* __restrict__ nrm = smem_u + 256;       // [2][NHH][16] = 64 f
  float* __restrict__ st = smem_u;              // [4][16][20] = 1280 f
  float* __restrict__ pvr = smem_u;             // [4][2][16][33] = 4224 f

  const int tid = threadIdx.x;
  const int w = tid >> 6;
  const int l = tid & 63;
  const int qgrp = blockIdx.x >> 2;
  const int hp = blockIdx.x & 3;   // head pair index
  const int hq = hp * NHH;         // head base for this block
  const int i0 = qgrp * QT;
  _Float16* __restrict__ simp = sim_ws + (size_t)hp * N_TOK * N_TOK;
  _Float16* __restrict__ rawp = raw_ws + (size_t)hp * N_TOK * N_TOK;

  // ---- stage Q: 3 planes x 2 heads x 16 rows x 32 d ----
  if (tid < 128) {
    const int hh = tid >> 6, row = (tid >> 2) & 15, dg = tid & 3;
    const size_t src =
        ((size_t)((hq + hh) * N_TOK) + (i0 + row)) * HD + dg * 8;
    *(uint4*)&qst[0][hh][row][dg * 8] = *(const uint4*)(qc2 + src);
    *(uint4*)&qst[1][hh][row][dg * 8] = *(const uint4*)(qr2 + src);
    *(uint4*)&qst[2][hh][row][dg * 8] = *(const uint4*)(vn2 + src);
  }
  __syncthreads();

  const int q = l & 15;
  const int kg = l >> 4;  // 0..3
  const int i_glob = i0 + q;           // real query index (all 16 real)
  const int bs = (i_glob / 10) * 10;   // decade start for the mask

  const f32x4 zero4 = {0.f, 0.f, 0.f, 0.f};

  // ======== pass 1: softmax denominators (2 heads) ========
  float sc[NHH], sr[NHH];
#pragma unroll
  for (int hh = 0; hh < NHH; hh++) { sc[hh] = 0.f; sr[hh] = 0.f; }

  for (int t = w; t < NT; t += 4) {
    const int mb = t * 16;
#pragma unroll
    for (int hh = 0; hh < NHH; hh++) {
      const size_t koff =
          ((size_t)((hq + hh) * N_TOK) + mb + q) * HD + kg * 8;
      const f16x8 akc = *(const f16x8*)(kc2 + koff);
      const f16x8 akr = *(const f16x8*)(kr2 + koff);
      const f16x8 bqc = *(const f16x8*)&qst[0][hh][q][kg * 8];
      const f16x8 bqr = *(const f16x8*)&qst[1][hh][q][kg * 8];
      const f32x4 dc =
          __builtin_amdgcn_mfma_f32_16x16x32_f16(akc, bqc, zero4, 0, 0, 0);
      const f32x4 dr =
          __builtin_amdgcn_mfma_f32_16x16x32_f16(akr, bqr, zero4, 0, 0, 0);
#pragma unroll
      for (int i = 0; i < 4; i++) {
        sc[hh] += __expf(dc[i] * SCALE - SCALE);
        sr[hh] += __expf(dr[i] * SCALE - SCALE);
      }
    }
  }
#pragma unroll
  for (int hh = 0; hh < NHH; hh++) {
    sc[hh] += __shfl_xor(sc[hh], 16, 64);
    sc[hh] += __shfl_xor(sc[hh], 32, 64);
    sr[hh] += __shfl_xor(sr[hh], 16, 64);
    sr[hh] += __shfl_xor(sr[hh], 32, 64);
  }
  if (l < 16) {
#pragma unroll
    for (int hh = 0; hh < NHH; hh++) {
      sums_l[((w * 2 + 0) * NHH + hh) * 16 + l] = sc[hh];
      sums_l[((w * 2 + 1) * NHH + hh) * 16 + l] = sr[hh];
    }
  }
  __syncthreads();
  if (tid < 64) {
    const int pl = tid >> 5, hh = (tid >> 4) & 1, qq = tid & 15;
    const float s = sums_l[((0 * 2 + pl) * NHH + hh) * 16 + qq] +
                    sums_l[((1 * 2 + pl) * NHH + hh) * 16 + qq] +
                    sums_l[((2 * 2 + pl) * NHH + hh) * 16 + qq] +
                    sums_l[((3 * 2 + pl) * NHH + hh) * 16 + qq];
    nrm[(pl * NHH + hh) * 16 + qq] = 0.5f / s;
  }
  __syncthreads();
  float ncr[NHH], nrr[NHH];
#pragma unroll
  for (int hh = 0; hh < NHH; hh++) {
    ncr[hh] = nrm[(0 * NHH + hh) * 16 + q];
    nrr[hh] = nrm[(1 * NHH + hh) * 16 + q];
  }
  __syncthreads();  // nrm reads done -> st (aliased) may be written

  // ======== pass 2: combine + mask + sim/raw + PV ========
  f32x4 pv[NHH][2];
#pragma unroll
  for (int hh = 0; hh < NHH; hh++) { pv[hh][0] = zero4; pv[hh][1] = zero4; }

  for (int t = w; t < NT; t += 4) {
    const int mb = t * 16;
    f32x4 simt = zero4;
    f32x4 rawt = zero4;
#pragma unroll
    for (int hh = 0; hh < NHH; hh++) {
      const int h = hq + hh;
      const size_t koff = ((size_t)(h * N_TOK) + mb + q) * HD + kg * 8;
      const f16x8 akc = *(const f16x8*)(kc2 + koff);
      const f16x8 akr = *(const f16x8*)(kr2 + koff);
      const f16x8 avn = *(const f16x8*)(vn2 + koff);
      const f16x8 bqc = *(const f16x8*)&qst[0][hh][q][kg * 8];
      const f16x8 bqr = *(const f16x8*)&qst[1][hh][q][kg * 8];
      const f16x8 bqv = *(const f16x8*)&qst[2][hh][q][kg * 8];
      const f32x4 dc =
          __builtin_amdgcn_mfma_f32_16x16x32_f16(akc, bqc, zero4, 0, 0, 0);
      const f32x4 dr =
          __builtin_amdgcn_mfma_f32_16x16x32_f16(akr, bqr, zero4, 0, 0, 0);
      rawt = __builtin_amdgcn_mfma_f32_16x16x32_f16(avn, bqv, rawt, 0, 0, 0);

      f16x4 pa;
#pragma unroll
      for (int i = 0; i < 4; i++) {
        const float ec = __expf(dc[i] * SCALE - SCALE);
        const float er = __expf(dr[i] * SCALE - SCALE);
        float ai = ncr[hh] * ec + nrr[hh] * er;
        const int m = mb + kg * 4 + i;
        if (m >= bs && m < bs + 9 && m != i_glob) ai = 0.f;
        simt[i] += ai;
        pa[i] = (_Float16)ai;
      }
      const f16x4 bv0 = *(const f16x4*)(
          v_t + ((size_t)(h * HD) + q) * N_TOK + mb + kg * 4);
      const f16x4 bv1 = *(const f16x4*)(
          v_t + ((size_t)(h * HD) + 16 + q) * N_TOK + mb + kg * 4);
      pv[hh][0] =
          __builtin_amdgcn_mfma_f32_16x16x16f16(pa, bv0, pv[hh][0], 0, 0, 0);
      pv[hh][1] =
          __builtin_amdgcn_mfma_f32_16x16x16f16(pa, bv1, pv[hh][1], 0, 0, 0);
    }
    // ---- stream partial sim tile (f16): 16 rows x 16 cols per wave ----
    st[(w * 16 + q) * 20 + kg * 4 + 0] = simt[0];
    st[(w * 16 + q) * 20 + kg * 4 + 1] = simt[1];
    st[(w * 16 + q) * 20 + kg * 4 + 2] = simt[2];
    st[(w * 16 + q) * 20 + kg * 4 + 3] = simt[3];
    {
      const int row = l >> 2, mo = (l & 3) * 4;
      const float4 v4 = *(const float4*)&st[(w * 16 + row) * 20 + mo];
      uint2 u;
      u.x = h2u((half2_t){(_Float16)v4.x, (_Float16)v4.y});
      u.y = h2u((half2_t){(_Float16)v4.z, (_Float16)v4.w});
      *(uint2*)(simp + (size_t)(i0 + row) * N_TOK + mb + mo) = u;
    }
    // ---- stream partial raw tile (f16) ----
    st[(w * 16 + q) * 20 + kg * 4 + 0] = rawt[0];
    st[(w * 16 + q) * 20 + kg * 4 + 1] = rawt[1];
    st[(w * 16 + q) * 20 + kg * 4 + 2] = rawt[2];
    st[(w * 16 + q) * 20 + kg * 4 + 3] = rawt[3];
    {
      const int row = l >> 2, mo = (l & 3) * 4;
      const float4 v4 = *(const float4*)&st[(w * 16 + row) * 20 + mo];
      uint2 u;
      u.x = h2u((half2_t){(_Float16)v4.x, (_Float16)v4.y});
      u.y = h2u((half2_t){(_Float16)v4.z, (_Float16)v4.w});
      *(uint2*)(rawp + (size_t)(i0 + row) * N_TOK + mb + mo) = u;
    }
  }

  // ======== PV cross-wave reduction + out_x (2 heads, 16 queries) ========
  __syncthreads();  // st reads done -> pvr (aliased) may be written
#pragma unroll
  for (int hh = 0; hh < NHH; hh++) {
#pragma unroll
    for (int i = 0; i < 4; i++) {
      pvr[((w * 2 + hh) * 16 + kg * 4 + i) * 33 + q] = pv[hh][0][i];
      pvr[((w * 2 + hh) * 16 + kg * 4 + i) * 33 + 16 + q] = pv[hh][1][i];
    }
  }
  __syncthreads();
  {
    const int hh = tid >> 7, qg2 = (tid >> 5) & 3, d = tid & 31;
#pragma unroll
    for (int qi = 0; qi < 4; qi++) {
      const int qq = qg2 * 4 + qi;
      float s = 0.f;
#pragma unroll
      for (int wv = 0; wv < 4; wv++) {
        s += pvr[((wv * 2 + hh) * 16 + qq) * 33 + d];
      }
      out_x[(size_t)(i0 + qq) * 512 + (hq + hh) * 32 + d] = s;
    }
  }
  // ---- v_rm copy half for this block's 2 heads ----
  if (tid < 64) {
    const int hh = tid >> 5, d = tid & 31;
    const int h = hq + hh;
#pragma unroll
    for (int qq = 0; qq < QT; qq++) {
      out_x[(size_t)(i0 + qq) * 512 + 256 + h * 32 + d] =
          v_rm[((size_t)(h * N_TOK) + i0 + qq) * HD + d];
    }
  }
}

// ---------------------------------------------------------------------------
// Kernel 3 (r34 -> r35): sim_round2 rewrite. Post-mortem r34: non-attn
// budget ~101us; by elimination sim_round2 is ~50-65us and has BOTH session
// diseases: grid 250 < 256 CUs (r31 lesson) AND scalar f16 loads (8 scalar
// loads/element; Common-mistake #2). Fix: grid 1000 (2 rows/block, 4x block
// parallelism) + vectorized f16x8 loads (each thread owns 8 CONTIGUOUS
// cols; one 16B load per plane; 250 active lanes cover a row exactly).
// Same reduction structure (3 block reductions per row); f32 out as 2x
// float4. grid = 1000, block = 256.
// ---------------------------------------------------------------------------
__global__ __launch_bounds__(256) void sim_round2_kernel(
    const _Float16* __restrict__ sim_ws, const _Float16* __restrict__ raw_ws,
    float* __restrict__ out_sim) {
  __shared__ float red[16];
  const int tid = threadIdx.x;
  const size_t NN = (size_t)N_TOK * N_TOK;
  const bool act = tid < 250;
#pragma unroll
  for (int r = 0; r < 2; r++) {
    const int i = blockIdx.x * 2 + r;
    float s[8], rw[8];
    if (act) {
      const size_t base = (size_t)i * N_TOK + tid * 8;
      const f16x8 s0 = *(const f16x8*)(sim_ws + base);
      const f16x8 s1 = *(const f16x8*)(sim_ws + NN + base);
      const f16x8 s2 = *(const f16x8*)(sim_ws + 2 * NN + base);
      const f16x8 s3 = *(const f16x8*)(sim_ws + 3 * NN + base);
      const f16x8 r0 = *(const f16x8*)(raw_ws + base);
      const f16x8 r1 = *(const f16x8*)(raw_ws + NN + base);
      const f16x8 r2 = *(const f16x8*)(raw_ws + 2 * NN + base);
      const f16x8 r3 = *(const f16x8*)(raw_ws + 3 * NN + base);
#pragma unroll
      for (int e = 0; e < 8; e++) {
        s[e] = ((float)s0[e] + (float)s1[e] + (float)s2[e] + (float)s3[e]) *
               0.125f;
        rw[e] = (float)r0[e] + (float)r1[e] + (float)r2[e] + (float)r3[e];
      }
    } else {
#pragma unroll
      for (int e = 0; e < 8; e++) { s[e] = -1e30f; rw[e] = 0.f; }
    }
    float lm = -1e30f;
#pragma unroll
    for (int e = 0; e < 8; e++) lm = fmaxf(lm, s[e]);
    const float M = block_max256(lm, red);
    float ls = 0.f;
#pragma unroll
    for (int e = 0; e < 8; e++) {
      const float ev = __expf(s[e] - M);
      s[e] = ev;
      ls += ev;
    }
    const float S = block_sum256(ls, red);
    const float invS = 1.0f / S;
    float lms = 0.f;
#pragma unroll
    for (int e = 0; e < 8; e++) {
      const float p = s[e] * invS;
      const float mp = (act && (rw[e] * 0.125f > SIM_TH)) ? p : 0.f;
      s[e] = mp;
      lms += mp;
    }
    const float MS = block_sum256(lms, red);
    const float invMS = 1.0f / (MS + EPSF);
    if (act) {
      float* __restrict__ outp = out_sim + (size_t)i * N_TOK + tid * 8;
      const float4 o0 = {s[0] * invMS, s[1] * invMS, s[2] * invMS,
                         s[3] * invMS};
      const float4 o1 = {s[4] * invMS, s[5] * invMS, s[6] * invMS,
                         s[7] * invMS};
      *(float4*)outp = o0;
      *(float4*)(outp + 4) = o1;
    }
  }
}

// ---------------------------------------------------------------------------
extern "C" void kernel_launch(void* const* d_in, const int* in_sizes, int n_in,
                              void* d_out, int out_size, void* d_ws,
                              size_t ws_size, hipStream_t stream) {
  const float* x_cls = (const float*)d_in[0];
  const float* x_reg = (const float*)d_in[1];
  const float* W_cls = (const float*)d_in[2];
  const float* W_reg = (const float*)d_in[3];

  // ws layout (~73 MB): v_rm f32, 6 f16 planes, sim f16 x4 partial planes,
  // raw f16 x4 partial planes, transposed-packed W f16 x2.
  const size_t seg = (size_t)NH * N_TOK * HD;  // 512000 elements
  float* v_rm = (float*)d_ws;
  _Float16* qc2 = (_Float16*)(v_rm + seg);
  _Float16* qr2 = qc2 + seg;
  _Float16* kc2 = qr2 + seg;
  _Float16* kr2 = kc2 + seg;
  _Float16* vn2 = kr2 + seg;
  _Float16* v_t = vn2 + seg;
  _Float16* sim_ws = v_t + seg;  // 4 x N*N f16
  _Float16* raw_ws = sim_ws + 4 * (size_t)N_TOK * N_TOK;  // 4 x N*N f16
  _Float16* Wt_cls = raw_ws + 4 * (size_t)N_TOK * N_TOK;  // [768][256] f16
  _Float16* Wt_reg = Wt_cls + 768 * 256;

  dim3 g0(96, 2);
  wpackT_kernel<<<g0, 256, 0, stream>>>(W_cls, W_reg, Wt_cls, Wt_reg);

  dim3 g1(125, 5);
  qkv_mfma_kernel<<<g1, 256, 0, stream>>>(x_cls, x_reg, Wt_cls, Wt_reg, qc2,
                                          qr2, kc2, kr2, vn2, v_rm, v_t);

  float* out_x = (float*)d_out;                  // [2000, 512]
  float* out_sim = out_x + (size_t)N_TOK * 512;  // [2000, 2000]
  attn33_kernel<<<500, 256, 0, stream>>>(qc2, qr2, kc2, kr2, vn2, v_t, v_rm,
                                         out_x, sim_ws, raw_ws);
  sim_round2_kernel<<<1000, 256, 0, stream>>>(sim_ws, raw_ws, out_sim);
}

// Round 15
// 155.935 us; speedup vs baseline: 3.2221x; 1.0426x over previous
//
#include <hip/hip_runtime.h>
#include <math.h>

#define N_TOK 2000
#define NH 8
#define NHH 2   // heads per attn block (4-way head split)
#define HD 32
#define SCALE 25.0f
#define SIM_TH 0.75f
#define EPSF 1e-8f
#define NT 125  // key tiles of 16 (125*16 = 2000 exact)
#define NTS 63  // key-half split point (tiles): kh=0 -> [0,63), kh=1 -> [63,125)
#define QT 16   // query rows per attn block — ALL 16 MFMA cols real

typedef _Float16 half2_t __attribute__((ext_vector_type(2)));
typedef _Float16 f16x4 __attribute__((ext_vector_type(4)));
typedef _Float16 f16x8 __attribute__((ext_vector_type(8)));
typedef float f32x4 __attribute__((ext_vector_type(4)));

__device__ __forceinline__ half2_t u2h(unsigned u) {
  return __builtin_bit_cast(half2_t, u);
}
__device__ __forceinline__ unsigned h2u(half2_t h) {
  return __builtin_bit_cast(unsigned, h);
}

__device__ __forceinline__ float block_max256(float v, float* red) {
#pragma unroll
  for (int off = 32; off > 0; off >>= 1) v = fmaxf(v, __shfl_xor(v, off, 64));
  __syncthreads();
  if ((threadIdx.x & 63) == 0) red[threadIdx.x >> 6] = v;
  __syncthreads();
  return fmaxf(fmaxf(red[0], red[1]), fmaxf(red[2], red[3]));
}
__device__ __forceinline__ float block_sum256(float v, float* red) {
#pragma unroll
  for (int off = 32; off > 0; off >>= 1) v += __shfl_xor(v, off, 64);
  __syncthreads();
  if ((threadIdx.x & 63) == 0) red[threadIdx.x >> 6] = v;
  __syncthreads();
  return (red[0] + red[1]) + (red[2] + red[3]);
}

// ---------------------------------------------------------------------------
// Kernel 0 (UNCHANGED): pack W fp32 [256][768] transposed to f16 Wt[768][256]
// grid = (96, 2), block = 256.
// ---------------------------------------------------------------------------
__global__ __launch_bounds__(256) void wpackT_kernel(
    const float* __restrict__ W_cls, const float* __restrict__ W_reg,
    _Float16* __restrict__ Wt_cls, _Float16* __restrict__ Wt_reg) {
  const int idx = blockIdx.x * 256 + threadIdx.x;  // 0..24575
  const int kc = idx / 768;                        // 0..31 (k chunk of 8)
  const int n = idx % 768;
  const float* __restrict__ W = blockIdx.y ? W_reg : W_cls;
  _Float16* __restrict__ Wt = blockIdx.y ? Wt_reg : Wt_cls;
  uint4 o;
  o.x = h2u((half2_t){(_Float16)W[(kc * 8 + 0) * 768 + n],
                      (_Float16)W[(kc * 8 + 1) * 768 + n]});
  o.y = h2u((half2_t){(_Float16)W[(kc * 8 + 2) * 768 + n],
                      (_Float16)W[(kc * 8 + 3) * 768 + n]});
  o.z = h2u((half2_t){(_Float16)W[(kc * 8 + 4) * 768 + n],
                      (_Float16)W[(kc * 8 + 5) * 768 + n]});
  o.w = h2u((half2_t){(_Float16)W[(kc * 8 + 6) * 768 + n],
                      (_Float16)W[(kc * 8 + 7) * 768 + n]});
  *(uint4*)(Wt + (size_t)n * 256 + kc * 8) = o;
}

// ---------------------------------------------------------------------------
// Kernel 1 (UNCHANGED): MFMA QKV projection. grid = (125, 5), block 256.
// ---------------------------------------------------------------------------
__global__ __launch_bounds__(256) void qkv_mfma_kernel(
    const float* __restrict__ x_cls, const float* __restrict__ x_reg,
    const _Float16* __restrict__ Wt_cls, const _Float16* __restrict__ Wt_reg,
    _Float16* __restrict__ qc2, _Float16* __restrict__ qr2,
    _Float16* __restrict__ kc2, _Float16* __restrict__ kr2,
    _Float16* __restrict__ vn2, float* __restrict__ v_rm,
    _Float16* __restrict__ v_t) {
  __shared__ _Float16 xs[16][264];  // +8 pad: token stride 528B -> <=2-way

  const int tid = threadIdx.x;
  const int c = blockIdx.y;
  const int which = (c >= 3) ? 1 : 0;
  const int sec = which ? (c - 3) : c;  // 0=q, 1=k, 2=v(cls only)
  const int n0 = sec * 256;
  const int i0 = blockIdx.x * 16;
  const float* __restrict__ x = which ? x_reg : x_cls;
  const _Float16* __restrict__ Wt = which ? Wt_reg : Wt_cls;

  // ---- stage x: 16 tokens x 256 k, f32 -> f16 ----
  {
    const int tok = tid >> 4, c4 = tid & 15;
    const float4* __restrict__ xr =
        (const float4*)(x + (size_t)(i0 + tok) * 256);
#pragma unroll
    for (int r = 0; r < 4; r++) {
      const float4 v = xr[c4 + 16 * r];
      *(unsigned*)&xs[tok][(c4 + 16 * r) * 4] =
          h2u((half2_t){(_Float16)v.x, (_Float16)v.y});
      *(unsigned*)&xs[tok][(c4 + 16 * r) * 4 + 2] =
          h2u((half2_t){(_Float16)v.z, (_Float16)v.w});
    }
  }
  __syncthreads();

  const int w = tid >> 6, l = tid & 63;
  const int q = l & 15, kg = l >> 4;
  const f32x4 zero4 = {0.f, 0.f, 0.f, 0.f};
  f32x4 acc[4] = {zero4, zero4, zero4, zero4};
  const int nb = n0 + w * 64;

#pragma unroll
  for (int ks = 0; ks < 8; ks++) {
    const int k0 = ks * 32;
    const f16x8 bx = *(const f16x8*)&xs[q][k0 + kg * 8];
#pragma unroll
    for (int t2 = 0; t2 < 4; t2++) {
      const f16x8 aw = *(const f16x8*)(
          Wt + (size_t)(nb + t2 * 16 + q) * 256 + k0 + kg * 8);
      acc[t2] =
          __builtin_amdgcn_mfma_f32_16x16x32_f16(aw, bx, acc[t2], 0, 0, 0);
    }
  }

  // ---- l2norm sums: group0 = tiles {0,1}, group1 = tiles {2,3} ----
  float ss0 = 0.f, ss1 = 0.f;
#pragma unroll
  for (int i = 0; i < 4; i++) {
    ss0 += acc[0][i] * acc[0][i] + acc[1][i] * acc[1][i];
    ss1 += acc[2][i] * acc[2][i] + acc[3][i] * acc[3][i];
  }
  ss0 += __shfl_xor(ss0, 16, 64);
  ss0 += __shfl_xor(ss0, 32, 64);
  ss1 += __shfl_xor(ss1, 16, 64);
  ss1 += __shfl_xor(ss1, 32, 64);
  const float inv0 = 1.0f / (sqrtf(ss0) + EPSF);
  const float inv1 = 1.0f / (sqrtf(ss1) + EPSF);

  const int tok = i0 + q;
#pragma unroll
  for (int t2 = 0; t2 < 4; t2++) {
    const float inv = (t2 < 2) ? inv0 : inv1;
    const int nrel = w * 64 + t2 * 16 + kg * 4;  // + i
    const int h = nrel >> 5, d0 = nrel & 31;
    uint2 un;
    un.x = h2u((half2_t){(_Float16)(acc[t2][0] * inv),
                         (_Float16)(acc[t2][1] * inv)});
    un.y = h2u((half2_t){(_Float16)(acc[t2][2] * inv),
                         (_Float16)(acc[t2][3] * inv)});
    const size_t off = ((size_t)(h * N_TOK) + tok) * 32 + d0;
    if (sec == 0) {
      *(uint2*)((which ? qr2 : qc2) + off) = un;
    } else if (sec == 1) {
      *(uint2*)((which ? kr2 : kc2) + off) = un;
    } else {
      *(uint2*)(vn2 + off) = un;
      const float4 vr = {acc[t2][0], acc[t2][1], acc[t2][2], acc[t2][3]};
      *(float4*)(v_rm + off) = vr;
#pragma unroll
      for (int i = 0; i < 4; i++) {
        v_t[((size_t)(h * 32) + d0 + i) * N_TOK + tok] = (_Float16)acc[t2][i];
      }
    }
  }
}

// ---------------------------------------------------------------------------
// Kernel 2a (r35 -> r36): attn pass 1 with 2-way KEY SPLIT, grid 500 -> 1000.
// Post-mortem r33-r35: attn was grid-limited three rounds running (500
// blocks / 256 CUs -> occ pinned 18.9%, VALU+MFMA = 43% issue, ~57% stall).
// Fixed-max softmax (exp(25s-25)) makes denominators ADDITIVE, so the key
// range splits cleanly across blocks: kh=0 -> tiles [0,63), kh=1 -> [63,125).
// p1 computes partial sums for its half -> sums_ws[kh] (no atomics; kernel
// ordering gives visibility). Work conserved, concurrency doubled.
// b = qgrp*8 + hp*2 + kh. grid = 1000, block = 256.
// ---------------------------------------------------------------------------
__global__ __launch_bounds__(256) void attn_p1_kernel(
    const _Float16* __restrict__ qc2, const _Float16* __restrict__ qr2,
    const _Float16* __restrict__ kc2, const _Float16* __restrict__ kr2,
    float* __restrict__ sums_ws) {
  __shared__ _Float16 qst[2][NHH][QT][40];
  __shared__ float sums_l[4][2][NHH][16];

  const int tid = threadIdx.x;
  const int w = tid >> 6;
  const int l = tid & 63;
  const int qgrp = blockIdx.x >> 3;
  const int hp = (blockIdx.x >> 1) & 3;
  const int kh = blockIdx.x & 1;
  const int hq = hp * NHH;
  const int i0 = qgrp * QT;

  if (tid < 128) {
    const int hh = tid >> 6, row = (tid >> 2) & 15, dg = tid & 3;
    const size_t src =
        ((size_t)((hq + hh) * N_TOK) + (i0 + row)) * HD + dg * 8;
    *(uint4*)&qst[0][hh][row][dg * 8] = *(const uint4*)(qc2 + src);
    *(uint4*)&qst[1][hh][row][dg * 8] = *(const uint4*)(qr2 + src);
  }
  __syncthreads();

  const int q = l & 15, kg = l >> 4;
  const f32x4 zero4 = {0.f, 0.f, 0.f, 0.f};

  float sc[NHH], sr[NHH];
#pragma unroll
  for (int hh = 0; hh < NHH; hh++) { sc[hh] = 0.f; sr[hh] = 0.f; }

  const int t0 = kh ? NTS : 0;
  const int t1 = kh ? NT : NTS;
  for (int t = t0 + w; t < t1; t += 4) {
    const int mb = t * 16;
#pragma unroll
    for (int hh = 0; hh < NHH; hh++) {
      const size_t koff =
          ((size_t)((hq + hh) * N_TOK) + mb + q) * HD + kg * 8;
      const f16x8 akc = *(const f16x8*)(kc2 + koff);
      const f16x8 akr = *(const f16x8*)(kr2 + koff);
      const f16x8 bqc = *(const f16x8*)&qst[0][hh][q][kg * 8];
      const f16x8 bqr = *(const f16x8*)&qst[1][hh][q][kg * 8];
      const f32x4 dc =
          __builtin_amdgcn_mfma_f32_16x16x32_f16(akc, bqc, zero4, 0, 0, 0);
      const f32x4 dr =
          __builtin_amdgcn_mfma_f32_16x16x32_f16(akr, bqr, zero4, 0, 0, 0);
#pragma unroll
      for (int i = 0; i < 4; i++) {
        sc[hh] += __expf(dc[i] * SCALE - SCALE);
        sr[hh] += __expf(dr[i] * SCALE - SCALE);
      }
    }
  }
#pragma unroll
  for (int hh = 0; hh < NHH; hh++) {
    sc[hh] += __shfl_xor(sc[hh], 16, 64);
    sc[hh] += __shfl_xor(sc[hh], 32, 64);
    sr[hh] += __shfl_xor(sr[hh], 16, 64);
    sr[hh] += __shfl_xor(sr[hh], 32, 64);
  }
  if (l < 16) {
#pragma unroll
    for (int hh = 0; hh < NHH; hh++) {
      sums_l[w][0][hh][l] = sc[hh];
      sums_l[w][1][hh][l] = sr[hh];
    }
  }
  __syncthreads();
  if (tid < 64) {
    const int pl = tid >> 5, hh = (tid >> 4) & 1, qq = tid & 15;
    const float s = sums_l[0][pl][hh][qq] + sums_l[1][pl][hh][qq] +
                    sums_l[2][pl][hh][qq] + sums_l[3][pl][hh][qq];
    sums_ws[((size_t)(kh * 2 + pl) * NH + hq + hh) * N_TOK + i0 + qq] = s;
  }
}

// ---------------------------------------------------------------------------
// Kernel 2b: attn pass 2, key-split. Reads both halves' sums -> nrm;
// recomputes scores for its half, combines/masks, streams sim/raw (columns
// disjoint by kh), PV partial -> pv_ws[kh]. out_x and v_rm copy moved to
// sim_round2. grid = 1000, block = 256.
// ---------------------------------------------------------------------------
__global__ __launch_bounds__(256) void attn_p2_kernel(
    const _Float16* __restrict__ qc2, const _Float16* __restrict__ qr2,
    const _Float16* __restrict__ kc2, const _Float16* __restrict__ kr2,
    const _Float16* __restrict__ vn2, const _Float16* __restrict__ v_t,
    const float* __restrict__ sums_ws, float* __restrict__ pv_ws,
    _Float16* __restrict__ sim_ws, _Float16* __restrict__ raw_ws) {
  __shared__ _Float16 qst[3][NHH][QT][40];  // staged Q planes (7.7 KB)
  __shared__ float smem_u[4224];            // 16.9 KB union

  float* __restrict__ nrm = smem_u + 3584;      // [2][NHH][16] = 64 f (tail)
  float* __restrict__ st = smem_u;              // [4][16][20] = 1280 f
  float* __restrict__ pvr = smem_u;             // [4][2][16][33] = 4224 f*
  // *pvr aliases nrm's tail, but pvr is only used AFTER the main loop when
  // nrm is no longer needed (ncr/nrr cached in registers).

  const int tid = threadIdx.x;
  const int w = tid >> 6;
  const int l = tid & 63;
  const int qgrp = blockIdx.x >> 3;
  const int hp = (blockIdx.x >> 1) & 3;
  const int kh = blockIdx.x & 1;
  const int hq = hp * NHH;
  const int i0 = qgrp * QT;
  _Float16* __restrict__ simp = sim_ws + (size_t)hp * N_TOK * N_TOK;
  _Float16* __restrict__ rawp = raw_ws + (size_t)hp * N_TOK * N_TOK;

  // ---- stage Q: 3 planes x 2 heads x 16 rows x 32 d ----
  if (tid < 128) {
    const int hh = tid >> 6, row = (tid >> 2) & 15, dg = tid & 3;
    const size_t src =
        ((size_t)((hq + hh) * N_TOK) + (i0 + row)) * HD + dg * 8;
    *(uint4*)&qst[0][hh][row][dg * 8] = *(const uint4*)(qc2 + src);
    *(uint4*)&qst[1][hh][row][dg * 8] = *(const uint4*)(qr2 + src);
    *(uint4*)&qst[2][hh][row][dg * 8] = *(const uint4*)(vn2 + src);
  }
  // ---- nrm from both key-half partial sums ----
  if (tid < 64) {
    const int pl = tid >> 5, hh = (tid >> 4) & 1, qq = tid & 15;
    const size_t base = ((size_t)pl * NH + hq + hh) * N_TOK + i0 + qq;
    const float s =
        sums_ws[base] + sums_ws[(size_t)2 * NH * N_TOK + base];
    nrm[(pl * NHH + hh) * 16 + qq] = 0.5f / s;
  }
  __syncthreads();

  const int q = l & 15;
  const int kg = l >> 4;
  const int i_glob = i0 + q;
  const int bs = (i_glob / 10) * 10;

  float ncr[NHH], nrr[NHH];
#pragma unroll
  for (int hh = 0; hh < NHH; hh++) {
    ncr[hh] = nrm[(0 * NHH + hh) * 16 + q];
    nrr[hh] = nrm[(1 * NHH + hh) * 16 + q];
  }
  __syncthreads();  // nrm reads done -> st (aliased region) may be written

  const f32x4 zero4 = {0.f, 0.f, 0.f, 0.f};
  f32x4 pv[NHH][2];
#pragma unroll
  for (int hh = 0; hh < NHH; hh++) { pv[hh][0] = zero4; pv[hh][1] = zero4; }

  const int t0 = kh ? NTS : 0;
  const int t1 = kh ? NT : NTS;
  for (int t = t0 + w; t < t1; t += 4) {
    const int mb = t * 16;
    f32x4 simt = zero4;
    f32x4 rawt = zero4;
#pragma unroll
    for (int hh = 0; hh < NHH; hh++) {
      const int h = hq + hh;
      const size_t koff = ((size_t)(h * N_TOK) + mb + q) * HD + kg * 8;
      const f16x8 akc = *(const f16x8*)(kc2 + koff);
      const f16x8 akr = *(const f16x8*)(kr2 + koff);
      const f16x8 avn = *(const f16x8*)(vn2 + koff);
      const f16x8 bqc = *(const f16x8*)&qst[0][hh][q][kg * 8];
      const f16x8 bqr = *(const f16x8*)&qst[1][hh][q][kg * 8];
      const f16x8 bqv = *(const f16x8*)&qst[2][hh][q][kg * 8];
      const f32x4 dc =
          __builtin_amdgcn_mfma_f32_16x16x32_f16(akc, bqc, zero4, 0, 0, 0);
      const f32x4 dr =
          __builtin_amdgcn_mfma_f32_16x16x32_f16(akr, bqr, zero4, 0, 0, 0);
      rawt = __builtin_amdgcn_mfma_f32_16x16x32_f16(avn, bqv, rawt, 0, 0, 0);

      f16x4 pa;
#pragma unroll
      for (int i = 0; i < 4; i++) {
        const float ec = __expf(dc[i] * SCALE - SCALE);
        const float er = __expf(dr[i] * SCALE - SCALE);
        float ai = ncr[hh] * ec + nrr[hh] * er;
        const int m = mb + kg * 4 + i;
        if (m >= bs && m < bs + 9 && m != i_glob) ai = 0.f;
        simt[i] += ai;
        pa[i] = (_Float16)ai;
      }
      const f16x4 bv0 = *(const f16x4*)(
          v_t + ((size_t)(h * HD) + q) * N_TOK + mb + kg * 4);
      const f16x4 bv1 = *(const f16x4*)(
          v_t + ((size_t)(h * HD) + 16 + q) * N_TOK + mb + kg * 4);
      pv[hh][0] =
          __builtin_amdgcn_mfma_f32_16x16x16f16(pa, bv0, pv[hh][0], 0, 0, 0);
      pv[hh][1] =
          __builtin_amdgcn_mfma_f32_16x16x16f16(pa, bv1, pv[hh][1], 0, 0, 0);
    }
    // ---- stream partial sim tile (f16): 16 rows x 16 cols per wave ----
    st[(w * 16 + q) * 20 + kg * 4 + 0] = simt[0];
    st[(w * 16 + q) * 20 + kg * 4 + 1] = simt[1];
    st[(w * 16 + q) * 20 + kg * 4 + 2] = simt[2];
    st[(w * 16 + q) * 20 + kg * 4 + 3] = simt[3];
    {
      const int row = l >> 2, mo = (l & 3) * 4;
      const float4 v4 = *(const float4*)&st[(w * 16 + row) * 20 + mo];
      uint2 u;
      u.x = h2u((half2_t){(_Float16)v4.x, (_Float16)v4.y});
      u.y = h2u((half2_t){(_Float16)v4.z, (_Float16)v4.w});
      *(uint2*)(simp + (size_t)(i0 + row) * N_TOK + mb + mo) = u;
    }
    // ---- stream partial raw tile (f16) ----
    st[(w * 16 + q) * 20 + kg * 4 + 0] = rawt[0];
    st[(w * 16 + q) * 20 + kg * 4 + 1] = rawt[1];
    st[(w * 16 + q) * 20 + kg * 4 + 2] = rawt[2];
    st[(w * 16 + q) * 20 + kg * 4 + 3] = rawt[3];
    {
      const int row = l >> 2, mo = (l & 3) * 4;
      const float4 v4 = *(const float4*)&st[(w * 16 + row) * 20 + mo];
      uint2 u;
      u.x = h2u((half2_t){(_Float16)v4.x, (_Float16)v4.y});
      u.y = h2u((half2_t){(_Float16)v4.z, (_Float16)v4.w});
      *(uint2*)(rawp + (size_t)(i0 + row) * N_TOK + mb + mo) = u;
    }
  }

  // ======== PV cross-wave reduction -> pv_ws[kh] ========
  __syncthreads();  // st reads done -> pvr (aliased) may be written
#pragma unroll
  for (int hh = 0; hh < NHH; hh++) {
#pragma unroll
    for (int i = 0; i < 4; i++) {
      pvr[((w * 2 + hh) * 16 + kg * 4 + i) * 33 + q] = pv[hh][0][i];
      pvr[((w * 2 + hh) * 16 + kg * 4 + i) * 33 + 16 + q] = pv[hh][1][i];
    }
  }
  __syncthreads();
  {
    const int hh = tid >> 7, qg2 = (tid >> 5) & 3, d = tid & 31;
#pragma unroll
    for (int qi = 0; qi < 4; qi++) {
      const int qq = qg2 * 4 + qi;
      float s = 0.f;
#pragma unroll
      for (int wv = 0; wv < 4; wv++) {
        s += pvr[((wv * 2 + hh) * 16 + qq) * 33 + d];
      }
      pv_ws[(size_t)kh * N_TOK * 256 + (size_t)(i0 + qq) * 256 +
            (hq + hh) * 32 + d] = s;
    }
  }
}

// ---------------------------------------------------------------------------
// Kernel 3 (r35 -> r36): sim_round2 + out_x assembly (pv halves + v_rm).
// grid = 1000, block = 256; 2 rows per block.
// ---------------------------------------------------------------------------
__global__ __launch_bounds__(256) void sim_round2_kernel(
    const _Float16* __restrict__ sim_ws, const _Float16* __restrict__ raw_ws,
    const float* __restrict__ pv_ws, const float* __restrict__ v_rm,
    float* __restrict__ out_x, float* __restrict__ out_sim) {
  __shared__ float red[16];
  const int tid = threadIdx.x;
  const size_t NN = (size_t)N_TOK * N_TOK;
  const size_t PVN = (size_t)N_TOK * 256;
  const bool act = tid < 250;
#pragma unroll
  for (int r = 0; r < 2; r++) {
    const int i = blockIdx.x * 2 + r;
    // ---- out_x assembly: attn half = pv halves sum; copy half = v_rm ----
    out_x[(size_t)i * 512 + tid] =
        pv_ws[(size_t)i * 256 + tid] + pv_ws[PVN + (size_t)i * 256 + tid];
    out_x[(size_t)i * 512 + 256 + tid] =
        v_rm[((size_t)(tid >> 5) * N_TOK + i) * 32 + (tid & 31)];

    float s[8], rw[8];
    if (act) {
      const size_t base = (size_t)i * N_TOK + tid * 8;
      const f16x8 s0 = *(const f16x8*)(sim_ws + base);
      const f16x8 s1 = *(const f16x8*)(sim_ws + NN + base);
      const f16x8 s2 = *(const f16x8*)(sim_ws + 2 * NN + base);
      const f16x8 s3 = *(const f16x8*)(sim_ws + 3 * NN + base);
      const f16x8 r0 = *(const f16x8*)(raw_ws + base);
      const f16x8 r1 = *(const f16x8*)(raw_ws + NN + base);
      const f16x8 r2 = *(const f16x8*)(raw_ws + 2 * NN + base);
      const f16x8 r3 = *(const f16x8*)(raw_ws + 3 * NN + base);
#pragma unroll
      for (int e = 0; e < 8; e++) {
        s[e] = ((float)s0[e] + (float)s1[e] + (float)s2[e] + (float)s3[e]) *
               0.125f;
        rw[e] = (float)r0[e] + (float)r1[e] + (float)r2[e] + (float)r3[e];
      }
    } else {
#pragma unroll
      for (int e = 0; e < 8; e++) { s[e] = -1e30f; rw[e] = 0.f; }
    }
    float lm = -1e30f;
#pragma unroll
    for (int e = 0; e < 8; e++) lm = fmaxf(lm, s[e]);
    const float M = block_max256(lm, red);
    float ls = 0.f;
#pragma unroll
    for (int e = 0; e < 8; e++) {
      const float ev = __expf(s[e] - M);
      s[e] = ev;
      ls += ev;
    }
    const float S = block_sum256(ls, red);
    const float invS = 1.0f / S;
    float lms = 0.f;
#pragma unroll
    for (int e = 0; e < 8; e++) {
      const float p = s[e] * invS;
      const float mp = (act && (rw[e] * 0.125f > SIM_TH)) ? p : 0.f;
      s[e] = mp;
      lms += mp;
    }
    const float MS = block_sum256(lms, red);
    const float invMS = 1.0f / (MS + EPSF);
    if (act) {
      float* __restrict__ outp = out_sim + (size_t)i * N_TOK + tid * 8;
      const float4 o0 = {s[0] * invMS, s[1] * invMS, s[2] * invMS,
                         s[3] * invMS};
      const float4 o1 = {s[4] * invMS, s[5] * invMS, s[6] * invMS,
                         s[7] * invMS};
      *(float4*)outp = o0;
      *(float4*)(outp + 4) = o1;
    }
  }
}

// ---------------------------------------------------------------------------
extern "C" void kernel_launch(void* const* d_in, const int* in_sizes, int n_in,
                              void* d_out, int out_size, void* d_ws,
                              size_t ws_size, hipStream_t stream) {
  const float* x_cls = (const float*)d_in[0];
  const float* x_reg = (const float*)d_in[1];
  const float* W_cls = (const float*)d_in[2];
  const float* W_reg = (const float*)d_in[3];

  // ws layout (~78 MB): v_rm f32, 6 f16 planes, sim f16 x4 partials, raw
  // f16 x4 partials, Wt f16 x2, sums_ws f32, pv_ws f32 x2.
  const size_t seg = (size_t)NH * N_TOK * HD;  // 512000 elements
  float* v_rm = (float*)d_ws;
  _Float16* qc2 = (_Float16*)(v_rm + seg);
  _Float16* qr2 = qc2 + seg;
  _Float16* kc2 = qr2 + seg;
  _Float16* kr2 = kc2 + seg;
  _Float16* vn2 = kr2 + seg;
  _Float16* v_t = vn2 + seg;
  _Float16* sim_ws = v_t + seg;  // 4 x N*N f16
  _Float16* raw_ws = sim_ws + 4 * (size_t)N_TOK * N_TOK;  // 4 x N*N f16
  _Float16* Wt_cls = raw_ws + 4 * (size_t)N_TOK * N_TOK;  // [768][256] f16
  _Float16* Wt_reg = Wt_cls + 768 * 256;
  float* sums_ws = (float*)(Wt_reg + 768 * 256);  // [2kh][2pl][8h][2000] f32
  float* pv_ws = sums_ws + 4 * NH * N_TOK;        // [2kh][2000][256] f32

  dim3 g0(96, 2);
  wpackT_kernel<<<g0, 256, 0, stream>>>(W_cls, W_reg, Wt_cls, Wt_reg);

  dim3 g1(125, 5);
  qkv_mfma_kernel<<<g1, 256, 0, stream>>>(x_cls, x_reg, Wt_cls, Wt_reg, qc2,
                                          qr2, kc2, kr2, vn2, v_rm, v_t);

  float* out_x = (float*)d_out;                  // [2000, 512]
  float* out_sim = out_x + (size_t)N_TOK * 512;  // [2000, 2000]
  attn_p1_kernel<<<1000, 256, 0, stream>>>(qc2, qr2, kc2, kr2, sums_ws);
  attn_p2_kernel<<<1000, 256, 0, stream>>>(qc2, qr2, kc2, kr2, vn2, v_t,
                                           sums_ws, pv_ws, sim_ws, raw_ws);
  sim_round2_kernel<<<1000, 256, 0, stream>>>(sim_ws, raw_ws, pv_ws, v_rm,
                                              out_x, out_sim);
}